// Round 13
// baseline (862.354 us; speedup 1.0000x reference)
//
#include <hip/hip_runtime.h>

#define EPS 1e-5f

typedef __attribute__((ext_vector_type(8))) short bf16x8;
typedef __attribute__((ext_vector_type(4))) float f32x4;

__device__ __forceinline__ unsigned short f2bf(float f) {
    unsigned u = __float_as_uint(f);
    u += 0x7fffu + ((u >> 16) & 1u);
    return (unsigned short)(u >> 16);
}
__device__ __forceinline__ float bf2f(unsigned short s) {
    return __uint_as_float(((unsigned)s) << 16);
}

// ---------------------------------------------------------------------------
__global__ void k_detect(const int* __restrict__ ei, int* __restrict__ flag) {
    if (blockIdx.x == 0 && threadIdx.x == 0) {
        int is64 = 1;
        for (int k = 0; k < 16; ++k) is64 &= (ei[2 * k + 1] == 0) ? 1 : 0;
        *flag = is64;
    }
}

// ---------------------------------------------------------------------------
// CSR build: histogram -> exclusive scan -> fill
__global__ void k_hist(const int* __restrict__ ei, const int* __restrict__ flag,
                       int E, int* __restrict__ cnt) {
    int e = blockIdx.x * blockDim.x + threadIdx.x;
    if (e >= E) return;
    int d = (*flag) ? (int)((const long long*)ei)[E + e] : ei[E + e];
    atomicAdd(&cnt[d], 1);
}

__device__ __forceinline__ int block_incl_scan(int v, int tid, int* total) {
    __shared__ int wsum[4];
    __shared__ int tot;
#pragma unroll
    for (int o = 1; o < 64; o <<= 1) {
        int u = __shfl_up(v, o, 64);
        if ((tid & 63) >= o) v += u;
    }
    if ((tid & 63) == 63) wsum[tid >> 6] = v;
    __syncthreads();
    int w = tid >> 6, add = 0;
    if (w > 0) add += wsum[0];
    if (w > 1) add += wsum[1];
    if (w > 2) add += wsum[2];
    v += add;
    if (tid == 255) tot = v;
    __syncthreads();
    *total = tot;
    __syncthreads();
    return v;
}

__global__ __launch_bounds__(256) void k_scanA(const int* __restrict__ cnt, int n,
                                               int* __restrict__ bsums) {
    int tid = threadIdx.x;
    int idx = blockIdx.x * 1024 + tid * 4;
    int s = 0;
#pragma unroll
    for (int k = 0; k < 4; ++k) { int i = idx + k; if (i < n) s += cnt[i]; }
#pragma unroll
    for (int o = 32; o > 0; o >>= 1) s += __shfl_xor(s, o, 64);
    __shared__ int ws[4];
    if ((tid & 63) == 0) ws[tid >> 6] = s;
    __syncthreads();
    if (tid == 0) bsums[blockIdx.x] = ws[0] + ws[1] + ws[2] + ws[3];
}

__global__ __launch_bounds__(256) void k_scanB(int* __restrict__ bsums, int nb,
                                               int* __restrict__ rowptr, int N) {
    int tid = threadIdx.x;
    __shared__ int sh_carry;
    if (tid == 0) sh_carry = 0;
    __syncthreads();
    int niter = (nb + 255) / 256;
    for (int it = 0; it < niter; ++it) {
        int i = it * 256 + tid;
        int v = (i < nb) ? bsums[i] : 0;
        int tot;
        int inc = block_incl_scan(v, tid, &tot);
        int carry = sh_carry;
        if (i < nb) bsums[i] = carry + inc - v;
        __syncthreads();
        if (tid == 0) sh_carry = carry + tot;
        __syncthreads();
    }
    if (tid == 0) rowptr[N] = sh_carry;
}

__global__ __launch_bounds__(256) void k_scanC(int* __restrict__ cnt_rowptr, int n,
                                               const int* __restrict__ bsums,
                                               int* __restrict__ cursor) {
    int tid = threadIdx.x;
    int idx = blockIdx.x * 1024 + tid * 4;
    int v[4]; int s = 0;
#pragma unroll
    for (int k = 0; k < 4; ++k) { int i = idx + k; v[k] = (i < n) ? cnt_rowptr[i] : 0; s += v[k]; }
    int tot;
    int inc = block_incl_scan(s, tid, &tot);
    int off = bsums[blockIdx.x] + inc - s;
#pragma unroll
    for (int k = 0; k < 4; ++k) {
        int i = idx + k;
        if (i < n) { cnt_rowptr[i] = off; cursor[i] = off; off += v[k]; }
    }
}

__global__ void k_fill(const int* __restrict__ ei, const int* __restrict__ flag, int E,
                       int* __restrict__ cursor, int* __restrict__ csr) {
    int e = blockIdx.x * blockDim.x + threadIdx.x;
    if (e >= E) return;
    int s, d;
    if (*flag) {
        s = (int)((const long long*)ei)[e];
        d = (int)((const long long*)ei)[E + e];
    } else {
        s = ei[e]; d = ei[E + e];
    }
    int pos = atomicAdd(&cursor[d], 1);
    csr[pos] = s;
}

// ---------------------------------------------------------------------------
// Layer-1 gather FUSED with u-moment accumulation (u = (agg1, x), 14 scalars).
// agg1 values are in registers -> moments cost no extra traffic.
__global__ __launch_bounds__(256) void k_gather1m(
    const float* __restrict__ x, const int* __restrict__ rowptr,
    const int* __restrict__ csr, float* __restrict__ agg1,
    float* __restrict__ mom, int n) {
    int tid = threadIdx.x;
    int i = blockIdx.x * 256 + tid;
    float m[14];
#pragma unroll
    for (int k = 0; k < 14; ++k) m[k] = 0.f;
    if (i < n) {
        int r0 = rowptr[i], r1 = rowptr[i + 1];
        float s0 = 0.f, s1 = 0.f;
        int j = r0;
        for (; j + 3 < r1; j += 4) {
            float2 v0 = ((const float2*)x)[csr[j]];
            float2 v1 = ((const float2*)x)[csr[j + 1]];
            float2 v2 = ((const float2*)x)[csr[j + 2]];
            float2 v3 = ((const float2*)x)[csr[j + 3]];
            s0 += v0.x + v1.x + v2.x + v3.x;
            s1 += v0.y + v1.y + v2.y + v3.y;
        }
        for (; j < r1; ++j) {
            float2 v = ((const float2*)x)[csr[j]];
            s0 += v.x; s1 += v.y;
        }
        float inv = 1.f / fmaxf((float)(r1 - r0), 1.f);
        float ax = s0 * inv, ay = s1 * inv;
        agg1[2 * i] = ax;
        agg1[2 * i + 1] = ay;
        float2 xv = ((const float2*)x)[i];
        m[0] = ax;        m[1] = ay;        m[2] = xv.x;      m[3] = xv.y;
        m[4] = ax * ax;   m[5] = ax * ay;   m[6] = ax * xv.x; m[7] = ax * xv.y;
        m[8] = ay * ay;   m[9] = ay * xv.x; m[10] = ay * xv.y;
        m[11] = xv.x * xv.x; m[12] = xv.x * xv.y; m[13] = xv.y * xv.y;
    }
#pragma unroll
    for (int k = 0; k < 14; ++k) {
#pragma unroll
        for (int o = 32; o > 0; o >>= 1) m[k] += __shfl_xor(m[k], o, 64);
    }
    __shared__ float red[4][14];
    int w = tid >> 6;
    if ((tid & 63) == 0) {
#pragma unroll
        for (int k = 0; k < 14; ++k) red[w][k] = m[k];
    }
    __syncthreads();
    if (tid < 14)
        atomicAdd(&mom[tid], red[0][tid] + red[1][tid] + red[2][tid] + red[3][tid]);
}

// BN1-folded weights: x1_c = relu(a0*F0 + a1*F1 + x0*F2 + x1*F3 + F4).
__global__ void k_bnfold1(const float* __restrict__ mom,
                          const float* __restrict__ W1l, const float* __restrict__ b1,
                          const float* __restrict__ W1r,
                          const float* __restrict__ g1, const float* __restrict__ be1,
                          float* __restrict__ fold, float invN) {
    int c = threadIdx.x;  // 64 threads
    float w0 = W1l[c], w1 = W1l[64 + c], w2 = W1r[c], w3 = W1r[64 + c], w4 = b1[c];
    float S0 = mom[0], S1 = mom[1], S2 = mom[2], S3 = mom[3];
    float lin = (S0 * w0 + S1 * w1 + S2 * w2 + S3 * w3) * invN;
    float mean = lin + w4;
    float q = mom[4] * w0 * w0 + mom[8] * w1 * w1 + mom[11] * w2 * w2 + mom[13] * w3 * w3
            + 2.f * (mom[5] * w0 * w1 + mom[6] * w0 * w2 + mom[7] * w0 * w3
                   + mom[9] * w1 * w2 + mom[10] * w1 * w3 + mom[12] * w2 * w3);
    float Eh2 = q * invN + 2.f * w4 * lin + w4 * w4;
    float var = Eh2 - mean * mean;
    float al = g1[c] * rsqrtf(var + EPS);
    float be = be1[c] - mean * al;
    fold[c]       = al * w0;
    fold[64 + c]  = al * w1;
    fold[128 + c] = al * w2;
    fold[192 + c] = al * w3;
    fold[256 + c] = al * w4 + be;
}

// ---------------------------------------------------------------------------
__global__ void k_bnfin(const float* __restrict__ stats, const float* __restrict__ g,
                        const float* __restrict__ be, float* __restrict__ coef, float invN) {
    int c = threadIdx.x;
    float m = stats[c] * invN;
    float var = stats[64 + c] * invN - m * m;
    float a = g[c] * rsqrtf(var + EPS);
    coef[c] = a;
    coef[64 + c] = be[c] - m * a;
}

// ---------------------------------------------------------------------------
// Pre-transform: x1 = relu(bn1-folded(agg1, x)) on the fly; y = x1@W2l;
// z = x1@W2r + b2; t1 = x1.W3l; v1 = x1.W3r. LDS out-stage -> full-line stores.
#define LROW 72  // LDS row stride in shorts

__global__ __launch_bounds__(256) void k_dense_pre(
    const float* __restrict__ agg1, const float* __restrict__ xin,
    const float* __restrict__ fold,
    const float* __restrict__ W2l, const float* __restrict__ b2,
    const float* __restrict__ W2r,
    const float* __restrict__ W3l, const float* __restrict__ W3r,
    unsigned short* __restrict__ y, unsigned short* __restrict__ z,
    float* __restrict__ t1, float* __restrict__ v1, int n) {
    __shared__ unsigned short lds_w[16 * 64 * 8];                 // 16 KB
    __shared__ __align__(16) unsigned short lds_y[4][16 * LROW];
    __shared__ __align__(16) unsigned short lds_z[4][16 * LROW];
    int tid = threadIdx.x, w = tid >> 6, l = tid & 63, ln = l & 15, kg = l >> 4;

    for (int idx = tid; idx < 4096; idx += 256) {
        int k = idx >> 6, c = idx & 63;
        int lane = ((k >> 3) & 3) * 16 + (c & 15);
        int fbase = ((k >> 5) * 4 + (c >> 4)) * 64 + lane;
        lds_w[fbase * 8 + (k & 7)] = f2bf(W2l[idx]);
        lds_w[(8 * 64 + fbase) * 8 + (k & 7)] = f2bf(W2r[idx]);
    }
    __syncthreads();

    float bb[4];
#pragma unroll
    for (int cs = 0; cs < 4; ++cs) bb[cs] = b2[cs * 16 + ln];

    float F0[16], F1[16], F2[16], F3[16], F4[16];
#pragma unroll
    for (int j = 0; j < 8; ++j) {
        int c = kg * 8 + j;
        F0[j] = fold[c];       F1[j] = fold[64 + c];  F2[j] = fold[128 + c];
        F3[j] = fold[192 + c]; F4[j] = fold[256 + c];
        c += 32;
        F0[8 + j] = fold[c];       F1[8 + j] = fold[64 + c];  F2[8 + j] = fold[128 + c];
        F3[8 + j] = fold[192 + c]; F4[8 + j] = fold[256 + c];
    }
    bf16x8 b3a, b3b;
#pragma unroll
    for (int j = 0; j < 8; ++j) {
        float va = (ln == 0) ? W3l[kg * 8 + j] : ((ln == 1) ? W3r[kg * 8 + j] : 0.f);
        float vb = (ln == 0) ? W3l[32 + kg * 8 + j] : ((ln == 1) ? W3r[32 + kg * 8 + j] : 0.f);
        b3a[j] = (short)f2bf(va);
        b3b[j] = (short)f2bf(vb);
    }

    unsigned short* Ys = lds_y[w];
    unsigned short* Zs = lds_z[w];
    const bf16x8* wfrag = (const bf16x8*)lds_w;
    int nt = (n + 15) >> 4;
    int stride = gridDim.x * 4;

#define LOADH(T, A)                                                          \
    {                                                                        \
        int row_ = ((T) << 4) + ln;                                          \
        int rr_ = (row_ < n) ? row_ : (n - 1);                               \
        A##a = ((const float2*)agg1)[rr_];                                   \
        A##x = ((const float2*)xin)[rr_];                                    \
    }

#define PROCESSH(T, A)                                                       \
    {                                                                        \
        bf16x8 u0_, u1_;                                                     \
        _Pragma("unroll")                                                    \
        for (int j = 0; j < 8; ++j) {                                        \
            float h0_ = fmaf(A##a.x, F0[j], fmaf(A##a.y, F1[j],              \
                        fmaf(A##x.x, F2[j], fmaf(A##x.y, F3[j], F4[j]))));   \
            float h1_ = fmaf(A##a.x, F0[8 + j], fmaf(A##a.y, F1[8 + j],      \
                        fmaf(A##x.x, F2[8 + j], fmaf(A##x.y, F3[8 + j], F4[8 + j])))); \
            u0_[j] = (short)f2bf(fmaxf(0.f, h0_));                           \
            u1_[j] = (short)f2bf(fmaxf(0.f, h1_));                           \
        }                                                                    \
        f32x4 ya_[4], za_[4], a3_;                                           \
        _Pragma("unroll")                                                    \
        for (int cs = 0; cs < 4; ++cs) {                                     \
            ya_[cs] = (f32x4){0.f, 0.f, 0.f, 0.f};                           \
            za_[cs] = (f32x4){0.f, 0.f, 0.f, 0.f};                           \
        }                                                                    \
        a3_ = (f32x4){0.f, 0.f, 0.f, 0.f};                                   \
        _Pragma("unroll")                                                    \
        for (int cs = 0; cs < 4; ++cs) {                                     \
            ya_[cs] = __builtin_amdgcn_mfma_f32_16x16x32_bf16(u0_, wfrag[(0 * 4 + cs) * 64 + l], ya_[cs], 0, 0, 0);  \
            ya_[cs] = __builtin_amdgcn_mfma_f32_16x16x32_bf16(u1_, wfrag[(1 * 4 + cs) * 64 + l], ya_[cs], 0, 0, 0);  \
            za_[cs] = __builtin_amdgcn_mfma_f32_16x16x32_bf16(u0_, wfrag[(8 + cs) * 64 + l], za_[cs], 0, 0, 0);      \
            za_[cs] = __builtin_amdgcn_mfma_f32_16x16x32_bf16(u1_, wfrag[(12 + cs) * 64 + l], za_[cs], 0, 0, 0);     \
        }                                                                    \
        a3_ = __builtin_amdgcn_mfma_f32_16x16x32_bf16(u0_, b3a, a3_, 0, 0, 0); \
        a3_ = __builtin_amdgcn_mfma_f32_16x16x32_bf16(u1_, b3b, a3_, 0, 0, 0); \
        _Pragma("unroll")                                                    \
        for (int cs = 0; cs < 4; ++cs) {                                     \
            _Pragma("unroll")                                                \
            for (int r = 0; r < 4; ++r) {                                    \
                Ys[(kg * 4 + r) * LROW + cs * 16 + ln] = f2bf(ya_[cs][r]);   \
                Zs[(kg * 4 + r) * LROW + cs * 16 + ln] = f2bf(za_[cs][r] + bb[cs]); \
            }                                                                \
        }                                                                    \
        int base_ = (T) << 4;                                                \
        if (ln < 2) {                                                        \
            float* d3_ = (ln == 0) ? t1 : v1;                                \
            _Pragma("unroll")                                                \
            for (int r = 0; r < 4; ++r) {                                    \
                int row_ = base_ + kg * 4 + r;                               \
                if (row_ < n) d3_[row_] = a3_[r];                            \
            }                                                                \
        }                                                                    \
        asm volatile("s_waitcnt lgkmcnt(0)" ::: "memory");                   \
        int orow_ = l >> 2, oc_ = (l & 3) * 16;                              \
        if (base_ + orow_ < n) {                                             \
            const bf16x8* yp_ = (const bf16x8*)(Ys + orow_ * LROW + oc_);    \
            const bf16x8* zp_ = (const bf16x8*)(Zs + orow_ * LROW + oc_);    \
            bf16x8* yd_ = (bf16x8*)(y + (size_t)(base_ + orow_) * 64 + oc_); \
            bf16x8* zd_ = (bf16x8*)(z + (size_t)(base_ + orow_) * 64 + oc_); \
            yd_[0] = yp_[0]; yd_[1] = yp_[1];                                \
            zd_[0] = zp_[0]; zd_[1] = zp_[1];                                \
        }                                                                    \
        asm volatile("s_waitcnt lgkmcnt(0)" ::: "memory");                   \
    }

    float2 Pa, Px, Qa, Qx;
    int t = blockIdx.x * 4 + w;
    if (t < nt) {
        LOADH(t, P);
        while (t < nt) {
            int t1_ = t + stride;
            if (t1_ < nt) LOADH(t1_, Q);
            PROCESSH(t, P);
            int t2_ = t1_ + stride;
            if (t2_ < nt) LOADH(t2_, P);
            if (t1_ < nt) PROCESSH(t1_, Q);
            t = t2_;
        }
    }
#undef LOADH
#undef PROCESSH
}

// ---------------------------------------------------------------------------
// Gather + combine, ONE-SHOT: grid = ceil(n/32); each 8-lane group owns exactly
// one node (no grid-stride loop -> no serial chaining per wave; the scheduler
// interleaves 62k short waves). zh2 row load issued before the rowptr chain.
__global__ __launch_bounds__(256) void k_gather2b(
    const unsigned short* __restrict__ y, const int* __restrict__ rowptr,
    const int* __restrict__ csr, unsigned short* zh2,
    float* __restrict__ stats, int n) {
    int tid = threadIdx.x;
    int lg = tid & 7;
    int i = blockIdx.x * 32 + (tid >> 3);
    float ls[8] = {0.f, 0.f, 0.f, 0.f, 0.f, 0.f, 0.f, 0.f};
    float lq[8] = {0.f, 0.f, 0.f, 0.f, 0.f, 0.f, 0.f, 0.f};

    if (i < n) {
        bf16x8 z8 = *(const bf16x8*)(zh2 + (size_t)i * 64 + lg * 8);  // in flight early
        int r0 = rowptr[i], r1 = rowptr[i + 1];
        float s[8] = {0.f, 0.f, 0.f, 0.f, 0.f, 0.f, 0.f, 0.f};
        int j = r0;
        for (; j + 1 < r1; j += 2) {
            int a = csr[j], b = csr[j + 1];
            bf16x8 va = *(const bf16x8*)(y + (size_t)a * 64 + lg * 8);
            bf16x8 vb = *(const bf16x8*)(y + (size_t)b * 64 + lg * 8);
#pragma unroll
            for (int k = 0; k < 8; ++k)
                s[k] += bf2f((unsigned short)va[k]) + bf2f((unsigned short)vb[k]);
        }
        if (j < r1) {
            bf16x8 va = *(const bf16x8*)(y + (size_t)csr[j] * 64 + lg * 8);
#pragma unroll
            for (int k = 0; k < 8; ++k) s[k] += bf2f((unsigned short)va[k]);
        }
        float inv = 1.f / fmaxf((float)(r1 - r0), 1.f);
        bf16x8 hb;
#pragma unroll
        for (int k = 0; k < 8; ++k) {
            float h = fmaf(s[k], inv, bf2f((unsigned short)z8[k]));
            unsigned short b = f2bf(h);
            hb[k] = (short)b;
            float hf = bf2f(b);
            ls[k] += hf; lq[k] += hf * hf;
        }
        *(bf16x8*)(zh2 + (size_t)i * 64 + lg * 8) = hb;
    }

    // lanes sharing lg (l, l^8, ..., l^56) hold the same 8 channels
#pragma unroll
    for (int k = 0; k < 8; ++k) {
        ls[k] += __shfl_xor(ls[k], 8, 64);
        ls[k] += __shfl_xor(ls[k], 16, 64);
        ls[k] += __shfl_xor(ls[k], 32, 64);
        lq[k] += __shfl_xor(lq[k], 8, 64);
        lq[k] += __shfl_xor(lq[k], 16, 64);
        lq[k] += __shfl_xor(lq[k], 32, 64);
    }
    __shared__ float red[2][4][64];
    int w = tid >> 6;
    if ((tid & 63) < 8) {
#pragma unroll
        for (int k = 0; k < 8; ++k) {
            red[0][w][lg * 8 + k] = ls[k];
            red[1][w][lg * 8 + k] = lq[k];
        }
    }
    __syncthreads();
    if (tid < 64) {
        atomicAdd(&stats[tid], red[0][0][tid] + red[0][1][tid] + red[0][2][tid] + red[0][3][tid]);
        atomicAdd(&stats[64 + tid], red[1][0][tid] + red[1][1][tid] + red[1][2][tid] + red[1][3][tid]);
    }
}

// ---------------------------------------------------------------------------
// Finalize: t = relu(bn2(h2)).W3l + t1;  v = relu(bn2(h2)).W3r + v1.
__global__ __launch_bounds__(256) void k_finalize(
    const unsigned short* __restrict__ h2b,
    const float* __restrict__ t1, const float* __restrict__ v1,
    const float* __restrict__ coef2,
    const float* __restrict__ W3l, const float* __restrict__ W3r,
    float* __restrict__ tb, float* __restrict__ vb, int n) {
    int tid = threadIdx.x, c = tid & 63, w = tid >> 6;
    int i0 = (blockIdx.x * 4 + w) * 8;
    if (i0 >= n) return;
    float a2 = coef2[c], b2 = coef2[64 + c];
    float wl = W3l[c], wr = W3r[c];
    float tv[8], vv[8];
#pragma unroll
    for (int q = 0; q < 8; ++q) {
        int i = i0 + q; int ic = (i < n) ? i : (n - 1);
        float h2v = bf2f(h2b[(size_t)ic * 64 + c]);
        float x2v = fmaxf(0.f, fmaf(h2v, a2, b2));
        tv[q] = x2v * wl; vv[q] = x2v * wr;
    }
#pragma unroll
    for (int q = 0; q < 8; ++q) {
        float t = tv[q], v = vv[q];
#pragma unroll
        for (int o = 32; o > 0; o >>= 1) {
            t += __shfl_xor(t, o, 64);
            v += __shfl_xor(v, o, 64);
        }
        int i = i0 + q;
        if (c == 0 && i < n) { tb[i] = t + t1[i]; vb[i] = v + v1[i]; }
    }
}

// ---------------------------------------------------------------------------
__global__ void k_gather3(const float* __restrict__ tb, const float* __restrict__ vb,
                          const int* __restrict__ rowptr, const int* __restrict__ csr,
                          const float* __restrict__ b3, float* __restrict__ out, int n) {
    int i = blockIdx.x * blockDim.x + threadIdx.x;
    if (i >= n) return;
    int r0 = rowptr[i], r1 = rowptr[i + 1];
    float s = 0.f;
    int j = r0;
    for (; j + 3 < r1; j += 4)
        s += tb[csr[j]] + tb[csr[j + 1]] + tb[csr[j + 2]] + tb[csr[j + 3]];
    for (; j < r1; ++j) s += tb[csr[j]];
    float inv = 1.f / fmaxf((float)(r1 - r0), 1.f);
    out[i] = fmaf(s, inv, b3[0] + vb[i]);
}

// ---------------------------------------------------------------------------
// Workspace (4B units, N=500k, E=1.25M; cap 256 MiB = 67,108,864 units):
//   y 32N + zh2 32N + R 2N + t1 N + v1 N + rowptr N+1 + csr E + small
//   = 68N + E + ~1k = ~35.3M units = 141 MB (safe)
extern "C" void kernel_launch(void* const* d_in, const int* in_sizes, int n_in,
                              void* d_out, int out_size, void* d_ws, size_t ws_size,
                              hipStream_t stream) {
    const float* x   = (const float*)d_in[0];
    const int*   ei  = (const int*)d_in[1];
    const float* W1l = (const float*)d_in[2];
    const float* b1  = (const float*)d_in[3];
    const float* W1r = (const float*)d_in[4];
    const float* g1  = (const float*)d_in[5];
    const float* be1 = (const float*)d_in[6];
    const float* W2l = (const float*)d_in[7];
    const float* b2  = (const float*)d_in[8];
    const float* W2r = (const float*)d_in[9];
    const float* g2  = (const float*)d_in[10];
    const float* be2 = (const float*)d_in[11];
    const float* W3l = (const float*)d_in[12];
    const float* b3  = (const float*)d_in[13];
    const float* W3r = (const float*)d_in[14];

    int N = in_sizes[0] / 2;
    int E = in_sizes[1] / 2;

    float* ws   = (float*)d_ws;
    size_t nn   = (size_t)N;
    unsigned short* y   = (unsigned short*)ws;             // 32N units
    unsigned short* zh2 = (unsigned short*)(ws + 32 * nn); // 32N units (z -> h2)
    float* R     = ws + 64 * nn;            // 2N time-shared: cursor -> agg1 -> tb/vb
    int*   cursor = (int*)R;
    float* agg1   = R;
    float* tb     = R;
    float* vb     = R + nn;
    float* t1     = ws + 66 * nn;           // N
    float* v1     = ws + 67 * nn;           // N
    int*   rowptr = (int*)(ws + 68 * nn);   // N+1 (doubles as histogram cnt)
    int*   csr    = rowptr + (N + 1);       // E
    int*   bsums  = csr + E;                // 2048
    float* mom    = (float*)(bsums + 2048); // 16 (14 used)
    float* stats2 = mom + 16;               // 128: s2, q2
    float* coef2  = stats2 + 128;           // 128: a2, b2
    float* fold   = coef2 + 128;            // 320: F0..F4
    int*   flag   = (int*)(fold + 320);     // 64

    hipMemsetAsync(rowptr, 0, (size_t)(N + 1) * sizeof(int), stream);
    hipMemsetAsync(mom, 0, 16 * sizeof(float), stream);
    hipMemsetAsync(stats2, 0, 128 * sizeof(float), stream);

    k_detect<<<1, 1, 0, stream>>>(ei, flag);

    int ge = (E + 255) / 256;
    int gn = (N + 255) / 256;
    int nb = (N + 1023) / 1024;
    k_hist<<<ge, 256, 0, stream>>>(ei, flag, E, rowptr);
    k_scanA<<<nb, 256, 0, stream>>>(rowptr, N, bsums);
    k_scanB<<<1, 256, 0, stream>>>(bsums, nb, rowptr, N);
    k_scanC<<<nb, 256, 0, stream>>>(rowptr, N, bsums, cursor);
    k_fill<<<ge, 256, 0, stream>>>(ei, flag, E, cursor, csr);
    // cursor dead; R becomes agg1

    k_gather1m<<<gn, 256, 0, stream>>>(x, rowptr, csr, agg1, mom, N);
    k_bnfold1<<<1, 64, 0, stream>>>(mom, W1l, b1, W1r, g1, be1, fold, 1.0f / (float)N);

    k_dense_pre<<<2048, 256, 0, stream>>>(agg1, x, fold, W2l, b2, W2r, W3l, W3r,
                                          y, zh2, t1, v1, N);
    // agg1 dead after dense_pre

    int g2b = (N + 31) / 32;  // one node per 8-lane group
    k_gather2b<<<g2b, 256, 0, stream>>>(y, rowptr, csr, zh2, stats2, N);
    k_bnfin<<<1, 64, 0, stream>>>(stats2, g2, be2, coef2, 1.0f / (float)N);

    // R becomes tb/vb
    k_finalize<<<(N + 31) / 32, 256, 0, stream>>>(zh2, t1, v1, coef2,
                                                  W3l, W3r, tb, vb, N);
    k_gather3<<<gn, 256, 0, stream>>>(tb, vb, rowptr, csr, b3, (float*)d_out, N);
}

// Round 14
// 414.522 us; speedup vs baseline: 2.0804x; 2.0804x over previous
//
#include <hip/hip_runtime.h>

#define EPS 1e-5f

typedef __attribute__((ext_vector_type(8))) short bf16x8;
typedef __attribute__((ext_vector_type(4))) float f32x4;

__device__ __forceinline__ unsigned short f2bf(float f) {
    unsigned u = __float_as_uint(f);
    u += 0x7fffu + ((u >> 16) & 1u);
    return (unsigned short)(u >> 16);
}
__device__ __forceinline__ float bf2f(unsigned short s) {
    return __uint_as_float(((unsigned)s) << 16);
}

// ---------------------------------------------------------------------------
__global__ void k_detect(const int* __restrict__ ei, int* __restrict__ flag) {
    if (blockIdx.x == 0 && threadIdx.x == 0) {
        int is64 = 1;
        for (int k = 0; k < 16; ++k) is64 &= (ei[2 * k + 1] == 0) ? 1 : 0;
        *flag = is64;
    }
}

// ---------------------------------------------------------------------------
// CSR build: histogram -> exclusive scan -> fill
__global__ void k_hist(const int* __restrict__ ei, const int* __restrict__ flag,
                       int E, int* __restrict__ cnt) {
    int e = blockIdx.x * blockDim.x + threadIdx.x;
    if (e >= E) return;
    int d = (*flag) ? (int)((const long long*)ei)[E + e] : ei[E + e];
    atomicAdd(&cnt[d], 1);
}

__device__ __forceinline__ int block_incl_scan(int v, int tid, int* total) {
    __shared__ int wsum[4];
    __shared__ int tot;
#pragma unroll
    for (int o = 1; o < 64; o <<= 1) {
        int u = __shfl_up(v, o, 64);
        if ((tid & 63) >= o) v += u;
    }
    if ((tid & 63) == 63) wsum[tid >> 6] = v;
    __syncthreads();
    int w = tid >> 6, add = 0;
    if (w > 0) add += wsum[0];
    if (w > 1) add += wsum[1];
    if (w > 2) add += wsum[2];
    v += add;
    if (tid == 255) tot = v;
    __syncthreads();
    *total = tot;
    __syncthreads();
    return v;
}

__global__ __launch_bounds__(256) void k_scanA(const int* __restrict__ cnt, int n,
                                               int* __restrict__ bsums) {
    int tid = threadIdx.x;
    int idx = blockIdx.x * 1024 + tid * 4;
    int s = 0;
#pragma unroll
    for (int k = 0; k < 4; ++k) { int i = idx + k; if (i < n) s += cnt[i]; }
#pragma unroll
    for (int o = 32; o > 0; o >>= 1) s += __shfl_xor(s, o, 64);
    __shared__ int ws[4];
    if ((tid & 63) == 0) ws[tid >> 6] = s;
    __syncthreads();
    if (tid == 0) bsums[blockIdx.x] = ws[0] + ws[1] + ws[2] + ws[3];
}

__global__ __launch_bounds__(256) void k_scanB(int* __restrict__ bsums, int nb,
                                               int* __restrict__ rowptr, int N) {
    int tid = threadIdx.x;
    __shared__ int sh_carry;
    if (tid == 0) sh_carry = 0;
    __syncthreads();
    int niter = (nb + 255) / 256;
    for (int it = 0; it < niter; ++it) {
        int i = it * 256 + tid;
        int v = (i < nb) ? bsums[i] : 0;
        int tot;
        int inc = block_incl_scan(v, tid, &tot);
        int carry = sh_carry;
        if (i < nb) bsums[i] = carry + inc - v;
        __syncthreads();
        if (tid == 0) sh_carry = carry + tot;
        __syncthreads();
    }
    if (tid == 0) rowptr[N] = sh_carry;
}

__global__ __launch_bounds__(256) void k_scanC(int* __restrict__ cnt_rowptr, int n,
                                               const int* __restrict__ bsums,
                                               int* __restrict__ cursor) {
    int tid = threadIdx.x;
    int idx = blockIdx.x * 1024 + tid * 4;
    int v[4]; int s = 0;
#pragma unroll
    for (int k = 0; k < 4; ++k) { int i = idx + k; v[k] = (i < n) ? cnt_rowptr[i] : 0; s += v[k]; }
    int tot;
    int inc = block_incl_scan(s, tid, &tot);
    int off = bsums[blockIdx.x] + inc - s;
#pragma unroll
    for (int k = 0; k < 4; ++k) {
        int i = idx + k;
        if (i < n) { cnt_rowptr[i] = off; cursor[i] = off; off += v[k]; }
    }
}

__global__ void k_fill(const int* __restrict__ ei, const int* __restrict__ flag, int E,
                       int* __restrict__ cursor, int* __restrict__ csr) {
    int e = blockIdx.x * blockDim.x + threadIdx.x;
    if (e >= E) return;
    int s, d;
    if (*flag) {
        s = (int)((const long long*)ei)[e];
        d = (int)((const long long*)ei)[E + e];
    } else {
        s = ei[e]; d = ei[E + e];
    }
    int pos = atomicAdd(&cursor[d], 1);
    csr[pos] = s;
}

// ---------------------------------------------------------------------------
// Layer-1 gather fused with u-moments (u = (agg1, x), 14 scalars).
// ATOMIC-FREE stats: per-block partials to pmom[k][block].
__global__ __launch_bounds__(256) void k_gather1m(
    const float* __restrict__ x, const int* __restrict__ rowptr,
    const int* __restrict__ csr, float* __restrict__ agg1,
    float* __restrict__ pmom, int n) {
    int tid = threadIdx.x;
    int i = blockIdx.x * 256 + tid;
    float m[14];
#pragma unroll
    for (int k = 0; k < 14; ++k) m[k] = 0.f;
    if (i < n) {
        int r0 = rowptr[i], r1 = rowptr[i + 1];
        float s0 = 0.f, s1 = 0.f;
        int j = r0;
        for (; j + 3 < r1; j += 4) {
            float2 v0 = ((const float2*)x)[csr[j]];
            float2 v1 = ((const float2*)x)[csr[j + 1]];
            float2 v2 = ((const float2*)x)[csr[j + 2]];
            float2 v3 = ((const float2*)x)[csr[j + 3]];
            s0 += v0.x + v1.x + v2.x + v3.x;
            s1 += v0.y + v1.y + v2.y + v3.y;
        }
        for (; j < r1; ++j) {
            float2 v = ((const float2*)x)[csr[j]];
            s0 += v.x; s1 += v.y;
        }
        float inv = 1.f / fmaxf((float)(r1 - r0), 1.f);
        float ax = s0 * inv, ay = s1 * inv;
        agg1[2 * i] = ax;
        agg1[2 * i + 1] = ay;
        float2 xv = ((const float2*)x)[i];
        m[0] = ax;        m[1] = ay;        m[2] = xv.x;      m[3] = xv.y;
        m[4] = ax * ax;   m[5] = ax * ay;   m[6] = ax * xv.x; m[7] = ax * xv.y;
        m[8] = ay * ay;   m[9] = ay * xv.x; m[10] = ay * xv.y;
        m[11] = xv.x * xv.x; m[12] = xv.x * xv.y; m[13] = xv.y * xv.y;
    }
#pragma unroll
    for (int k = 0; k < 14; ++k) {
#pragma unroll
        for (int o = 32; o > 0; o >>= 1) m[k] += __shfl_xor(m[k], o, 64);
    }
    __shared__ float red[4][14];
    int w = tid >> 6;
    if ((tid & 63) == 0) {
#pragma unroll
        for (int k = 0; k < 14; ++k) red[w][k] = m[k];
    }
    __syncthreads();
    if (tid < 14)
        pmom[(size_t)tid * gridDim.x + blockIdx.x] =
            red[0][tid] + red[1][tid] + red[2][tid] + red[3][tid];
}

// ---------------------------------------------------------------------------
// Reduce pmom partials + BN1-fold (1 block x 256).
// x1_c = relu(a0*F0 + a1*F1 + x0*F2 + x1*F3 + F4).
__global__ __launch_bounds__(256) void k_bnfold1(
    const float* __restrict__ pmom, int gn,
    const float* __restrict__ W1l, const float* __restrict__ b1,
    const float* __restrict__ W1r,
    const float* __restrict__ g1, const float* __restrict__ be1,
    float* __restrict__ fold, float invN) {
    int tid = threadIdx.x;
    __shared__ float smom[14];
    __shared__ float ws[4];
    for (int k = 0; k < 14; ++k) {
        float s = 0.f;
        for (int idx = tid; idx < gn; idx += 256) s += pmom[(size_t)k * gn + idx];
#pragma unroll
        for (int o = 32; o > 0; o >>= 1) s += __shfl_xor(s, o, 64);
        if ((tid & 63) == 0) ws[tid >> 6] = s;
        __syncthreads();
        if (tid == 0) smom[k] = ws[0] + ws[1] + ws[2] + ws[3];
        __syncthreads();
    }
    if (tid < 64) {
        int c = tid;
        float w0 = W1l[c], w1 = W1l[64 + c], w2 = W1r[c], w3 = W1r[64 + c], w4 = b1[c];
        float lin = (smom[0] * w0 + smom[1] * w1 + smom[2] * w2 + smom[3] * w3) * invN;
        float mean = lin + w4;
        float q = smom[4] * w0 * w0 + smom[8] * w1 * w1 + smom[11] * w2 * w2 + smom[13] * w3 * w3
                + 2.f * (smom[5] * w0 * w1 + smom[6] * w0 * w2 + smom[7] * w0 * w3
                       + smom[9] * w1 * w2 + smom[10] * w1 * w3 + smom[12] * w2 * w3);
        float Eh2 = q * invN + 2.f * w4 * lin + w4 * w4;
        float var = Eh2 - mean * mean;
        float al = g1[c] * rsqrtf(var + EPS);
        float be = be1[c] - mean * al;
        fold[c]       = al * w0;
        fold[64 + c]  = al * w1;
        fold[128 + c] = al * w2;
        fold[192 + c] = al * w3;
        fold[256 + c] = al * w4 + be;
    }
}

// ---------------------------------------------------------------------------
// Reduce pstats[c][nb] -> stats2[c]  (c = 0..127; grid = 128 blocks)
__global__ __launch_bounds__(256) void k_sreduce(const float* __restrict__ pstats,
                                                 int nb, float* __restrict__ stats2) {
    int c = blockIdx.x, tid = threadIdx.x;
    float s = 0.f;
    for (int i = tid; i < nb; i += 256) s += pstats[(size_t)c * nb + i];
#pragma unroll
    for (int o = 32; o > 0; o >>= 1) s += __shfl_xor(s, o, 64);
    __shared__ float ws[4];
    if ((tid & 63) == 0) ws[tid >> 6] = s;
    __syncthreads();
    if (tid == 0) stats2[c] = ws[0] + ws[1] + ws[2] + ws[3];
}

__global__ void k_bnfin(const float* __restrict__ stats, const float* __restrict__ g,
                        const float* __restrict__ be, float* __restrict__ coef, float invN) {
    int c = threadIdx.x;
    float m = stats[c] * invN;
    float var = stats[64 + c] * invN - m * m;
    float a = g[c] * rsqrtf(var + EPS);
    coef[c] = a;
    coef[64 + c] = be[c] - m * a;
}

// ---------------------------------------------------------------------------
// Pre-transform: x1 = relu(bn1-folded(agg1, x)) on the fly; y = x1@W2l;
// z = x1@W2r + b2; t1 = x1.W3l; v1 = x1.W3r. LDS out-stage -> full-line stores.
#define LROW 72  // LDS row stride in shorts

__global__ __launch_bounds__(256) void k_dense_pre(
    const float* __restrict__ agg1, const float* __restrict__ xin,
    const float* __restrict__ fold,
    const float* __restrict__ W2l, const float* __restrict__ b2,
    const float* __restrict__ W2r,
    const float* __restrict__ W3l, const float* __restrict__ W3r,
    unsigned short* __restrict__ y, unsigned short* __restrict__ z,
    float* __restrict__ t1, float* __restrict__ v1, int n) {
    __shared__ unsigned short lds_w[16 * 64 * 8];                 // 16 KB
    __shared__ __align__(16) unsigned short lds_y[4][16 * LROW];
    __shared__ __align__(16) unsigned short lds_z[4][16 * LROW];
    int tid = threadIdx.x, w = tid >> 6, l = tid & 63, ln = l & 15, kg = l >> 4;

    for (int idx = tid; idx < 4096; idx += 256) {
        int k = idx >> 6, c = idx & 63;
        int lane = ((k >> 3) & 3) * 16 + (c & 15);
        int fbase = ((k >> 5) * 4 + (c >> 4)) * 64 + lane;
        lds_w[fbase * 8 + (k & 7)] = f2bf(W2l[idx]);
        lds_w[(8 * 64 + fbase) * 8 + (k & 7)] = f2bf(W2r[idx]);
    }
    __syncthreads();

    float bb[4];
#pragma unroll
    for (int cs = 0; cs < 4; ++cs) bb[cs] = b2[cs * 16 + ln];

    float F0[16], F1[16], F2[16], F3[16], F4[16];
#pragma unroll
    for (int j = 0; j < 8; ++j) {
        int c = kg * 8 + j;
        F0[j] = fold[c];       F1[j] = fold[64 + c];  F2[j] = fold[128 + c];
        F3[j] = fold[192 + c]; F4[j] = fold[256 + c];
        c += 32;
        F0[8 + j] = fold[c];       F1[8 + j] = fold[64 + c];  F2[8 + j] = fold[128 + c];
        F3[8 + j] = fold[192 + c]; F4[8 + j] = fold[256 + c];
    }
    bf16x8 b3a, b3b;
#pragma unroll
    for (int j = 0; j < 8; ++j) {
        float va = (ln == 0) ? W3l[kg * 8 + j] : ((ln == 1) ? W3r[kg * 8 + j] : 0.f);
        float vb = (ln == 0) ? W3l[32 + kg * 8 + j] : ((ln == 1) ? W3r[32 + kg * 8 + j] : 0.f);
        b3a[j] = (short)f2bf(va);
        b3b[j] = (short)f2bf(vb);
    }

    unsigned short* Ys = lds_y[w];
    unsigned short* Zs = lds_z[w];
    const bf16x8* wfrag = (const bf16x8*)lds_w;
    int nt = (n + 15) >> 4;
    int stride = gridDim.x * 4;

#define LOADH(T, A)                                                          \
    {                                                                        \
        int row_ = ((T) << 4) + ln;                                          \
        int rr_ = (row_ < n) ? row_ : (n - 1);                               \
        A##a = ((const float2*)agg1)[rr_];                                   \
        A##x = ((const float2*)xin)[rr_];                                    \
    }

#define PROCESSH(T, A)                                                       \
    {                                                                        \
        bf16x8 u0_, u1_;                                                     \
        _Pragma("unroll")                                                    \
        for (int j = 0; j < 8; ++j) {                                        \
            float h0_ = fmaf(A##a.x, F0[j], fmaf(A##a.y, F1[j],              \
                        fmaf(A##x.x, F2[j], fmaf(A##x.y, F3[j], F4[j]))));   \
            float h1_ = fmaf(A##a.x, F0[8 + j], fmaf(A##a.y, F1[8 + j],      \
                        fmaf(A##x.x, F2[8 + j], fmaf(A##x.y, F3[8 + j], F4[8 + j])))); \
            u0_[j] = (short)f2bf(fmaxf(0.f, h0_));                           \
            u1_[j] = (short)f2bf(fmaxf(0.f, h1_));                           \
        }                                                                    \
        f32x4 ya_[4], za_[4], a3_;                                           \
        _Pragma("unroll")                                                    \
        for (int cs = 0; cs < 4; ++cs) {                                     \
            ya_[cs] = (f32x4){0.f, 0.f, 0.f, 0.f};                           \
            za_[cs] = (f32x4){0.f, 0.f, 0.f, 0.f};                           \
        }                                                                    \
        a3_ = (f32x4){0.f, 0.f, 0.f, 0.f};                                   \
        _Pragma("unroll")                                                    \
        for (int cs = 0; cs < 4; ++cs) {                                     \
            ya_[cs] = __builtin_amdgcn_mfma_f32_16x16x32_bf16(u0_, wfrag[(0 * 4 + cs) * 64 + l], ya_[cs], 0, 0, 0);  \
            ya_[cs] = __builtin_amdgcn_mfma_f32_16x16x32_bf16(u1_, wfrag[(1 * 4 + cs) * 64 + l], ya_[cs], 0, 0, 0);  \
            za_[cs] = __builtin_amdgcn_mfma_f32_16x16x32_bf16(u0_, wfrag[(8 + cs) * 64 + l], za_[cs], 0, 0, 0);      \
            za_[cs] = __builtin_amdgcn_mfma_f32_16x16x32_bf16(u1_, wfrag[(12 + cs) * 64 + l], za_[cs], 0, 0, 0);     \
        }                                                                    \
        a3_ = __builtin_amdgcn_mfma_f32_16x16x32_bf16(u0_, b3a, a3_, 0, 0, 0); \
        a3_ = __builtin_amdgcn_mfma_f32_16x16x32_bf16(u1_, b3b, a3_, 0, 0, 0); \
        _Pragma("unroll")                                                    \
        for (int cs = 0; cs < 4; ++cs) {                                     \
            _Pragma("unroll")                                                \
            for (int r = 0; r < 4; ++r) {                                    \
                Ys[(kg * 4 + r) * LROW + cs * 16 + ln] = f2bf(ya_[cs][r]);   \
                Zs[(kg * 4 + r) * LROW + cs * 16 + ln] = f2bf(za_[cs][r] + bb[cs]); \
            }                                                                \
        }                                                                    \
        int base_ = (T) << 4;                                                \
        if (ln < 2) {                                                        \
            float* d3_ = (ln == 0) ? t1 : v1;                                \
            _Pragma("unroll")                                                \
            for (int r = 0; r < 4; ++r) {                                    \
                int row_ = base_ + kg * 4 + r;                               \
                if (row_ < n) d3_[row_] = a3_[r];                            \
            }                                                                \
        }                                                                    \
        asm volatile("s_waitcnt lgkmcnt(0)" ::: "memory");                   \
        int orow_ = l >> 2, oc_ = (l & 3) * 16;                              \
        if (base_ + orow_ < n) {                                             \
            const bf16x8* yp_ = (const bf16x8*)(Ys + orow_ * LROW + oc_);    \
            const bf16x8* zp_ = (const bf16x8*)(Zs + orow_ * LROW + oc_);    \
            bf16x8* yd_ = (bf16x8*)(y + (size_t)(base_ + orow_) * 64 + oc_); \
            bf16x8* zd_ = (bf16x8*)(z + (size_t)(base_ + orow_) * 64 + oc_); \
            yd_[0] = yp_[0]; yd_[1] = yp_[1];                                \
            zd_[0] = zp_[0]; zd_[1] = zp_[1];                                \
        }                                                                    \
        asm volatile("s_waitcnt lgkmcnt(0)" ::: "memory");                   \
    }

    float2 Pa, Px, Qa, Qx;
    int t = blockIdx.x * 4 + w;
    if (t < nt) {
        LOADH(t, P);
        while (t < nt) {
            int t1_ = t + stride;
            if (t1_ < nt) LOADH(t1_, Q);
            PROCESSH(t, P);
            int t2_ = t1_ + stride;
            if (t2_ < nt) LOADH(t2_, P);
            if (t1_ < nt) PROCESSH(t1_, Q);
            t = t2_;
        }
    }
#undef LOADH
#undef PROCESSH
}

// ---------------------------------------------------------------------------
// Gather + combine: h2_i = mean_j y[src_j] + z_i (z holds +b2), in place on z.
// 8-lane groups, grid-stride (2048 blocks, round-12 proven). ATOMIC-FREE
// stats: per-block partials to pstats[c][block].
__global__ __launch_bounds__(256) void k_gather2b(
    const unsigned short* __restrict__ y, const int* __restrict__ rowptr,
    const int* __restrict__ csr, unsigned short* zh2,
    float* __restrict__ pstats, int n) {
    int tid = threadIdx.x;
    int lg = tid & 7;
    int gid0 = blockIdx.x * 32 + (tid >> 3);
    int gstep = gridDim.x * 32;
    float ls[8] = {0.f, 0.f, 0.f, 0.f, 0.f, 0.f, 0.f, 0.f};
    float lq[8] = {0.f, 0.f, 0.f, 0.f, 0.f, 0.f, 0.f, 0.f};

    for (int i = gid0; i < n; i += gstep) {
        bf16x8 z8 = *(const bf16x8*)(zh2 + (size_t)i * 64 + lg * 8);  // early, in flight
        int r0 = rowptr[i], r1 = rowptr[i + 1];
        float s[8] = {0.f, 0.f, 0.f, 0.f, 0.f, 0.f, 0.f, 0.f};
        int j = r0;
        for (; j + 1 < r1; j += 2) {
            int a = csr[j], b = csr[j + 1];
            bf16x8 va = *(const bf16x8*)(y + (size_t)a * 64 + lg * 8);
            bf16x8 vb = *(const bf16x8*)(y + (size_t)b * 64 + lg * 8);
#pragma unroll
            for (int k = 0; k < 8; ++k)
                s[k] += bf2f((unsigned short)va[k]) + bf2f((unsigned short)vb[k]);
        }
        if (j < r1) {
            bf16x8 va = *(const bf16x8*)(y + (size_t)csr[j] * 64 + lg * 8);
#pragma unroll
            for (int k = 0; k < 8; ++k) s[k] += bf2f((unsigned short)va[k]);
        }
        float inv = 1.f / fmaxf((float)(r1 - r0), 1.f);
        bf16x8 hb;
#pragma unroll
        for (int k = 0; k < 8; ++k) {
            float h = fmaf(s[k], inv, bf2f((unsigned short)z8[k]));
            unsigned short b = f2bf(h);
            hb[k] = (short)b;
            float hf = bf2f(b);
            ls[k] += hf; lq[k] += hf * hf;
        }
        *(bf16x8*)(zh2 + (size_t)i * 64 + lg * 8) = hb;
    }

    // lanes sharing lg (l, l^8, ..., l^56) hold the same 8 channels
#pragma unroll
    for (int k = 0; k < 8; ++k) {
        ls[k] += __shfl_xor(ls[k], 8, 64);
        ls[k] += __shfl_xor(ls[k], 16, 64);
        ls[k] += __shfl_xor(ls[k], 32, 64);
        lq[k] += __shfl_xor(lq[k], 8, 64);
        lq[k] += __shfl_xor(lq[k], 16, 64);
        lq[k] += __shfl_xor(lq[k], 32, 64);
    }
    __shared__ float red[2][4][64];
    int w = tid >> 6;
    if ((tid & 63) < 8) {
#pragma unroll
        for (int k = 0; k < 8; ++k) {
            red[0][w][lg * 8 + k] = ls[k];
            red[1][w][lg * 8 + k] = lq[k];
        }
    }
    __syncthreads();
    if (tid < 128) {
        int c = tid & 63;
        int half = tid >> 6;
        float v = red[half][0][c] + red[half][1][c] + red[half][2][c] + red[half][3][c];
        pstats[(size_t)tid * gridDim.x + blockIdx.x] = v;
    }
}

// ---------------------------------------------------------------------------
// Finalize: t = relu(bn2(h2)).W3l + t1;  v = relu(bn2(h2)).W3r + v1.
__global__ __launch_bounds__(256) void k_finalize(
    const unsigned short* __restrict__ h2b,
    const float* __restrict__ t1, const float* __restrict__ v1,
    const float* __restrict__ coef2,
    const float* __restrict__ W3l, const float* __restrict__ W3r,
    float* __restrict__ tb, float* __restrict__ vb, int n) {
    int tid = threadIdx.x, c = tid & 63, w = tid >> 6;
    int i0 = (blockIdx.x * 4 + w) * 8;
    if (i0 >= n) return;
    float a2 = coef2[c], b2 = coef2[64 + c];
    float wl = W3l[c], wr = W3r[c];
    float tv[8], vv[8];
#pragma unroll
    for (int q = 0; q < 8; ++q) {
        int i = i0 + q; int ic = (i < n) ? i : (n - 1);
        float h2v = bf2f(h2b[(size_t)ic * 64 + c]);
        float x2v = fmaxf(0.f, fmaf(h2v, a2, b2));
        tv[q] = x2v * wl; vv[q] = x2v * wr;
    }
#pragma unroll
    for (int q = 0; q < 8; ++q) {
        float t = tv[q], v = vv[q];
#pragma unroll
        for (int o = 32; o > 0; o >>= 1) {
            t += __shfl_xor(t, o, 64);
            v += __shfl_xor(v, o, 64);
        }
        int i = i0 + q;
        if (c == 0 && i < n) { tb[i] = t + t1[i]; vb[i] = v + v1[i]; }
    }
}

// ---------------------------------------------------------------------------
__global__ void k_gather3(const float* __restrict__ tb, const float* __restrict__ vb,
                          const int* __restrict__ rowptr, const int* __restrict__ csr,
                          const float* __restrict__ b3, float* __restrict__ out, int n) {
    int i = blockIdx.x * blockDim.x + threadIdx.x;
    if (i >= n) return;
    int r0 = rowptr[i], r1 = rowptr[i + 1];
    float s = 0.f;
    int j = r0;
    for (; j + 3 < r1; j += 4)
        s += tb[csr[j]] + tb[csr[j + 1]] + tb[csr[j + 2]] + tb[csr[j + 3]];
    for (; j < r1; ++j) s += tb[csr[j]];
    float inv = 1.f / fmaxf((float)(r1 - r0), 1.f);
    out[i] = fmaf(s, inv, b3[0] + vb[i]);
}

// ---------------------------------------------------------------------------
// Workspace (4B units, N=500k, E=1.25M; cap 256 MiB = 67,108,864 units):
//   y 32N + zh2 32N + R 2N + t1 N + v1 N + rowptr N+1 + csr E
//   + bsums 2048 + pstats 128*2048 + pmom 14*2048 + small
//   = 68N + E + ~295k = ~35.5M units = 142 MB (safe)
extern "C" void kernel_launch(void* const* d_in, const int* in_sizes, int n_in,
                              void* d_out, int out_size, void* d_ws, size_t ws_size,
                              hipStream_t stream) {
    const float* x   = (const float*)d_in[0];
    const int*   ei  = (const int*)d_in[1];
    const float* W1l = (const float*)d_in[2];
    const float* b1  = (const float*)d_in[3];
    const float* W1r = (const float*)d_in[4];
    const float* g1  = (const float*)d_in[5];
    const float* be1 = (const float*)d_in[6];
    const float* W2l = (const float*)d_in[7];
    const float* b2  = (const float*)d_in[8];
    const float* W2r = (const float*)d_in[9];
    const float* g2  = (const float*)d_in[10];
    const float* be2 = (const float*)d_in[11];
    const float* W3l = (const float*)d_in[12];
    const float* b3  = (const float*)d_in[13];
    const float* W3r = (const float*)d_in[14];

    int N = in_sizes[0] / 2;
    int E = in_sizes[1] / 2;

    float* ws   = (float*)d_ws;
    size_t nn   = (size_t)N;
    unsigned short* y   = (unsigned short*)ws;             // 32N units
    unsigned short* zh2 = (unsigned short*)(ws + 32 * nn); // 32N units (z -> h2)
    float* R     = ws + 64 * nn;            // 2N time-shared: cursor -> agg1 -> tb/vb
    int*   cursor = (int*)R;
    float* agg1   = R;
    float* tb     = R;
    float* vb     = R + nn;
    float* t1     = ws + 66 * nn;           // N
    float* v1     = ws + 67 * nn;           // N
    int*   rowptr = (int*)(ws + 68 * nn);   // N+1 (doubles as histogram cnt)
    int*   csr    = rowptr + (N + 1);       // E
    int*   bsums  = csr + E;                // 2048
    float* pstats = (float*)(bsums + 2048); // 128 * 2048 partial stats
    float* pmom   = pstats + 128 * 2048;    // 14 * 2048 partial moments
    float* stats2 = pmom + 14 * 2048;       // 128: s2 | q2
    float* coef2  = stats2 + 128;           // 128: a2, b2
    float* fold   = coef2 + 128;            // 320: F0..F4
    int*   flag   = (int*)(fold + 320);     // 64

    hipMemsetAsync(rowptr, 0, (size_t)(N + 1) * sizeof(int), stream);

    k_detect<<<1, 1, 0, stream>>>(ei, flag);

    int ge = (E + 255) / 256;
    int gn = (N + 255) / 256;
    int nb = (N + 1023) / 1024;
    k_hist<<<ge, 256, 0, stream>>>(ei, flag, E, rowptr);
    k_scanA<<<nb, 256, 0, stream>>>(rowptr, N, bsums);
    k_scanB<<<1, 256, 0, stream>>>(bsums, nb, rowptr, N);
    k_scanC<<<nb, 256, 0, stream>>>(rowptr, N, bsums, cursor);
    k_fill<<<ge, 256, 0, stream>>>(ei, flag, E, cursor, csr);
    // cursor dead; R becomes agg1

    k_gather1m<<<gn, 256, 0, stream>>>(x, rowptr, csr, agg1, pmom, N);
    k_bnfold1<<<1, 256, 0, stream>>>(pmom, gn, W1l, b1, W1r, g1, be1, fold,
                                     1.0f / (float)N);

    k_dense_pre<<<2048, 256, 0, stream>>>(agg1, x, fold, W2l, b2, W2r, W3l, W3r,
                                          y, zh2, t1, v1, N);
    // agg1 dead after dense_pre

    k_gather2b<<<2048, 256, 0, stream>>>(y, rowptr, csr, zh2, pstats, N);
    k_sreduce<<<128, 256, 0, stream>>>(pstats, 2048, stats2);
    k_bnfin<<<1, 64, 0, stream>>>(stats2, g2, be2, coef2, 1.0f / (float)N);

    // R becomes tb/vb
    k_finalize<<<(N + 31) / 32, 256, 0, stream>>>(zh2, t1, v1, coef2,
                                                  W3l, W3r, tb, vb, N);
    k_gather3<<<gn, 256, 0, stream>>>(tb, vb, rowptr, csr, b3, (float*)d_out, N);
}

// Round 15
// 389.699 us; speedup vs baseline: 2.2129x; 1.0637x over previous
//
#include <hip/hip_runtime.h>

#define EPS 1e-5f

typedef __attribute__((ext_vector_type(8))) short bf16x8;
typedef __attribute__((ext_vector_type(4))) float f32x4;

__device__ __forceinline__ unsigned short f2bf(float f) {
    unsigned u = __float_as_uint(f);
    u += 0x7fffu + ((u >> 16) & 1u);
    return (unsigned short)(u >> 16);
}
__device__ __forceinline__ float bf2f(unsigned short s) {
    return __uint_as_float(((unsigned)s) << 16);
}

// ---------------------------------------------------------------------------
__global__ void k_detect(const int* __restrict__ ei, int* __restrict__ flag) {
    if (blockIdx.x == 0 && threadIdx.x == 0) {
        int is64 = 1;
        for (int k = 0; k < 16; ++k) is64 &= (ei[2 * k + 1] == 0) ? 1 : 0;
        *flag = is64;
    }
}

// ---------------------------------------------------------------------------
// CSR build: histogram -> exclusive scan -> range-partitioned fill
__global__ void k_hist(const int* __restrict__ ei, const int* __restrict__ flag,
                       int E, int* __restrict__ cnt) {
    int e = blockIdx.x * blockDim.x + threadIdx.x;
    if (e >= E) return;
    int d = (*flag) ? (int)((const long long*)ei)[E + e] : ei[E + e];
    atomicAdd(&cnt[d], 1);
}

__device__ __forceinline__ int block_incl_scan(int v, int tid, int* total) {
    __shared__ int wsum[4];
    __shared__ int tot;
#pragma unroll
    for (int o = 1; o < 64; o <<= 1) {
        int u = __shfl_up(v, o, 64);
        if ((tid & 63) >= o) v += u;
    }
    if ((tid & 63) == 63) wsum[tid >> 6] = v;
    __syncthreads();
    int w = tid >> 6, add = 0;
    if (w > 0) add += wsum[0];
    if (w > 1) add += wsum[1];
    if (w > 2) add += wsum[2];
    v += add;
    if (tid == 255) tot = v;
    __syncthreads();
    *total = tot;
    __syncthreads();
    return v;
}

__global__ __launch_bounds__(256) void k_scanA(const int* __restrict__ cnt, int n,
                                               int* __restrict__ bsums) {
    int tid = threadIdx.x;
    int idx = blockIdx.x * 1024 + tid * 4;
    int s = 0;
#pragma unroll
    for (int k = 0; k < 4; ++k) { int i = idx + k; if (i < n) s += cnt[i]; }
#pragma unroll
    for (int o = 32; o > 0; o >>= 1) s += __shfl_xor(s, o, 64);
    __shared__ int ws[4];
    if ((tid & 63) == 0) ws[tid >> 6] = s;
    __syncthreads();
    if (tid == 0) bsums[blockIdx.x] = ws[0] + ws[1] + ws[2] + ws[3];
}

__global__ __launch_bounds__(256) void k_scanB(int* __restrict__ bsums, int nb,
                                               int* __restrict__ rowptr, int N) {
    int tid = threadIdx.x;
    __shared__ int sh_carry;
    if (tid == 0) sh_carry = 0;
    __syncthreads();
    int niter = (nb + 255) / 256;
    for (int it = 0; it < niter; ++it) {
        int i = it * 256 + tid;
        int v = (i < nb) ? bsums[i] : 0;
        int tot;
        int inc = block_incl_scan(v, tid, &tot);
        int carry = sh_carry;
        if (i < nb) bsums[i] = carry + inc - v;
        __syncthreads();
        if (tid == 0) sh_carry = carry + tot;
        __syncthreads();
    }
    if (tid == 0) rowptr[N] = sh_carry;
}

__global__ __launch_bounds__(256) void k_scanC(int* __restrict__ cnt_rowptr, int n,
                                               const int* __restrict__ bsums,
                                               int* __restrict__ cursor) {
    int tid = threadIdx.x;
    int idx = blockIdx.x * 1024 + tid * 4;
    int v[4]; int s = 0;
#pragma unroll
    for (int k = 0; k < 4; ++k) { int i = idx + k; v[k] = (i < n) ? cnt_rowptr[i] : 0; s += v[k]; }
    int tot;
    int inc = block_incl_scan(s, tid, &tot);
    int off = bsums[blockIdx.x] + inc - s;
#pragma unroll
    for (int k = 0; k < 4; ++k) {
        int i = idx + k;
        if (i < n) { cnt_rowptr[i] = off; cursor[i] = off; off += v[k]; }
    }
}

// Range-partitioned fill: pass handles dst in [lo, hi). The csr region touched
// per pass (~E/NPASS entries) is L2-resident -> scattered 4B stores merge into
// full lines before writeback (kills the 16x write amplification seen in the
// single-pass fill: WRITE_SIZE 87.7MB for 7MB logical).
__global__ void k_fill_range(const int* __restrict__ ei, const int* __restrict__ flag,
                             int E, int* __restrict__ cursor, int* __restrict__ csr,
                             int lo, int hi) {
    int e = blockIdx.x * blockDim.x + threadIdx.x;
    if (e >= E) return;
    int f = *flag;
    int d = f ? (int)((const long long*)ei)[E + e] : ei[E + e];
    if (d < lo || d >= hi) return;
    int s = f ? (int)((const long long*)ei)[e] : ei[e];
    int pos = atomicAdd(&cursor[d], 1);
    csr[pos] = s;
}

// ---------------------------------------------------------------------------
// Layer-1 gather fused with u-moments (u = (agg1, x), 14 scalars).
// ATOMIC-FREE stats: per-block partials to pmom[k][block].
__global__ __launch_bounds__(256) void k_gather1m(
    const float* __restrict__ x, const int* __restrict__ rowptr,
    const int* __restrict__ csr, float* __restrict__ agg1,
    float* __restrict__ pmom, int n) {
    int tid = threadIdx.x;
    int i = blockIdx.x * 256 + tid;
    float m[14];
#pragma unroll
    for (int k = 0; k < 14; ++k) m[k] = 0.f;
    if (i < n) {
        int r0 = rowptr[i], r1 = rowptr[i + 1];
        float s0 = 0.f, s1 = 0.f;
        int j = r0;
        for (; j + 3 < r1; j += 4) {
            float2 v0 = ((const float2*)x)[csr[j]];
            float2 v1 = ((const float2*)x)[csr[j + 1]];
            float2 v2 = ((const float2*)x)[csr[j + 2]];
            float2 v3 = ((const float2*)x)[csr[j + 3]];
            s0 += v0.x + v1.x + v2.x + v3.x;
            s1 += v0.y + v1.y + v2.y + v3.y;
        }
        for (; j < r1; ++j) {
            float2 v = ((const float2*)x)[csr[j]];
            s0 += v.x; s1 += v.y;
        }
        float inv = 1.f / fmaxf((float)(r1 - r0), 1.f);
        float ax = s0 * inv, ay = s1 * inv;
        agg1[2 * i] = ax;
        agg1[2 * i + 1] = ay;
        float2 xv = ((const float2*)x)[i];
        m[0] = ax;        m[1] = ay;        m[2] = xv.x;      m[3] = xv.y;
        m[4] = ax * ax;   m[5] = ax * ay;   m[6] = ax * xv.x; m[7] = ax * xv.y;
        m[8] = ay * ay;   m[9] = ay * xv.x; m[10] = ay * xv.y;
        m[11] = xv.x * xv.x; m[12] = xv.x * xv.y; m[13] = xv.y * xv.y;
    }
#pragma unroll
    for (int k = 0; k < 14; ++k) {
#pragma unroll
        for (int o = 32; o > 0; o >>= 1) m[k] += __shfl_xor(m[k], o, 64);
    }
    __shared__ float red[4][14];
    int w = tid >> 6;
    if ((tid & 63) == 0) {
#pragma unroll
        for (int k = 0; k < 14; ++k) red[w][k] = m[k];
    }
    __syncthreads();
    if (tid < 14)
        pmom[(size_t)tid * gridDim.x + blockIdx.x] =
            red[0][tid] + red[1][tid] + red[2][tid] + red[3][tid];
}

// ---------------------------------------------------------------------------
// Reduce pmom partials + BN1-fold (1 block x 256).
__global__ __launch_bounds__(256) void k_bnfold1(
    const float* __restrict__ pmom, int gn,
    const float* __restrict__ W1l, const float* __restrict__ b1,
    const float* __restrict__ W1r,
    const float* __restrict__ g1, const float* __restrict__ be1,
    float* __restrict__ fold, float invN) {
    int tid = threadIdx.x;
    __shared__ float smom[14];
    __shared__ float ws[4];
    for (int k = 0; k < 14; ++k) {
        float s = 0.f;
        for (int idx = tid; idx < gn; idx += 256) s += pmom[(size_t)k * gn + idx];
#pragma unroll
        for (int o = 32; o > 0; o >>= 1) s += __shfl_xor(s, o, 64);
        if ((tid & 63) == 0) ws[tid >> 6] = s;
        __syncthreads();
        if (tid == 0) smom[k] = ws[0] + ws[1] + ws[2] + ws[3];
        __syncthreads();
    }
    if (tid < 64) {
        int c = tid;
        float w0 = W1l[c], w1 = W1l[64 + c], w2 = W1r[c], w3 = W1r[64 + c], w4 = b1[c];
        float lin = (smom[0] * w0 + smom[1] * w1 + smom[2] * w2 + smom[3] * w3) * invN;
        float mean = lin + w4;
        float q = smom[4] * w0 * w0 + smom[8] * w1 * w1 + smom[11] * w2 * w2 + smom[13] * w3 * w3
                + 2.f * (smom[5] * w0 * w1 + smom[6] * w0 * w2 + smom[7] * w0 * w3
                       + smom[9] * w1 * w2 + smom[10] * w1 * w3 + smom[12] * w2 * w3);
        float Eh2 = q * invN + 2.f * w4 * lin + w4 * w4;
        float var = Eh2 - mean * mean;
        float al = g1[c] * rsqrtf(var + EPS);
        float be = be1[c] - mean * al;
        fold[c]       = al * w0;
        fold[64 + c]  = al * w1;
        fold[128 + c] = al * w2;
        fold[192 + c] = al * w3;
        fold[256 + c] = al * w4 + be;
    }
}

// ---------------------------------------------------------------------------
// Reduce pstats[c][nb] -> stats2[c]  (c = 0..127; grid = 128 blocks)
__global__ __launch_bounds__(256) void k_sreduce(const float* __restrict__ pstats,
                                                 int nb, float* __restrict__ stats2) {
    int c = blockIdx.x, tid = threadIdx.x;
    float s = 0.f;
    for (int i = tid; i < nb; i += 256) s += pstats[(size_t)c * nb + i];
#pragma unroll
    for (int o = 32; o > 0; o >>= 1) s += __shfl_xor(s, o, 64);
    __shared__ float ws[4];
    if ((tid & 63) == 0) ws[tid >> 6] = s;
    __syncthreads();
    if (tid == 0) stats2[c] = ws[0] + ws[1] + ws[2] + ws[3];
}

__global__ void k_bnfin(const float* __restrict__ stats, const float* __restrict__ g,
                        const float* __restrict__ be, float* __restrict__ coef, float invN) {
    int c = threadIdx.x;
    float m = stats[c] * invN;
    float var = stats[64 + c] * invN - m * m;
    float a = g[c] * rsqrtf(var + EPS);
    coef[c] = a;
    coef[64 + c] = be[c] - m * a;
}

// ---------------------------------------------------------------------------
// Pre-transform: x1 = relu(bn1-folded(agg1, x)) on the fly; y = x1@W2l;
// z = x1@W2r + b2; t1 = x1.W3l; v1 = x1.W3r. LDS out-stage -> full-line stores.
#define LROW 72  // LDS row stride in shorts

__global__ __launch_bounds__(256) void k_dense_pre(
    const float* __restrict__ agg1, const float* __restrict__ xin,
    const float* __restrict__ fold,
    const float* __restrict__ W2l, const float* __restrict__ b2,
    const float* __restrict__ W2r,
    const float* __restrict__ W3l, const float* __restrict__ W3r,
    unsigned short* __restrict__ y, unsigned short* __restrict__ z,
    float* __restrict__ t1, float* __restrict__ v1, int n) {
    __shared__ unsigned short lds_w[16 * 64 * 8];                 // 16 KB
    __shared__ __align__(16) unsigned short lds_y[4][16 * LROW];
    __shared__ __align__(16) unsigned short lds_z[4][16 * LROW];
    int tid = threadIdx.x, w = tid >> 6, l = tid & 63, ln = l & 15, kg = l >> 4;

    for (int idx = tid; idx < 4096; idx += 256) {
        int k = idx >> 6, c = idx & 63;
        int lane = ((k >> 3) & 3) * 16 + (c & 15);
        int fbase = ((k >> 5) * 4 + (c >> 4)) * 64 + lane;
        lds_w[fbase * 8 + (k & 7)] = f2bf(W2l[idx]);
        lds_w[(8 * 64 + fbase) * 8 + (k & 7)] = f2bf(W2r[idx]);
    }
    __syncthreads();

    float bb[4];
#pragma unroll
    for (int cs = 0; cs < 4; ++cs) bb[cs] = b2[cs * 16 + ln];

    float F0[16], F1[16], F2[16], F3[16], F4[16];
#pragma unroll
    for (int j = 0; j < 8; ++j) {
        int c = kg * 8 + j;
        F0[j] = fold[c];       F1[j] = fold[64 + c];  F2[j] = fold[128 + c];
        F3[j] = fold[192 + c]; F4[j] = fold[256 + c];
        c += 32;
        F0[8 + j] = fold[c];       F1[8 + j] = fold[64 + c];  F2[8 + j] = fold[128 + c];
        F3[8 + j] = fold[192 + c]; F4[8 + j] = fold[256 + c];
    }
    bf16x8 b3a, b3b;
#pragma unroll
    for (int j = 0; j < 8; ++j) {
        float va = (ln == 0) ? W3l[kg * 8 + j] : ((ln == 1) ? W3r[kg * 8 + j] : 0.f);
        float vb = (ln == 0) ? W3l[32 + kg * 8 + j] : ((ln == 1) ? W3r[32 + kg * 8 + j] : 0.f);
        b3a[j] = (short)f2bf(va);
        b3b[j] = (short)f2bf(vb);
    }

    unsigned short* Ys = lds_y[w];
    unsigned short* Zs = lds_z[w];
    const bf16x8* wfrag = (const bf16x8*)lds_w;
    int nt = (n + 15) >> 4;
    int stride = gridDim.x * 4;

#define LOADH(T, A)                                                          \
    {                                                                        \
        int row_ = ((T) << 4) + ln;                                          \
        int rr_ = (row_ < n) ? row_ : (n - 1);                               \
        A##a = ((const float2*)agg1)[rr_];                                   \
        A##x = ((const float2*)xin)[rr_];                                    \
    }

#define PROCESSH(T, A)                                                       \
    {                                                                        \
        bf16x8 u0_, u1_;                                                     \
        _Pragma("unroll")                                                    \
        for (int j = 0; j < 8; ++j) {                                        \
            float h0_ = fmaf(A##a.x, F0[j], fmaf(A##a.y, F1[j],              \
                        fmaf(A##x.x, F2[j], fmaf(A##x.y, F3[j], F4[j]))));   \
            float h1_ = fmaf(A##a.x, F0[8 + j], fmaf(A##a.y, F1[8 + j],      \
                        fmaf(A##x.x, F2[8 + j], fmaf(A##x.y, F3[8 + j], F4[8 + j])))); \
            u0_[j] = (short)f2bf(fmaxf(0.f, h0_));                           \
            u1_[j] = (short)f2bf(fmaxf(0.f, h1_));                           \
        }                                                                    \
        f32x4 ya_[4], za_[4], a3_;                                           \
        _Pragma("unroll")                                                    \
        for (int cs = 0; cs < 4; ++cs) {                                     \
            ya_[cs] = (f32x4){0.f, 0.f, 0.f, 0.f};                           \
            za_[cs] = (f32x4){0.f, 0.f, 0.f, 0.f};                           \
        }                                                                    \
        a3_ = (f32x4){0.f, 0.f, 0.f, 0.f};                                   \
        _Pragma("unroll")                                                    \
        for (int cs = 0; cs < 4; ++cs) {                                     \
            ya_[cs] = __builtin_amdgcn_mfma_f32_16x16x32_bf16(u0_, wfrag[(0 * 4 + cs) * 64 + l], ya_[cs], 0, 0, 0);  \
            ya_[cs] = __builtin_amdgcn_mfma_f32_16x16x32_bf16(u1_, wfrag[(1 * 4 + cs) * 64 + l], ya_[cs], 0, 0, 0);  \
            za_[cs] = __builtin_amdgcn_mfma_f32_16x16x32_bf16(u0_, wfrag[(8 + cs) * 64 + l], za_[cs], 0, 0, 0);      \
            za_[cs] = __builtin_amdgcn_mfma_f32_16x16x32_bf16(u1_, wfrag[(12 + cs) * 64 + l], za_[cs], 0, 0, 0);     \
        }                                                                    \
        a3_ = __builtin_amdgcn_mfma_f32_16x16x32_bf16(u0_, b3a, a3_, 0, 0, 0); \
        a3_ = __builtin_amdgcn_mfma_f32_16x16x32_bf16(u1_, b3b, a3_, 0, 0, 0); \
        _Pragma("unroll")                                                    \
        for (int cs = 0; cs < 4; ++cs) {                                     \
            _Pragma("unroll")                                                \
            for (int r = 0; r < 4; ++r) {                                    \
                Ys[(kg * 4 + r) * LROW + cs * 16 + ln] = f2bf(ya_[cs][r]);   \
                Zs[(kg * 4 + r) * LROW + cs * 16 + ln] = f2bf(za_[cs][r] + bb[cs]); \
            }                                                                \
        }                                                                    \
        int base_ = (T) << 4;                                                \
        if (ln < 2) {                                                        \
            float* d3_ = (ln == 0) ? t1 : v1;                                \
            _Pragma("unroll")                                                \
            for (int r = 0; r < 4; ++r) {                                    \
                int row_ = base_ + kg * 4 + r;                               \
                if (row_ < n) d3_[row_] = a3_[r];                            \
            }                                                                \
        }                                                                    \
        asm volatile("s_waitcnt lgkmcnt(0)" ::: "memory");                   \
        int orow_ = l >> 2, oc_ = (l & 3) * 16;                              \
        if (base_ + orow_ < n) {                                             \
            const bf16x8* yp_ = (const bf16x8*)(Ys + orow_ * LROW + oc_);    \
            const bf16x8* zp_ = (const bf16x8*)(Zs + orow_ * LROW + oc_);    \
            bf16x8* yd_ = (bf16x8*)(y + (size_t)(base_ + orow_) * 64 + oc_); \
            bf16x8* zd_ = (bf16x8*)(z + (size_t)(base_ + orow_) * 64 + oc_); \
            yd_[0] = yp_[0]; yd_[1] = yp_[1];                                \
            zd_[0] = zp_[0]; zd_[1] = zp_[1];                                \
        }                                                                    \
        asm volatile("s_waitcnt lgkmcnt(0)" ::: "memory");                   \
    }

    float2 Pa, Px, Qa, Qx;
    int t = blockIdx.x * 4 + w;
    if (t < nt) {
        LOADH(t, P);
        while (t < nt) {
            int t1_ = t + stride;
            if (t1_ < nt) LOADH(t1_, Q);
            PROCESSH(t, P);
            int t2_ = t1_ + stride;
            if (t2_ < nt) LOADH(t2_, P);
            if (t1_ < nt) PROCESSH(t1_, Q);
            t = t2_;
        }
    }
#undef LOADH
#undef PROCESSH
}

// ---------------------------------------------------------------------------
// Gather + combine: h2_i = mean_j y[src_j] + z_i (z holds +b2), in place on z.
// 8-lane groups, grid-stride (2048 blocks). ATOMIC-FREE stats partials.
__global__ __launch_bounds__(256) void k_gather2b(
    const unsigned short* __restrict__ y, const int* __restrict__ rowptr,
    const int* __restrict__ csr, unsigned short* zh2,
    float* __restrict__ pstats, int n) {
    int tid = threadIdx.x;
    int lg = tid & 7;
    int gid0 = blockIdx.x * 32 + (tid >> 3);
    int gstep = gridDim.x * 32;
    float ls[8] = {0.f, 0.f, 0.f, 0.f, 0.f, 0.f, 0.f, 0.f};
    float lq[8] = {0.f, 0.f, 0.f, 0.f, 0.f, 0.f, 0.f, 0.f};

    for (int i = gid0; i < n; i += gstep) {
        bf16x8 z8 = *(const bf16x8*)(zh2 + (size_t)i * 64 + lg * 8);  // early, in flight
        int r0 = rowptr[i], r1 = rowptr[i + 1];
        float s[8] = {0.f, 0.f, 0.f, 0.f, 0.f, 0.f, 0.f, 0.f};
        int j = r0;
        for (; j + 1 < r1; j += 2) {
            int a = csr[j], b = csr[j + 1];
            bf16x8 va = *(const bf16x8*)(y + (size_t)a * 64 + lg * 8);
            bf16x8 vb = *(const bf16x8*)(y + (size_t)b * 64 + lg * 8);
#pragma unroll
            for (int k = 0; k < 8; ++k)
                s[k] += bf2f((unsigned short)va[k]) + bf2f((unsigned short)vb[k]);
        }
        if (j < r1) {
            bf16x8 va = *(const bf16x8*)(y + (size_t)csr[j] * 64 + lg * 8);
#pragma unroll
            for (int k = 0; k < 8; ++k) s[k] += bf2f((unsigned short)va[k]);
        }
        float inv = 1.f / fmaxf((float)(r1 - r0), 1.f);
        bf16x8 hb;
#pragma unroll
        for (int k = 0; k < 8; ++k) {
            float h = fmaf(s[k], inv, bf2f((unsigned short)z8[k]));
            unsigned short b = f2bf(h);
            hb[k] = (short)b;
            float hf = bf2f(b);
            ls[k] += hf; lq[k] += hf * hf;
        }
        *(bf16x8*)(zh2 + (size_t)i * 64 + lg * 8) = hb;
    }

#pragma unroll
    for (int k = 0; k < 8; ++k) {
        ls[k] += __shfl_xor(ls[k], 8, 64);
        ls[k] += __shfl_xor(ls[k], 16, 64);
        ls[k] += __shfl_xor(ls[k], 32, 64);
        lq[k] += __shfl_xor(lq[k], 8, 64);
        lq[k] += __shfl_xor(lq[k], 16, 64);
        lq[k] += __shfl_xor(lq[k], 32, 64);
    }
    __shared__ float red[2][4][64];
    int w = tid >> 6;
    if ((tid & 63) < 8) {
#pragma unroll
        for (int k = 0; k < 8; ++k) {
            red[0][w][lg * 8 + k] = ls[k];
            red[1][w][lg * 8 + k] = lq[k];
        }
    }
    __syncthreads();
    if (tid < 128) {
        int c = tid & 63;
        int half = tid >> 6;
        float v = red[half][0][c] + red[half][1][c] + red[half][2][c] + red[half][3][c];
        pstats[(size_t)tid * gridDim.x + blockIdx.x] = v;
    }
}

// ---------------------------------------------------------------------------
// Finalize: t = relu(bn2(h2)).W3l + t1;  v = relu(bn2(h2)).W3r + v1.
__global__ __launch_bounds__(256) void k_finalize(
    const unsigned short* __restrict__ h2b,
    const float* __restrict__ t1, const float* __restrict__ v1,
    const float* __restrict__ coef2,
    const float* __restrict__ W3l, const float* __restrict__ W3r,
    float* __restrict__ tb, float* __restrict__ vb, int n) {
    int tid = threadIdx.x, c = tid & 63, w = tid >> 6;
    int i0 = (blockIdx.x * 4 + w) * 8;
    if (i0 >= n) return;
    float a2 = coef2[c], b2 = coef2[64 + c];
    float wl = W3l[c], wr = W3r[c];
    float tv[8], vv[8];
#pragma unroll
    for (int q = 0; q < 8; ++q) {
        int i = i0 + q; int ic = (i < n) ? i : (n - 1);
        float h2v = bf2f(h2b[(size_t)ic * 64 + c]);
        float x2v = fmaxf(0.f, fmaf(h2v, a2, b2));
        tv[q] = x2v * wl; vv[q] = x2v * wr;
    }
#pragma unroll
    for (int q = 0; q < 8; ++q) {
        float t = tv[q], v = vv[q];
#pragma unroll
        for (int o = 32; o > 0; o >>= 1) {
            t += __shfl_xor(t, o, 64);
            v += __shfl_xor(v, o, 64);
        }
        int i = i0 + q;
        if (c == 0 && i < n) { tb[i] = t + t1[i]; vb[i] = v + v1[i]; }
    }
}

// ---------------------------------------------------------------------------
__global__ void k_gather3(const float* __restrict__ tb, const float* __restrict__ vb,
                          const int* __restrict__ rowptr, const int* __restrict__ csr,
                          const float* __restrict__ b3, float* __restrict__ out, int n) {
    int i = blockIdx.x * blockDim.x + threadIdx.x;
    if (i >= n) return;
    int r0 = rowptr[i], r1 = rowptr[i + 1];
    float s = 0.f;
    int j = r0;
    for (; j + 3 < r1; j += 4)
        s += tb[csr[j]] + tb[csr[j + 1]] + tb[csr[j + 2]] + tb[csr[j + 3]];
    for (; j < r1; ++j) s += tb[csr[j]];
    float inv = 1.f / fmaxf((float)(r1 - r0), 1.f);
    out[i] = fmaf(s, inv, b3[0] + vb[i]);
}

// ---------------------------------------------------------------------------
// Workspace (4B units, N=500k, E=1.25M; cap 256 MiB = 67,108,864 units):
//   y 32N + zh2 32N + R 2N + t1 N + v1 N + rowptr N+1 + csr E
//   + bsums 2048 + pstats 128*2048 + pmom 14*2048 + small
//   = 68N + E + ~295k = ~35.5M units = 142 MB (safe)
extern "C" void kernel_launch(void* const* d_in, const int* in_sizes, int n_in,
                              void* d_out, int out_size, void* d_ws, size_t ws_size,
                              hipStream_t stream) {
    const float* x   = (const float*)d_in[0];
    const int*   ei  = (const int*)d_in[1];
    const float* W1l = (const float*)d_in[2];
    const float* b1  = (const float*)d_in[3];
    const float* W1r = (const float*)d_in[4];
    const float* g1  = (const float*)d_in[5];
    const float* be1 = (const float*)d_in[6];
    const float* W2l = (const float*)d_in[7];
    const float* b2  = (const float*)d_in[8];
    const float* W2r = (const float*)d_in[9];
    const float* g2  = (const float*)d_in[10];
    const float* be2 = (const float*)d_in[11];
    const float* W3l = (const float*)d_in[12];
    const float* b3  = (const float*)d_in[13];
    const float* W3r = (const float*)d_in[14];

    int N = in_sizes[0] / 2;
    int E = in_sizes[1] / 2;

    float* ws   = (float*)d_ws;
    size_t nn   = (size_t)N;
    unsigned short* y   = (unsigned short*)ws;             // 32N units
    unsigned short* zh2 = (unsigned short*)(ws + 32 * nn); // 32N units (z -> h2)
    float* R     = ws + 64 * nn;            // 2N time-shared: cursor -> agg1 -> tb/vb
    int*   cursor = (int*)R;
    float* agg1   = R;
    float* tb     = R;
    float* vb     = R + nn;
    float* t1     = ws + 66 * nn;           // N
    float* v1     = ws + 67 * nn;           // N
    int*   rowptr = (int*)(ws + 68 * nn);   // N+1 (doubles as histogram cnt)
    int*   csr    = rowptr + (N + 1);       // E
    int*   bsums  = csr + E;                // 2048
    float* pstats = (float*)(bsums + 2048); // 128 * 2048 partial stats
    float* pmom   = pstats + 128 * 2048;    // 14 * 2048 partial moments
    float* stats2 = pmom + 14 * 2048;       // 128: s2 | q2
    float* coef2  = stats2 + 128;           // 128: a2, b2
    float* fold   = coef2 + 128;            // 320: F0..F4
    int*   flag   = (int*)(fold + 320);     // 64

    hipMemsetAsync(rowptr, 0, (size_t)(N + 1) * sizeof(int), stream);

    k_detect<<<1, 1, 0, stream>>>(ei, flag);

    int ge = (E + 255) / 256;
    int gn = (N + 255) / 256;
    int nb = (N + 1023) / 1024;
    k_hist<<<ge, 256, 0, stream>>>(ei, flag, E, rowptr);
    k_scanA<<<nb, 256, 0, stream>>>(rowptr, N, bsums);
    k_scanB<<<1, 256, 0, stream>>>(bsums, nb, rowptr, N);
    k_scanC<<<nb, 256, 0, stream>>>(rowptr, N, bsums, cursor);
    // Range-partitioned fill: 4 passes, each pass's csr/cursor region L2-fits.
    {
        const int NPASS = 4;
        int span = (N + NPASS - 1) / NPASS;
        for (int p = 0; p < NPASS; ++p) {
            int lo = p * span;
            int hi = min(N, lo + span);
            k_fill_range<<<ge, 256, 0, stream>>>(ei, flag, E, cursor, csr, lo, hi);
        }
    }
    // cursor dead; R becomes agg1

    k_gather1m<<<gn, 256, 0, stream>>>(x, rowptr, csr, agg1, pmom, N);
    k_bnfold1<<<1, 256, 0, stream>>>(pmom, gn, W1l, b1, W1r, g1, be1, fold,
                                     1.0f / (float)N);

    k_dense_pre<<<2048, 256, 0, stream>>>(agg1, x, fold, W2l, b2, W2r, W3l, W3r,
                                          y, zh2, t1, v1, N);
    // agg1 dead after dense_pre

    k_gather2b<<<2048, 256, 0, stream>>>(y, rowptr, csr, zh2, pstats, N);
    k_sreduce<<<128, 256, 0, stream>>>(pstats, 2048, stats2);
    k_bnfin<<<1, 64, 0, stream>>>(stats2, g2, be2, coef2, 1.0f / (float)N);

    // R becomes tb/vb
    k_finalize<<<(N + 31) / 32, 256, 0, stream>>>(zh2, t1, v1, coef2,
                                                  W3l, W3r, tb, vb, N);
    k_gather3<<<gn, 256, 0, stream>>>(tb, vb, rowptr, csr, b3, (float*)d_out, N);
}

// Round 16
// 361.033 us; speedup vs baseline: 2.3886x; 1.0794x over previous
//
#include <hip/hip_runtime.h>

#define EPS 1e-5f

typedef __attribute__((ext_vector_type(8))) short bf16x8;
typedef __attribute__((ext_vector_type(4))) float f32x4;

__device__ __forceinline__ unsigned short f2bf(float f) {
    unsigned u = __float_as_uint(f);
    u += 0x7fffu + ((u >> 16) & 1u);
    return (unsigned short)(u >> 16);
}
__device__ __forceinline__ float bf2f(unsigned short s) {
    return __uint_as_float(((unsigned)s) << 16);
}

// ---------------------------------------------------------------------------
__global__ void k_detect(const int* __restrict__ ei, int* __restrict__ flag) {
    if (blockIdx.x == 0 && threadIdx.x == 0) {
        int is64 = 1;
        for (int k = 0; k < 16; ++k) is64 &= (ei[2 * k + 1] == 0) ? 1 : 0;
        *flag = is64;
    }
}

// ---------------------------------------------------------------------------
// CSR build: histogram -> exclusive scan -> range-partitioned fill
__global__ void k_hist(const int* __restrict__ ei, const int* __restrict__ flag,
                       int E, int* __restrict__ cnt) {
    int e = blockIdx.x * blockDim.x + threadIdx.x;
    if (e >= E) return;
    int d = (*flag) ? (int)((const long long*)ei)[E + e] : ei[E + e];
    atomicAdd(&cnt[d], 1);
}

__device__ __forceinline__ int block_incl_scan(int v, int tid, int* total) {
    __shared__ int wsum[4];
    __shared__ int tot;
#pragma unroll
    for (int o = 1; o < 64; o <<= 1) {
        int u = __shfl_up(v, o, 64);
        if ((tid & 63) >= o) v += u;
    }
    if ((tid & 63) == 63) wsum[tid >> 6] = v;
    __syncthreads();
    int w = tid >> 6, add = 0;
    if (w > 0) add += wsum[0];
    if (w > 1) add += wsum[1];
    if (w > 2) add += wsum[2];
    v += add;
    if (tid == 255) tot = v;
    __syncthreads();
    *total = tot;
    __syncthreads();
    return v;
}

__global__ __launch_bounds__(256) void k_scanA(const int* __restrict__ cnt, int n,
                                               int* __restrict__ bsums) {
    int tid = threadIdx.x;
    int idx = blockIdx.x * 1024 + tid * 4;
    int s = 0;
#pragma unroll
    for (int k = 0; k < 4; ++k) { int i = idx + k; if (i < n) s += cnt[i]; }
#pragma unroll
    for (int o = 32; o > 0; o >>= 1) s += __shfl_xor(s, o, 64);
    __shared__ int ws[4];
    if ((tid & 63) == 0) ws[tid >> 6] = s;
    __syncthreads();
    if (tid == 0) bsums[blockIdx.x] = ws[0] + ws[1] + ws[2] + ws[3];
}

__global__ __launch_bounds__(256) void k_scanB(int* __restrict__ bsums, int nb,
                                               int* __restrict__ rowptr, int N) {
    int tid = threadIdx.x;
    __shared__ int sh_carry;
    if (tid == 0) sh_carry = 0;
    __syncthreads();
    int niter = (nb + 255) / 256;
    for (int it = 0; it < niter; ++it) {
        int i = it * 256 + tid;
        int v = (i < nb) ? bsums[i] : 0;
        int tot;
        int inc = block_incl_scan(v, tid, &tot);
        int carry = sh_carry;
        if (i < nb) bsums[i] = carry + inc - v;
        __syncthreads();
        if (tid == 0) sh_carry = carry + tot;
        __syncthreads();
    }
    if (tid == 0) rowptr[N] = sh_carry;
}

__global__ __launch_bounds__(256) void k_scanC(int* __restrict__ cnt_rowptr, int n,
                                               const int* __restrict__ bsums,
                                               int* __restrict__ cursor) {
    int tid = threadIdx.x;
    int idx = blockIdx.x * 1024 + tid * 4;
    int v[4]; int s = 0;
#pragma unroll
    for (int k = 0; k < 4; ++k) { int i = idx + k; v[k] = (i < n) ? cnt_rowptr[i] : 0; s += v[k]; }
    int tot;
    int inc = block_incl_scan(s, tid, &tot);
    int off = bsums[blockIdx.x] + inc - s;
#pragma unroll
    for (int k = 0; k < 4; ++k) {
        int i = idx + k;
        if (i < n) { cnt_rowptr[i] = off; cursor[i] = off; off += v[k]; }
    }
}

// Range-partitioned fill: pass handles dst in [lo, hi); per-pass csr/cursor
// region is L2-resident -> scattered 4B stores merge into full lines.
__global__ void k_fill_range(const int* __restrict__ ei, const int* __restrict__ flag,
                             int E, int* __restrict__ cursor, int* __restrict__ csr,
                             int lo, int hi) {
    int e = blockIdx.x * blockDim.x + threadIdx.x;
    if (e >= E) return;
    int f = *flag;
    int d = f ? (int)((const long long*)ei)[E + e] : ei[E + e];
    if (d < lo || d >= hi) return;
    int s = f ? (int)((const long long*)ei)[e] : ei[e];
    int pos = atomicAdd(&cursor[d], 1);
    csr[pos] = s;
}

// ---------------------------------------------------------------------------
// Layer-1 gather fused with u-moments (u = (agg1, x), 14 scalars).
// ATOMIC-FREE stats: per-block partials to pmom[k][block].
__global__ __launch_bounds__(256) void k_gather1m(
    const float* __restrict__ x, const int* __restrict__ rowptr,
    const int* __restrict__ csr, float* __restrict__ agg1,
    float* __restrict__ pmom, int n) {
    int tid = threadIdx.x;
    int i = blockIdx.x * 256 + tid;
    float m[14];
#pragma unroll
    for (int k = 0; k < 14; ++k) m[k] = 0.f;
    if (i < n) {
        int r0 = rowptr[i], r1 = rowptr[i + 1];
        float s0 = 0.f, s1 = 0.f;
        int j = r0;
        for (; j + 3 < r1; j += 4) {
            float2 v0 = ((const float2*)x)[csr[j]];
            float2 v1 = ((const float2*)x)[csr[j + 1]];
            float2 v2 = ((const float2*)x)[csr[j + 2]];
            float2 v3 = ((const float2*)x)[csr[j + 3]];
            s0 += v0.x + v1.x + v2.x + v3.x;
            s1 += v0.y + v1.y + v2.y + v3.y;
        }
        for (; j < r1; ++j) {
            float2 v = ((const float2*)x)[csr[j]];
            s0 += v.x; s1 += v.y;
        }
        float inv = 1.f / fmaxf((float)(r1 - r0), 1.f);
        float ax = s0 * inv, ay = s1 * inv;
        agg1[2 * i] = ax;
        agg1[2 * i + 1] = ay;
        float2 xv = ((const float2*)x)[i];
        m[0] = ax;        m[1] = ay;        m[2] = xv.x;      m[3] = xv.y;
        m[4] = ax * ax;   m[5] = ax * ay;   m[6] = ax * xv.x; m[7] = ax * xv.y;
        m[8] = ay * ay;   m[9] = ay * xv.x; m[10] = ay * xv.y;
        m[11] = xv.x * xv.x; m[12] = xv.x * xv.y; m[13] = xv.y * xv.y;
    }
#pragma unroll
    for (int k = 0; k < 14; ++k) {
#pragma unroll
        for (int o = 32; o > 0; o >>= 1) m[k] += __shfl_xor(m[k], o, 64);
    }
    __shared__ float red[4][14];
    int w = tid >> 6;
    if ((tid & 63) == 0) {
#pragma unroll
        for (int k = 0; k < 14; ++k) red[w][k] = m[k];
    }
    __syncthreads();
    if (tid < 14)
        pmom[(size_t)tid * gridDim.x + blockIdx.x] =
            red[0][tid] + red[1][tid] + red[2][tid] + red[3][tid];
}

// ---------------------------------------------------------------------------
// Reduce pmom partials + BN1-fold (1 block x 256).
__global__ __launch_bounds__(256) void k_bnfold1(
    const float* __restrict__ pmom, int gn,
    const float* __restrict__ W1l, const float* __restrict__ b1,
    const float* __restrict__ W1r,
    const float* __restrict__ g1, const float* __restrict__ be1,
    float* __restrict__ fold, float invN) {
    int tid = threadIdx.x;
    __shared__ float smom[14];
    __shared__ float ws[4];
    for (int k = 0; k < 14; ++k) {
        float s = 0.f;
        for (int idx = tid; idx < gn; idx += 256) s += pmom[(size_t)k * gn + idx];
#pragma unroll
        for (int o = 32; o > 0; o >>= 1) s += __shfl_xor(s, o, 64);
        if ((tid & 63) == 0) ws[tid >> 6] = s;
        __syncthreads();
        if (tid == 0) smom[k] = ws[0] + ws[1] + ws[2] + ws[3];
        __syncthreads();
    }
    if (tid < 64) {
        int c = tid;
        float w0 = W1l[c], w1 = W1l[64 + c], w2 = W1r[c], w3 = W1r[64 + c], w4 = b1[c];
        float lin = (smom[0] * w0 + smom[1] * w1 + smom[2] * w2 + smom[3] * w3) * invN;
        float mean = lin + w4;
        float q = smom[4] * w0 * w0 + smom[8] * w1 * w1 + smom[11] * w2 * w2 + smom[13] * w3 * w3
                + 2.f * (smom[5] * w0 * w1 + smom[6] * w0 * w2 + smom[7] * w0 * w3
                       + smom[9] * w1 * w2 + smom[10] * w1 * w3 + smom[12] * w2 * w3);
        float Eh2 = q * invN + 2.f * w4 * lin + w4 * w4;
        float var = Eh2 - mean * mean;
        float al = g1[c] * rsqrtf(var + EPS);
        float be = be1[c] - mean * al;
        fold[c]       = al * w0;
        fold[64 + c]  = al * w1;
        fold[128 + c] = al * w2;
        fold[192 + c] = al * w3;
        fold[256 + c] = al * w4 + be;
    }
}

// ---------------------------------------------------------------------------
// Reduce pstats[c][nb] -> stats2[c]  (c = 0..127; grid = 128 blocks)
__global__ __launch_bounds__(256) void k_sreduce(const float* __restrict__ pstats,
                                                 int nb, float* __restrict__ stats2) {
    int c = blockIdx.x, tid = threadIdx.x;
    float s = 0.f;
    for (int i = tid; i < nb; i += 256) s += pstats[(size_t)c * nb + i];
#pragma unroll
    for (int o = 32; o > 0; o >>= 1) s += __shfl_xor(s, o, 64);
    __shared__ float ws[4];
    if ((tid & 63) == 0) ws[tid >> 6] = s;
    __syncthreads();
    if (tid == 0) stats2[c] = ws[0] + ws[1] + ws[2] + ws[3];
}

__global__ void k_bnfin(const float* __restrict__ stats, const float* __restrict__ g,
                        const float* __restrict__ be, float* __restrict__ coef, float invN) {
    int c = threadIdx.x;
    float m = stats[c] * invN;
    float var = stats[64 + c] * invN - m * m;
    float a = g[c] * rsqrtf(var + EPS);
    coef[c] = a;
    coef[64 + c] = be[c] - m * a;
}

// ---------------------------------------------------------------------------
// Pre-transform: x1 = relu(bn1-folded(agg1, x)) on the fly; y = x1@W2l;
// z = x1@W2r + b2; t1 = x1.W3l; v1 = x1.W3r. LDS out-stage -> full-line stores.
#define LROW 72  // LDS row stride in shorts

__global__ __launch_bounds__(256) void k_dense_pre(
    const float* __restrict__ agg1, const float* __restrict__ xin,
    const float* __restrict__ fold,
    const float* __restrict__ W2l, const float* __restrict__ b2,
    const float* __restrict__ W2r,
    const float* __restrict__ W3l, const float* __restrict__ W3r,
    unsigned short* __restrict__ y, unsigned short* __restrict__ z,
    float* __restrict__ t1, float* __restrict__ v1, int n) {
    __shared__ unsigned short lds_w[16 * 64 * 8];                 // 16 KB
    __shared__ __align__(16) unsigned short lds_y[4][16 * LROW];
    __shared__ __align__(16) unsigned short lds_z[4][16 * LROW];
    int tid = threadIdx.x, w = tid >> 6, l = tid & 63, ln = l & 15, kg = l >> 4;

    for (int idx = tid; idx < 4096; idx += 256) {
        int k = idx >> 6, c = idx & 63;
        int lane = ((k >> 3) & 3) * 16 + (c & 15);
        int fbase = ((k >> 5) * 4 + (c >> 4)) * 64 + lane;
        lds_w[fbase * 8 + (k & 7)] = f2bf(W2l[idx]);
        lds_w[(8 * 64 + fbase) * 8 + (k & 7)] = f2bf(W2r[idx]);
    }
    __syncthreads();

    float bb[4];
#pragma unroll
    for (int cs = 0; cs < 4; ++cs) bb[cs] = b2[cs * 16 + ln];

    float F0[16], F1[16], F2[16], F3[16], F4[16];
#pragma unroll
    for (int j = 0; j < 8; ++j) {
        int c = kg * 8 + j;
        F0[j] = fold[c];       F1[j] = fold[64 + c];  F2[j] = fold[128 + c];
        F3[j] = fold[192 + c]; F4[j] = fold[256 + c];
        c += 32;
        F0[8 + j] = fold[c];       F1[8 + j] = fold[64 + c];  F2[8 + j] = fold[128 + c];
        F3[8 + j] = fold[192 + c]; F4[8 + j] = fold[256 + c];
    }
    bf16x8 b3a, b3b;
#pragma unroll
    for (int j = 0; j < 8; ++j) {
        float va = (ln == 0) ? W3l[kg * 8 + j] : ((ln == 1) ? W3r[kg * 8 + j] : 0.f);
        float vb = (ln == 0) ? W3l[32 + kg * 8 + j] : ((ln == 1) ? W3r[32 + kg * 8 + j] : 0.f);
        b3a[j] = (short)f2bf(va);
        b3b[j] = (short)f2bf(vb);
    }

    unsigned short* Ys = lds_y[w];
    unsigned short* Zs = lds_z[w];
    const bf16x8* wfrag = (const bf16x8*)lds_w;
    int nt = (n + 15) >> 4;
    int stride = gridDim.x * 4;

#define LOADH(T, A)                                                          \
    {                                                                        \
        int row_ = ((T) << 4) + ln;                                          \
        int rr_ = (row_ < n) ? row_ : (n - 1);                               \
        A##a = ((const float2*)agg1)[rr_];                                   \
        A##x = ((const float2*)xin)[rr_];                                    \
    }

#define PROCESSH(T, A)                                                       \
    {                                                                        \
        bf16x8 u0_, u1_;                                                     \
        _Pragma("unroll")                                                    \
        for (int j = 0; j < 8; ++j) {                                        \
            float h0_ = fmaf(A##a.x, F0[j], fmaf(A##a.y, F1[j],              \
                        fmaf(A##x.x, F2[j], fmaf(A##x.y, F3[j], F4[j]))));   \
            float h1_ = fmaf(A##a.x, F0[8 + j], fmaf(A##a.y, F1[8 + j],      \
                        fmaf(A##x.x, F2[8 + j], fmaf(A##x.y, F3[8 + j], F4[8 + j])))); \
            u0_[j] = (short)f2bf(fmaxf(0.f, h0_));                           \
            u1_[j] = (short)f2bf(fmaxf(0.f, h1_));                           \
        }                                                                    \
        f32x4 ya_[4], za_[4], a3_;                                           \
        _Pragma("unroll")                                                    \
        for (int cs = 0; cs < 4; ++cs) {                                     \
            ya_[cs] = (f32x4){0.f, 0.f, 0.f, 0.f};                           \
            za_[cs] = (f32x4){0.f, 0.f, 0.f, 0.f};                           \
        }                                                                    \
        a3_ = (f32x4){0.f, 0.f, 0.f, 0.f};                                   \
        _Pragma("unroll")                                                    \
        for (int cs = 0; cs < 4; ++cs) {                                     \
            ya_[cs] = __builtin_amdgcn_mfma_f32_16x16x32_bf16(u0_, wfrag[(0 * 4 + cs) * 64 + l], ya_[cs], 0, 0, 0);  \
            ya_[cs] = __builtin_amdgcn_mfma_f32_16x16x32_bf16(u1_, wfrag[(1 * 4 + cs) * 64 + l], ya_[cs], 0, 0, 0);  \
            za_[cs] = __builtin_amdgcn_mfma_f32_16x16x32_bf16(u0_, wfrag[(8 + cs) * 64 + l], za_[cs], 0, 0, 0);      \
            za_[cs] = __builtin_amdgcn_mfma_f32_16x16x32_bf16(u1_, wfrag[(12 + cs) * 64 + l], za_[cs], 0, 0, 0);     \
        }                                                                    \
        a3_ = __builtin_amdgcn_mfma_f32_16x16x32_bf16(u0_, b3a, a3_, 0, 0, 0); \
        a3_ = __builtin_amdgcn_mfma_f32_16x16x32_bf16(u1_, b3b, a3_, 0, 0, 0); \
        _Pragma("unroll")                                                    \
        for (int cs = 0; cs < 4; ++cs) {                                     \
            _Pragma("unroll")                                                \
            for (int r = 0; r < 4; ++r) {                                    \
                Ys[(kg * 4 + r) * LROW + cs * 16 + ln] = f2bf(ya_[cs][r]);   \
                Zs[(kg * 4 + r) * LROW + cs * 16 + ln] = f2bf(za_[cs][r] + bb[cs]); \
            }                                                                \
        }                                                                    \
        int base_ = (T) << 4;                                                \
        if (ln < 2) {                                                        \
            float* d3_ = (ln == 0) ? t1 : v1;                                \
            _Pragma("unroll")                                                \
            for (int r = 0; r < 4; ++r) {                                    \
                int row_ = base_ + kg * 4 + r;                               \
                if (row_ < n) d3_[row_] = a3_[r];                            \
            }                                                                \
        }                                                                    \
        asm volatile("s_waitcnt lgkmcnt(0)" ::: "memory");                   \
        int orow_ = l >> 2, oc_ = (l & 3) * 16;                              \
        if (base_ + orow_ < n) {                                             \
            const bf16x8* yp_ = (const bf16x8*)(Ys + orow_ * LROW + oc_);    \
            const bf16x8* zp_ = (const bf16x8*)(Zs + orow_ * LROW + oc_);    \
            bf16x8* yd_ = (bf16x8*)(y + (size_t)(base_ + orow_) * 64 + oc_); \
            bf16x8* zd_ = (bf16x8*)(z + (size_t)(base_ + orow_) * 64 + oc_); \
            yd_[0] = yp_[0]; yd_[1] = yp_[1];                                \
            zd_[0] = zp_[0]; zd_[1] = zp_[1];                                \
        }                                                                    \
        asm volatile("s_waitcnt lgkmcnt(0)" ::: "memory");                   \
    }

    float2 Pa, Px, Qa, Qx;
    int t = blockIdx.x * 4 + w;
    if (t < nt) {
        LOADH(t, P);
        while (t < nt) {
            int t1_ = t + stride;
            if (t1_ < nt) LOADH(t1_, Q);
            PROCESSH(t, P);
            int t2_ = t1_ + stride;
            if (t2_ < nt) LOADH(t2_, P);
            if (t1_ < nt) PROCESSH(t1_, Q);
            t = t2_;
        }
    }
#undef LOADH
#undef PROCESSH
}

// ---------------------------------------------------------------------------
// Gather + combine: h2_i = mean_j y[src_j] + z_i (z holds +b2), in place on z.
// 8-lane groups, grid-stride (2048 blocks). ATOMIC-FREE stats partials.
__global__ __launch_bounds__(256) void k_gather2b(
    const unsigned short* __restrict__ y, const int* __restrict__ rowptr,
    const int* __restrict__ csr, unsigned short* zh2,
    float* __restrict__ pstats, int n) {
    int tid = threadIdx.x;
    int lg = tid & 7;
    int gid0 = blockIdx.x * 32 + (tid >> 3);
    int gstep = gridDim.x * 32;
    float ls[8] = {0.f, 0.f, 0.f, 0.f, 0.f, 0.f, 0.f, 0.f};
    float lq[8] = {0.f, 0.f, 0.f, 0.f, 0.f, 0.f, 0.f, 0.f};

    for (int i = gid0; i < n; i += gstep) {
        bf16x8 z8 = *(const bf16x8*)(zh2 + (size_t)i * 64 + lg * 8);  // early, in flight
        int r0 = rowptr[i], r1 = rowptr[i + 1];
        float s[8] = {0.f, 0.f, 0.f, 0.f, 0.f, 0.f, 0.f, 0.f};
        int j = r0;
        for (; j + 1 < r1; j += 2) {
            int a = csr[j], b = csr[j + 1];
            bf16x8 va = *(const bf16x8*)(y + (size_t)a * 64 + lg * 8);
            bf16x8 vb = *(const bf16x8*)(y + (size_t)b * 64 + lg * 8);
#pragma unroll
            for (int k = 0; k < 8; ++k)
                s[k] += bf2f((unsigned short)va[k]) + bf2f((unsigned short)vb[k]);
        }
        if (j < r1) {
            bf16x8 va = *(const bf16x8*)(y + (size_t)csr[j] * 64 + lg * 8);
#pragma unroll
            for (int k = 0; k < 8; ++k) s[k] += bf2f((unsigned short)va[k]);
        }
        float inv = 1.f / fmaxf((float)(r1 - r0), 1.f);
        bf16x8 hb;
#pragma unroll
        for (int k = 0; k < 8; ++k) {
            float h = fmaf(s[k], inv, bf2f((unsigned short)z8[k]));
            unsigned short b = f2bf(h);
            hb[k] = (short)b;
            float hf = bf2f(b);
            ls[k] += hf; lq[k] += hf * hf;
        }
        *(bf16x8*)(zh2 + (size_t)i * 64 + lg * 8) = hb;
    }

#pragma unroll
    for (int k = 0; k < 8; ++k) {
        ls[k] += __shfl_xor(ls[k], 8, 64);
        ls[k] += __shfl_xor(ls[k], 16, 64);
        ls[k] += __shfl_xor(ls[k], 32, 64);
        lq[k] += __shfl_xor(lq[k], 8, 64);
        lq[k] += __shfl_xor(lq[k], 16, 64);
        lq[k] += __shfl_xor(lq[k], 32, 64);
    }
    __shared__ float red[2][4][64];
    int w = tid >> 6;
    if ((tid & 63) < 8) {
#pragma unroll
        for (int k = 0; k < 8; ++k) {
            red[0][w][lg * 8 + k] = ls[k];
            red[1][w][lg * 8 + k] = lq[k];
        }
    }
    __syncthreads();
    if (tid < 128) {
        int c = tid & 63;
        int half = tid >> 6;
        float v = red[half][0][c] + red[half][1][c] + red[half][2][c] + red[half][3][c];
        pstats[(size_t)tid * gridDim.x + blockIdx.x] = v;
    }
}

// ---------------------------------------------------------------------------
// Finalize via MFMA: per 16-node tile, x2 = relu(bn2(h2)) in-register, then
// 2 MFMAs against [W3l | W3r] B-fragment (cols 0/1). Replaces 12 shuffle
// levels/node with 2 MFMAs/16 nodes. One tile per wave, one-shot grid.
__global__ __launch_bounds__(256) void k_finalize(
    const unsigned short* __restrict__ h2b,
    const float* __restrict__ t1, const float* __restrict__ v1,
    const float* __restrict__ coef2,
    const float* __restrict__ W3l, const float* __restrict__ W3r,
    float* __restrict__ tb, float* __restrict__ vb, int n) {
    int tid = threadIdx.x, w = tid >> 6, l = tid & 63, ln = l & 15, kg = l >> 4;

    // BN2 coefs for this lane's k-slice (k = kg*8+j and 32+kg*8+j)
    float c2a[16], c2b[16];
#pragma unroll
    for (int j = 0; j < 8; ++j) {
        c2a[j]     = coef2[kg * 8 + j];       c2b[j]     = coef2[64 + kg * 8 + j];
        c2a[8 + j] = coef2[32 + kg * 8 + j];  c2b[8 + j] = coef2[96 + kg * 8 + j];
    }
    // W3 B-fragments: col 0 = W3l, col 1 = W3r, others 0
    bf16x8 b3a, b3b;
#pragma unroll
    for (int j = 0; j < 8; ++j) {
        float va = (ln == 0) ? W3l[kg * 8 + j] : ((ln == 1) ? W3r[kg * 8 + j] : 0.f);
        float vb = (ln == 0) ? W3l[32 + kg * 8 + j] : ((ln == 1) ? W3r[32 + kg * 8 + j] : 0.f);
        b3a[j] = (short)f2bf(va);
        b3b[j] = (short)f2bf(vb);
    }

    int t = blockIdx.x * 4 + w;   // tile index; one tile per wave
    int nt = (n + 15) >> 4;
    if (t >= nt) return;
    int i0 = t << 4;
    int row = i0 + ln;
    int rr = (row < n) ? row : (n - 1);
    const unsigned short* hr = h2b + (size_t)rr * 64 + kg * 8;
    bf16x8 r0 = *(const bf16x8*)hr;
    bf16x8 r1 = *(const bf16x8*)(hr + 32);
    bf16x8 u0, u1;
#pragma unroll
    for (int j = 0; j < 8; ++j) {
        float f0 = bf2f((unsigned short)r0[j]);
        float f1 = bf2f((unsigned short)r1[j]);
        u0[j] = (short)f2bf(fmaxf(0.f, fmaf(f0, c2a[j], c2b[j])));
        u1[j] = (short)f2bf(fmaxf(0.f, fmaf(f1, c2a[8 + j], c2b[8 + j])));
    }
    f32x4 acc = (f32x4){0.f, 0.f, 0.f, 0.f};
    acc = __builtin_amdgcn_mfma_f32_16x16x32_bf16(u0, b3a, acc, 0, 0, 0);
    acc = __builtin_amdgcn_mfma_f32_16x16x32_bf16(u1, b3b, acc, 0, 0, 0);
    // C/D: col = lane&15 (0 -> t, 1 -> v), row = kg*4 + r
    if (ln < 2) {
        float* d = (ln == 0) ? tb : vb;
        const float* s1 = (ln == 0) ? t1 : v1;
#pragma unroll
        for (int r = 0; r < 4; ++r) {
            int orow = i0 + kg * 4 + r;
            if (orow < n) d[orow] = acc[r] + s1[orow];
        }
    }
}

// ---------------------------------------------------------------------------
__global__ void k_gather3(const float* __restrict__ tb, const float* __restrict__ vb,
                          const int* __restrict__ rowptr, const int* __restrict__ csr,
                          const float* __restrict__ b3, float* __restrict__ out, int n) {
    int i = blockIdx.x * blockDim.x + threadIdx.x;
    if (i >= n) return;
    int r0 = rowptr[i], r1 = rowptr[i + 1];
    float s = 0.f;
    int j = r0;
    for (; j + 3 < r1; j += 4)
        s += tb[csr[j]] + tb[csr[j + 1]] + tb[csr[j + 2]] + tb[csr[j + 3]];
    for (; j < r1; ++j) s += tb[csr[j]];
    float inv = 1.f / fmaxf((float)(r1 - r0), 1.f);
    out[i] = fmaf(s, inv, b3[0] + vb[i]);
}

// ---------------------------------------------------------------------------
// Workspace (4B units, N=500k, E=1.25M; cap 256 MiB = 67,108,864 units):
//   y 32N + zh2 32N + R 2N + t1 N + v1 N + rowptr N+1 + csr E
//   + bsums 2048 + pstats 128*2048 + pmom 14*2048 + small
//   = 68N + E + ~295k = ~35.5M units = 142 MB (safe)
extern "C" void kernel_launch(void* const* d_in, const int* in_sizes, int n_in,
                              void* d_out, int out_size, void* d_ws, size_t ws_size,
                              hipStream_t stream) {
    const float* x   = (const float*)d_in[0];
    const int*   ei  = (const int*)d_in[1];
    const float* W1l = (const float*)d_in[2];
    const float* b1  = (const float*)d_in[3];
    const float* W1r = (const float*)d_in[4];
    const float* g1  = (const float*)d_in[5];
    const float* be1 = (const float*)d_in[6];
    const float* W2l = (const float*)d_in[7];
    const float* b2  = (const float*)d_in[8];
    const float* W2r = (const float*)d_in[9];
    const float* g2  = (const float*)d_in[10];
    const float* be2 = (const float*)d_in[11];
    const float* W3l = (const float*)d_in[12];
    const float* b3  = (const float*)d_in[13];
    const float* W3r = (const float*)d_in[14];

    int N = in_sizes[0] / 2;
    int E = in_sizes[1] / 2;

    float* ws   = (float*)d_ws;
    size_t nn   = (size_t)N;
    unsigned short* y   = (unsigned short*)ws;             // 32N units
    unsigned short* zh2 = (unsigned short*)(ws + 32 * nn); // 32N units (z -> h2)
    float* R     = ws + 64 * nn;            // 2N time-shared: cursor -> agg1 -> tb/vb
    int*   cursor = (int*)R;
    float* agg1   = R;
    float* tb     = R;
    float* vb     = R + nn;
    float* t1     = ws + 66 * nn;           // N
    float* v1     = ws + 67 * nn;           // N
    int*   rowptr = (int*)(ws + 68 * nn);   // N+1 (doubles as histogram cnt)
    int*   csr    = rowptr + (N + 1);       // E
    int*   bsums  = csr + E;                // 2048
    float* pstats = (float*)(bsums + 2048); // 128 * 2048 partial stats
    float* pmom   = pstats + 128 * 2048;    // 14 * 2048 partial moments
    float* stats2 = pmom + 14 * 2048;       // 128: s2 | q2
    float* coef2  = stats2 + 128;           // 128: a2, b2
    float* fold   = coef2 + 128;            // 320: F0..F4
    int*   flag   = (int*)(fold + 320);     // 64

    hipMemsetAsync(rowptr, 0, (size_t)(N + 1) * sizeof(int), stream);

    k_detect<<<1, 1, 0, stream>>>(ei, flag);

    int ge = (E + 255) / 256;
    int gn = (N + 255) / 256;
    int nb = (N + 1023) / 1024;
    k_hist<<<ge, 256, 0, stream>>>(ei, flag, E, rowptr);
    k_scanA<<<nb, 256, 0, stream>>>(rowptr, N, bsums);
    k_scanB<<<1, 256, 0, stream>>>(bsums, nb, rowptr, N);
    k_scanC<<<nb, 256, 0, stream>>>(rowptr, N, bsums, cursor);
    // Range-partitioned fill: 4 passes, each pass's csr/cursor region L2-fits.
    {
        const int NPASS = 4;
        int span = (N + NPASS - 1) / NPASS;
        for (int p = 0; p < NPASS; ++p) {
            int lo = p * span;
            int hi = min(N, lo + span);
            k_fill_range<<<ge, 256, 0, stream>>>(ei, flag, E, cursor, csr, lo, hi);
        }
    }
    // cursor dead; R becomes agg1

    k_gather1m<<<gn, 256, 0, stream>>>(x, rowptr, csr, agg1, pmom, N);
    k_bnfold1<<<1, 256, 0, stream>>>(pmom, gn, W1l, b1, W1r, g1, be1, fold,
                                     1.0f / (float)N);

    k_dense_pre<<<2048, 256, 0, stream>>>(agg1, x, fold, W2l, b2, W2r, W3l, W3r,
                                          y, zh2, t1, v1, N);
    // agg1 dead after dense_pre

    k_gather2b<<<2048, 256, 0, stream>>>(y, rowptr, csr, zh2, pstats, N);
    k_sreduce<<<128, 256, 0, stream>>>(pstats, 2048, stats2);
    k_bnfin<<<1, 64, 0, stream>>>(stats2, g2, be2, coef2, 1.0f / (float)N);

    // R becomes tb/vb
    int nt = (N + 15) / 16;
    k_finalize<<<(nt + 3) / 4, 256, 0, stream>>>(zh2, t1, v1, coef2,
                                                 W3l, W3r, tb, vb, N);
    k_gather3<<<gn, 256, 0, stream>>>(tb, vb, rowptr, csr, b3, (float*)d_out, N);
}

// Round 17
// 350.278 us; speedup vs baseline: 2.4619x; 1.0307x over previous
//
#include <hip/hip_runtime.h>

#define EPS 1e-5f

typedef __attribute__((ext_vector_type(8))) short bf16x8;
typedef __attribute__((ext_vector_type(4))) float f32x4;

__device__ __forceinline__ unsigned short f2bf(float f) {
    unsigned u = __float_as_uint(f);
    u += 0x7fffu + ((u >> 16) & 1u);
    return (unsigned short)(u >> 16);
}
__device__ __forceinline__ float bf2f(unsigned short s) {
    return __uint_as_float(((unsigned)s) << 16);
}

// Storage channel permutation for y/zh2: c' = (c&15)*4 + (c>>4).
// orig(c') = (c'&3)*16 + (c'>>2). Lets MFMA lanes store contiguous ushort4.

// ---------------------------------------------------------------------------
__global__ void k_detect(const int* __restrict__ ei, int* __restrict__ flag) {
    if (blockIdx.x == 0 && threadIdx.x == 0) {
        int is64 = 1;
        for (int k = 0; k < 16; ++k) is64 &= (ei[2 * k + 1] == 0) ? 1 : 0;
        *flag = is64;
    }
}

// ---------------------------------------------------------------------------
// CSR build: histogram -> exclusive scan -> range-partitioned fill
__global__ void k_hist(const int* __restrict__ ei, const int* __restrict__ flag,
                       int E, int* __restrict__ cnt) {
    int e = blockIdx.x * blockDim.x + threadIdx.x;
    if (e >= E) return;
    int d = (*flag) ? (int)((const long long*)ei)[E + e] : ei[E + e];
    atomicAdd(&cnt[d], 1);
}

__device__ __forceinline__ int block_incl_scan(int v, int tid, int* total) {
    __shared__ int wsum[4];
    __shared__ int tot;
#pragma unroll
    for (int o = 1; o < 64; o <<= 1) {
        int u = __shfl_up(v, o, 64);
        if ((tid & 63) >= o) v += u;
    }
    if ((tid & 63) == 63) wsum[tid >> 6] = v;
    __syncthreads();
    int w = tid >> 6, add = 0;
    if (w > 0) add += wsum[0];
    if (w > 1) add += wsum[1];
    if (w > 2) add += wsum[2];
    v += add;
    if (tid == 255) tot = v;
    __syncthreads();
    *total = tot;
    __syncthreads();
    return v;
}

__global__ __launch_bounds__(256) void k_scanA(const int* __restrict__ cnt, int n,
                                               int* __restrict__ bsums) {
    int tid = threadIdx.x;
    int idx = blockIdx.x * 1024 + tid * 4;
    int s = 0;
#pragma unroll
    for (int k = 0; k < 4; ++k) { int i = idx + k; if (i < n) s += cnt[i]; }
#pragma unroll
    for (int o = 32; o > 0; o >>= 1) s += __shfl_xor(s, o, 64);
    __shared__ int ws[4];
    if ((tid & 63) == 0) ws[tid >> 6] = s;
    __syncthreads();
    if (tid == 0) bsums[blockIdx.x] = ws[0] + ws[1] + ws[2] + ws[3];
}

__global__ __launch_bounds__(256) void k_scanB(int* __restrict__ bsums, int nb,
                                               int* __restrict__ rowptr, int N) {
    int tid = threadIdx.x;
    __shared__ int sh_carry;
    if (tid == 0) sh_carry = 0;
    __syncthreads();
    int niter = (nb + 255) / 256;
    for (int it = 0; it < niter; ++it) {
        int i = it * 256 + tid;
        int v = (i < nb) ? bsums[i] : 0;
        int tot;
        int inc = block_incl_scan(v, tid, &tot);
        int carry = sh_carry;
        if (i < nb) bsums[i] = carry + inc - v;
        __syncthreads();
        if (tid == 0) sh_carry = carry + tot;
        __syncthreads();
    }
    if (tid == 0) rowptr[N] = sh_carry;
}

__global__ __launch_bounds__(256) void k_scanC(int* __restrict__ cnt_rowptr, int n,
                                               const int* __restrict__ bsums,
                                               int* __restrict__ cursor) {
    int tid = threadIdx.x;
    int idx = blockIdx.x * 1024 + tid * 4;
    int v[4]; int s = 0;
#pragma unroll
    for (int k = 0; k < 4; ++k) { int i = idx + k; v[k] = (i < n) ? cnt_rowptr[i] : 0; s += v[k]; }
    int tot;
    int inc = block_incl_scan(s, tid, &tot);
    int off = bsums[blockIdx.x] + inc - s;
#pragma unroll
    for (int k = 0; k < 4; ++k) {
        int i = idx + k;
        if (i < n) { cnt_rowptr[i] = off; cursor[i] = off; off += v[k]; }
    }
}

// Range-partitioned fill: pass handles dst in [lo, hi); per-pass csr/cursor
// region is L2-resident -> scattered 4B stores merge into full lines.
__global__ void k_fill_range(const int* __restrict__ ei, const int* __restrict__ flag,
                             int E, int* __restrict__ cursor, int* __restrict__ csr,
                             int lo, int hi) {
    int e = blockIdx.x * blockDim.x + threadIdx.x;
    if (e >= E) return;
    int f = *flag;
    int d = f ? (int)((const long long*)ei)[E + e] : ei[E + e];
    if (d < lo || d >= hi) return;
    int s = f ? (int)((const long long*)ei)[e] : ei[e];
    int pos = atomicAdd(&cursor[d], 1);
    csr[pos] = s;
}

// ---------------------------------------------------------------------------
// Layer-1 gather fused with u-moments (u = (agg1, x), 14 scalars).
__global__ __launch_bounds__(256) void k_gather1m(
    const float* __restrict__ x, const int* __restrict__ rowptr,
    const int* __restrict__ csr, float* __restrict__ agg1,
    float* __restrict__ pmom, int n) {
    int tid = threadIdx.x;
    int i = blockIdx.x * 256 + tid;
    float m[14];
#pragma unroll
    for (int k = 0; k < 14; ++k) m[k] = 0.f;
    if (i < n) {
        int r0 = rowptr[i], r1 = rowptr[i + 1];
        float s0 = 0.f, s1 = 0.f;
        int j = r0;
        for (; j + 3 < r1; j += 4) {
            float2 v0 = ((const float2*)x)[csr[j]];
            float2 v1 = ((const float2*)x)[csr[j + 1]];
            float2 v2 = ((const float2*)x)[csr[j + 2]];
            float2 v3 = ((const float2*)x)[csr[j + 3]];
            s0 += v0.x + v1.x + v2.x + v3.x;
            s1 += v0.y + v1.y + v2.y + v3.y;
        }
        for (; j < r1; ++j) {
            float2 v = ((const float2*)x)[csr[j]];
            s0 += v.x; s1 += v.y;
        }
        float inv = 1.f / fmaxf((float)(r1 - r0), 1.f);
        float ax = s0 * inv, ay = s1 * inv;
        agg1[2 * i] = ax;
        agg1[2 * i + 1] = ay;
        float2 xv = ((const float2*)x)[i];
        m[0] = ax;        m[1] = ay;        m[2] = xv.x;      m[3] = xv.y;
        m[4] = ax * ax;   m[5] = ax * ay;   m[6] = ax * xv.x; m[7] = ax * xv.y;
        m[8] = ay * ay;   m[9] = ay * xv.x; m[10] = ay * xv.y;
        m[11] = xv.x * xv.x; m[12] = xv.x * xv.y; m[13] = xv.y * xv.y;
    }
#pragma unroll
    for (int k = 0; k < 14; ++k) {
#pragma unroll
        for (int o = 32; o > 0; o >>= 1) m[k] += __shfl_xor(m[k], o, 64);
    }
    __shared__ float red[4][14];
    int w = tid >> 6;
    if ((tid & 63) == 0) {
#pragma unroll
        for (int k = 0; k < 14; ++k) red[w][k] = m[k];
    }
    __syncthreads();
    if (tid < 14)
        pmom[(size_t)tid * gridDim.x + blockIdx.x] =
            red[0][tid] + red[1][tid] + red[2][tid] + red[3][tid];
}

// ---------------------------------------------------------------------------
// Reduce pmom partials + BN1-fold (1 block x 256).
__global__ __launch_bounds__(256) void k_bnfold1(
    const float* __restrict__ pmom, int gn,
    const float* __restrict__ W1l, const float* __restrict__ b1,
    const float* __restrict__ W1r,
    const float* __restrict__ g1, const float* __restrict__ be1,
    float* __restrict__ fold, float invN) {
    int tid = threadIdx.x;
    __shared__ float smom[14];
    __shared__ float ws[4];
    for (int k = 0; k < 14; ++k) {
        float s = 0.f;
        for (int idx = tid; idx < gn; idx += 256) s += pmom[(size_t)k * gn + idx];
#pragma unroll
        for (int o = 32; o > 0; o >>= 1) s += __shfl_xor(s, o, 64);
        if ((tid & 63) == 0) ws[tid >> 6] = s;
        __syncthreads();
        if (tid == 0) smom[k] = ws[0] + ws[1] + ws[2] + ws[3];
        __syncthreads();
    }
    if (tid < 64) {
        int c = tid;
        float w0 = W1l[c], w1 = W1l[64 + c], w2 = W1r[c], w3 = W1r[64 + c], w4 = b1[c];
        float lin = (smom[0] * w0 + smom[1] * w1 + smom[2] * w2 + smom[3] * w3) * invN;
        float mean = lin + w4;
        float q = smom[4] * w0 * w0 + smom[8] * w1 * w1 + smom[11] * w2 * w2 + smom[13] * w3 * w3
                + 2.f * (smom[5] * w0 * w1 + smom[6] * w0 * w2 + smom[7] * w0 * w3
                       + smom[9] * w1 * w2 + smom[10] * w1 * w3 + smom[12] * w2 * w3);
        float Eh2 = q * invN + 2.f * w4 * lin + w4 * w4;
        float var = Eh2 - mean * mean;
        float al = g1[c] * rsqrtf(var + EPS);
        float be = be1[c] - mean * al;
        fold[c]       = al * w0;
        fold[64 + c]  = al * w1;
        fold[128 + c] = al * w2;
        fold[192 + c] = al * w3;
        fold[256 + c] = al * w4 + be;
    }
}

// ---------------------------------------------------------------------------
// Fused: reduce pstats[c'][nb] and pstats[64+c'][nb] -> BN2 coefs (perm space).
// BN params g2/be2 indexed via orig(c') = (c'&3)*16 + (c'>>2).
__global__ __launch_bounds__(256) void k_sredfin(
    const float* __restrict__ pstats, int nb,
    const float* __restrict__ g, const float* __restrict__ be,
    float* __restrict__ coef, float invN) {
    int c = blockIdx.x, tid = threadIdx.x;   // c = perm-space channel (0..63)
    float s = 0.f, q = 0.f;
    for (int i = tid; i < nb; i += 256) {
        s += pstats[(size_t)c * nb + i];
        q += pstats[(size_t)(64 + c) * nb + i];
    }
#pragma unroll
    for (int o = 32; o > 0; o >>= 1) {
        s += __shfl_xor(s, o, 64);
        q += __shfl_xor(q, o, 64);
    }
    __shared__ float ws[4], wq[4];
    if ((tid & 63) == 0) { ws[tid >> 6] = s; wq[tid >> 6] = q; }
    __syncthreads();
    if (tid == 0) {
        float S = ws[0] + ws[1] + ws[2] + ws[3];
        float Q = wq[0] + wq[1] + wq[2] + wq[3];
        float m = S * invN;
        float var = Q * invN - m * m;
        int o = (c & 3) * 16 + (c >> 2);      // original channel
        float a = g[o] * rsqrtf(var + EPS);
        coef[c] = a;
        coef[64 + c] = be[o] - m * a;
    }
}

// ---------------------------------------------------------------------------
// Pre-transform: x1 = relu(bn1-folded(agg1, x)) on the fly; y = x1@W2l;
// z = x1@W2r + b2; t1 = x1.W3l; v1 = x1.W3r. Direct PERMUTED ushort4 stores
// (no LDS out-stage): lane stores its 4 acc values contiguously; each 16-lane
// kg-group covers a full 128B line of one output row.
__global__ __launch_bounds__(256) void k_dense_pre(
    const float* __restrict__ agg1, const float* __restrict__ xin,
    const float* __restrict__ fold,
    const float* __restrict__ W2l, const float* __restrict__ b2,
    const float* __restrict__ W2r,
    const float* __restrict__ W3l, const float* __restrict__ W3r,
    unsigned short* __restrict__ y, unsigned short* __restrict__ z,
    float* __restrict__ t1, float* __restrict__ v1, int n) {
    __shared__ unsigned short lds_w[16 * 64 * 8];   // 16 KB (W frags only)
    int tid = threadIdx.x, w = tid >> 6, l = tid & 63, ln = l & 15, kg = l >> 4;

    for (int idx = tid; idx < 4096; idx += 256) {
        int k = idx >> 6, c = idx & 63;
        int lane = ((k >> 3) & 3) * 16 + (c & 15);
        int fbase = ((k >> 5) * 4 + (c >> 4)) * 64 + lane;
        lds_w[fbase * 8 + (k & 7)] = f2bf(W2l[idx]);
        lds_w[(8 * 64 + fbase) * 8 + (k & 7)] = f2bf(W2r[idx]);
    }
    __syncthreads();

    float bb[4];
#pragma unroll
    for (int cs = 0; cs < 4; ++cs) bb[cs] = b2[cs * 16 + ln];

    float F0[16], F1[16], F2[16], F3[16], F4[16];
#pragma unroll
    for (int j = 0; j < 8; ++j) {
        int c = kg * 8 + j;
        F0[j] = fold[c];       F1[j] = fold[64 + c];  F2[j] = fold[128 + c];
        F3[j] = fold[192 + c]; F4[j] = fold[256 + c];
        c += 32;
        F0[8 + j] = fold[c];       F1[8 + j] = fold[64 + c];  F2[8 + j] = fold[128 + c];
        F3[8 + j] = fold[192 + c]; F4[8 + j] = fold[256 + c];
    }
    bf16x8 b3a, b3b;   // orig-space W3 (u regs are orig layout)
#pragma unroll
    for (int j = 0; j < 8; ++j) {
        float va = (ln == 0) ? W3l[kg * 8 + j] : ((ln == 1) ? W3r[kg * 8 + j] : 0.f);
        float vb = (ln == 0) ? W3l[32 + kg * 8 + j] : ((ln == 1) ? W3r[32 + kg * 8 + j] : 0.f);
        b3a[j] = (short)f2bf(va);
        b3b[j] = (short)f2bf(vb);
    }

    const bf16x8* wfrag = (const bf16x8*)lds_w;
    int nt = (n + 15) >> 4;
    int stride = gridDim.x * 4;

#define LOADH(T, A)                                                          \
    {                                                                        \
        int row_ = ((T) << 4) + ln;                                          \
        int rr_ = (row_ < n) ? row_ : (n - 1);                               \
        A##a = ((const float2*)agg1)[rr_];                                   \
        A##x = ((const float2*)xin)[rr_];                                    \
    }

#define PROCESSH(T, A)                                                       \
    {                                                                        \
        bf16x8 u0_, u1_;                                                     \
        _Pragma("unroll")                                                    \
        for (int j = 0; j < 8; ++j) {                                        \
            float h0_ = fmaf(A##a.x, F0[j], fmaf(A##a.y, F1[j],              \
                        fmaf(A##x.x, F2[j], fmaf(A##x.y, F3[j], F4[j]))));   \
            float h1_ = fmaf(A##a.x, F0[8 + j], fmaf(A##a.y, F1[8 + j],      \
                        fmaf(A##x.x, F2[8 + j], fmaf(A##x.y, F3[8 + j], F4[8 + j])))); \
            u0_[j] = (short)f2bf(fmaxf(0.f, h0_));                           \
            u1_[j] = (short)f2bf(fmaxf(0.f, h1_));                           \
        }                                                                    \
        f32x4 ya_[4], za_[4], a3_;                                           \
        _Pragma("unroll")                                                    \
        for (int cs = 0; cs < 4; ++cs) {                                     \
            ya_[cs] = (f32x4){0.f, 0.f, 0.f, 0.f};                           \
            za_[cs] = (f32x4){0.f, 0.f, 0.f, 0.f};                           \
        }                                                                    \
        a3_ = (f32x4){0.f, 0.f, 0.f, 0.f};                                   \
        _Pragma("unroll")                                                    \
        for (int cs = 0; cs < 4; ++cs) {                                     \
            ya_[cs] = __builtin_amdgcn_mfma_f32_16x16x32_bf16(u0_, wfrag[(0 * 4 + cs) * 64 + l], ya_[cs], 0, 0, 0);  \
            ya_[cs] = __builtin_amdgcn_mfma_f32_16x16x32_bf16(u1_, wfrag[(1 * 4 + cs) * 64 + l], ya_[cs], 0, 0, 0);  \
            za_[cs] = __builtin_amdgcn_mfma_f32_16x16x32_bf16(u0_, wfrag[(8 + cs) * 64 + l], za_[cs], 0, 0, 0);      \
            za_[cs] = __builtin_amdgcn_mfma_f32_16x16x32_bf16(u1_, wfrag[(12 + cs) * 64 + l], za_[cs], 0, 0, 0);     \
        }                                                                    \
        a3_ = __builtin_amdgcn_mfma_f32_16x16x32_bf16(u0_, b3a, a3_, 0, 0, 0); \
        a3_ = __builtin_amdgcn_mfma_f32_16x16x32_bf16(u1_, b3b, a3_, 0, 0, 0); \
        int base_ = (T) << 4;                                                \
        _Pragma("unroll")                                                    \
        for (int r = 0; r < 4; ++r) {                                        \
            int row_ = base_ + kg * 4 + r;                                   \
            if (row_ < n) {                                                  \
                ushort4 yv_, zv_;                                            \
                yv_.x = f2bf(ya_[0][r]); yv_.y = f2bf(ya_[1][r]);            \
                yv_.z = f2bf(ya_[2][r]); yv_.w = f2bf(ya_[3][r]);            \
                zv_.x = f2bf(za_[0][r] + bb[0]); zv_.y = f2bf(za_[1][r] + bb[1]); \
                zv_.z = f2bf(za_[2][r] + bb[2]); zv_.w = f2bf(za_[3][r] + bb[3]); \
                *(ushort4*)(y + (size_t)row_ * 64 + ln * 4) = yv_;           \
                *(ushort4*)(z + (size_t)row_ * 64 + ln * 4) = zv_;           \
            }                                                                \
        }                                                                    \
        if (ln < 2) {                                                        \
            float* d3_ = (ln == 0) ? t1 : v1;                                \
            _Pragma("unroll")                                                \
            for (int r = 0; r < 4; ++r) {                                    \
                int row_ = base_ + kg * 4 + r;                               \
                if (row_ < n) d3_[row_] = a3_[r];                            \
            }                                                                \
        }                                                                    \
    }

    float2 Pa, Px, Qa, Qx;
    int t = blockIdx.x * 4 + w;
    if (t < nt) {
        LOADH(t, P);
        while (t < nt) {
            int t1_ = t + stride;
            if (t1_ < nt) LOADH(t1_, Q);
            PROCESSH(t, P);
            int t2_ = t1_ + stride;
            if (t2_ < nt) LOADH(t2_, P);
            if (t1_ < nt) PROCESSH(t1_, Q);
            t = t2_;
        }
    }
#undef LOADH
#undef PROCESSH
}

// ---------------------------------------------------------------------------
// Gather + combine: h2_i = mean_j y[src_j] + z_i, in place on z (perm space,
// channel-oblivious). 8-lane groups, grid-stride. ATOMIC-FREE stats partials
// (perm-space channels).
__global__ __launch_bounds__(256) void k_gather2b(
    const unsigned short* __restrict__ y, const int* __restrict__ rowptr,
    const int* __restrict__ csr, unsigned short* zh2,
    float* __restrict__ pstats, int n) {
    int tid = threadIdx.x;
    int lg = tid & 7;
    int gid0 = blockIdx.x * 32 + (tid >> 3);
    int gstep = gridDim.x * 32;
    float ls[8] = {0.f, 0.f, 0.f, 0.f, 0.f, 0.f, 0.f, 0.f};
    float lq[8] = {0.f, 0.f, 0.f, 0.f, 0.f, 0.f, 0.f, 0.f};

    for (int i = gid0; i < n; i += gstep) {
        bf16x8 z8 = *(const bf16x8*)(zh2 + (size_t)i * 64 + lg * 8);  // early
        int r0 = rowptr[i], r1 = rowptr[i + 1];
        float s[8] = {0.f, 0.f, 0.f, 0.f, 0.f, 0.f, 0.f, 0.f};
        int j = r0;
        for (; j + 1 < r1; j += 2) {
            int a = csr[j], b = csr[j + 1];
            bf16x8 va = *(const bf16x8*)(y + (size_t)a * 64 + lg * 8);
            bf16x8 vb = *(const bf16x8*)(y + (size_t)b * 64 + lg * 8);
#pragma unroll
            for (int k = 0; k < 8; ++k)
                s[k] += bf2f((unsigned short)va[k]) + bf2f((unsigned short)vb[k]);
        }
        if (j < r1) {
            bf16x8 va = *(const bf16x8*)(y + (size_t)csr[j] * 64 + lg * 8);
#pragma unroll
            for (int k = 0; k < 8; ++k) s[k] += bf2f((unsigned short)va[k]);
        }
        float inv = 1.f / fmaxf((float)(r1 - r0), 1.f);
        bf16x8 hb;
#pragma unroll
        for (int k = 0; k < 8; ++k) {
            float h = fmaf(s[k], inv, bf2f((unsigned short)z8[k]));
            unsigned short b = f2bf(h);
            hb[k] = (short)b;
            float hf = bf2f(b);
            ls[k] += hf; lq[k] += hf * hf;
        }
        *(bf16x8*)(zh2 + (size_t)i * 64 + lg * 8) = hb;
    }

#pragma unroll
    for (int k = 0; k < 8; ++k) {
        ls[k] += __shfl_xor(ls[k], 8, 64);
        ls[k] += __shfl_xor(ls[k], 16, 64);
        ls[k] += __shfl_xor(ls[k], 32, 64);
        lq[k] += __shfl_xor(lq[k], 8, 64);
        lq[k] += __shfl_xor(lq[k], 16, 64);
        lq[k] += __shfl_xor(lq[k], 32, 64);
    }
    __shared__ float red[2][4][64];
    int w = tid >> 6;
    if ((tid & 63) < 8) {
#pragma unroll
        for (int k = 0; k < 8; ++k) {
            red[0][w][lg * 8 + k] = ls[k];
            red[1][w][lg * 8 + k] = lq[k];
        }
    }
    __syncthreads();
    if (tid < 128) {
        int c = tid & 63;
        int half = tid >> 6;
        float v = red[half][0][c] + red[half][1][c] + red[half][2][c] + red[half][3][c];
        pstats[(size_t)tid * gridDim.x + blockIdx.x] = v;
    }
}

// ---------------------------------------------------------------------------
// Finalize via MFMA on PERM-space zh2: x2 = relu(bn2(h2)) in-register (coef2
// is perm space), 2 MFMAs against W3 indexed through orig(). One tile/wave.
__global__ __launch_bounds__(256) void k_finalize(
    const unsigned short* __restrict__ h2b,
    const float* __restrict__ t1, const float* __restrict__ v1,
    const float* __restrict__ coef2,
    const float* __restrict__ W3l, const float* __restrict__ W3r,
    float* __restrict__ tb, float* __restrict__ vb, int n) {
    int tid = threadIdx.x, w = tid >> 6, l = tid & 63, ln = l & 15, kg = l >> 4;

    float c2a[16], c2b[16];
#pragma unroll
    for (int j = 0; j < 8; ++j) {
        c2a[j]     = coef2[kg * 8 + j];       c2b[j]     = coef2[64 + kg * 8 + j];
        c2a[8 + j] = coef2[32 + kg * 8 + j];  c2b[8 + j] = coef2[96 + kg * 8 + j];
    }
    // W3 fragments in perm space: element j covers storage channel k',
    // original channel orig(k') = (k'&3)*16 + (k'>>2)
    bf16x8 b3a, b3b;
#pragma unroll
    for (int j = 0; j < 8; ++j) {
        int k0 = kg * 8 + j;
        int k1 = 32 + kg * 8 + j;
        int o0 = (k0 & 3) * 16 + (k0 >> 2);
        int o1 = (k1 & 3) * 16 + (k1 >> 2);
        float va = (ln == 0) ? W3l[o0] : ((ln == 1) ? W3r[o0] : 0.f);
        float vb = (ln == 0) ? W3l[o1] : ((ln == 1) ? W3r[o1] : 0.f);
        b3a[j] = (short)f2bf(va);
        b3b[j] = (short)f2bf(vb);
    }

    int t = blockIdx.x * 4 + w;
    int nt = (n + 15) >> 4;
    if (t >= nt) return;
    int i0 = t << 4;
    int row = i0 + ln;
    int rr = (row < n) ? row : (n - 1);
    const unsigned short* hr = h2b + (size_t)rr * 64 + kg * 8;
    bf16x8 r0 = *(const bf16x8*)hr;
    bf16x8 r1 = *(const bf16x8*)(hr + 32);
    bf16x8 u0, u1;
#pragma unroll
    for (int j = 0; j < 8; ++j) {
        float f0 = bf2f((unsigned short)r0[j]);
        float f1 = bf2f((unsigned short)r1[j]);
        u0[j] = (short)f2bf(fmaxf(0.f, fmaf(f0, c2a[j], c2b[j])));
        u1[j] = (short)f2bf(fmaxf(0.f, fmaf(f1, c2a[8 + j], c2b[8 + j])));
    }
    f32x4 acc = (f32x4){0.f, 0.f, 0.f, 0.f};
    acc = __builtin_amdgcn_mfma_f32_16x16x32_bf16(u0, b3a, acc, 0, 0, 0);
    acc = __builtin_amdgcn_mfma_f32_16x16x32_bf16(u1, b3b, acc, 0, 0, 0);
    if (ln < 2) {
        float* d = (ln == 0) ? tb : vb;
        const float* s1 = (ln == 0) ? t1 : v1;
#pragma unroll
        for (int r = 0; r < 4; ++r) {
            int orow = i0 + kg * 4 + r;
            if (orow < n) d[orow] = acc[r] + s1[orow];
        }
    }
}

// ---------------------------------------------------------------------------
__global__ void k_gather3(const float* __restrict__ tb, const float* __restrict__ vb,
                          const int* __restrict__ rowptr, const int* __restrict__ csr,
                          const float* __restrict__ b3, float* __restrict__ out, int n) {
    int i = blockIdx.x * blockDim.x + threadIdx.x;
    if (i >= n) return;
    int r0 = rowptr[i], r1 = rowptr[i + 1];
    float s = 0.f;
    int j = r0;
    for (; j + 3 < r1; j += 4)
        s += tb[csr[j]] + tb[csr[j + 1]] + tb[csr[j + 2]] + tb[csr[j + 3]];
    for (; j < r1; ++j) s += tb[csr[j]];
    float inv = 1.f / fmaxf((float)(r1 - r0), 1.f);
    out[i] = fmaf(s, inv, b3[0] + vb[i]);
}

// ---------------------------------------------------------------------------
// Workspace (4B units, N=500k, E=1.25M; cap 256 MiB = 67,108,864 units):
//   y 32N + zh2 32N + R 2N + t1 N + v1 N + rowptr N+1 + csr E
//   + bsums 2048 + pstats 128*2048 + pmom 14*2048 + small
//   = 68N + E + ~295k = ~35.5M units = 142 MB (safe)
extern "C" void kernel_launch(void* const* d_in, const int* in_sizes, int n_in,
                              void* d_out, int out_size, void* d_ws, size_t ws_size,
                              hipStream_t stream) {
    const float* x   = (const float*)d_in[0];
    const int*   ei  = (const int*)d_in[1];
    const float* W1l = (const float*)d_in[2];
    const float* b1  = (const float*)d_in[3];
    const float* W1r = (const float*)d_in[4];
    const float* g1  = (const float*)d_in[5];
    const float* be1 = (const float*)d_in[6];
    const float* W2l = (const float*)d_in[7];
    const float* b2  = (const float*)d_in[8];
    const float* W2r = (const float*)d_in[9];
    const float* g2  = (const float*)d_in[10];
    const float* be2 = (const float*)d_in[11];
    const float* W3l = (const float*)d_in[12];
    const float* b3  = (const float*)d_in[13];
    const float* W3r = (const float*)d_in[14];

    int N = in_sizes[0] / 2;
    int E = in_sizes[1] / 2;

    float* ws   = (float*)d_ws;
    size_t nn   = (size_t)N;
    unsigned short* y   = (unsigned short*)ws;             // 32N units
    unsigned short* zh2 = (unsigned short*)(ws + 32 * nn); // 32N units (z -> h2)
    float* R     = ws + 64 * nn;            // 2N time-shared: cursor -> agg1 -> tb/vb
    int*   cursor = (int*)R;
    float* agg1   = R;
    float* tb     = R;
    float* vb     = R + nn;
    float* t1     = ws + 66 * nn;           // N
    float* v1     = ws + 67 * nn;           // N
    int*   rowptr = (int*)(ws + 68 * nn);   // N+1 (doubles as histogram cnt)
    int*   csr    = rowptr + (N + 1);       // E
    int*   bsums  = csr + E;                // 2048
    float* pstats = (float*)(bsums + 2048); // 128 * 2048 partial stats
    float* pmom   = pstats + 128 * 2048;    // 14 * 2048 partial moments
    float* coef2  = pmom + 14 * 2048;       // 128: a2, b2 (perm space)
    float* fold   = coef2 + 128;            // 320: F0..F4
    int*   flag   = (int*)(fold + 320);     // 64

    hipMemsetAsync(rowptr, 0, (size_t)(N + 1) * sizeof(int), stream);

    k_detect<<<1, 1, 0, stream>>>(ei, flag);

    int ge = (E + 255) / 256;
    int gn = (N + 255) / 256;
    int nb = (N + 1023) / 1024;
    k_hist<<<ge, 256, 0, stream>>>(ei, flag, E, rowptr);
    k_scanA<<<nb, 256, 0, stream>>>(rowptr, N, bsums);
    k_scanB<<<1, 256, 0, stream>>>(bsums, nb, rowptr, N);
    k_scanC<<<nb, 256, 0, stream>>>(rowptr, N, bsums, cursor);
    {
        const int NPASS = 4;
        int span = (N + NPASS - 1) / NPASS;
        for (int p = 0; p < NPASS; ++p) {
            int lo = p * span;
            int hi = min(N, lo + span);
            k_fill_range<<<ge, 256, 0, stream>>>(ei, flag, E, cursor, csr, lo, hi);
        }
    }
    // cursor dead; R becomes agg1

    k_gather1m<<<gn, 256, 0, stream>>>(x, rowptr, csr, agg1, pmom, N);
    k_bnfold1<<<1, 256, 0, stream>>>(pmom, gn, W1l, b1, W1r, g1, be1, fold,
                                     1.0f / (float)N);

    k_dense_pre<<<2048, 256, 0, stream>>>(agg1, x, fold, W2l, b2, W2r, W3l, W3r,
                                          y, zh2, t1, v1, N);
    // agg1 dead after dense_pre

    k_gather2b<<<2048, 256, 0, stream>>>(y, rowptr, csr, zh2, pstats, N);
    k_sredfin<<<64, 256, 0, stream>>>(pstats, 2048, g2, be2, coef2, 1.0f / (float)N);

    // R becomes tb/vb
    int nt = (N + 15) / 16;
    k_finalize<<<(nt + 3) / 4, 256, 0, stream>>>(zh2, t1, v1, coef2,
                                                 W3l, W3r, tb, vb, N);
    k_gather3<<<gn, 256, 0, stream>>>(tb, vb, rowptr, csr, b3, (float*)d_out, N);
}

// Round 18
// 347.711 us; speedup vs baseline: 2.4801x; 1.0074x over previous
//
#include <hip/hip_runtime.h>

#define EPS 1e-5f

typedef __attribute__((ext_vector_type(8))) short bf16x8;
typedef __attribute__((ext_vector_type(4))) float f32x4;

__device__ __forceinline__ unsigned short f2bf(float f) {
    unsigned u = __float_as_uint(f);
    u += 0x7fffu + ((u >> 16) & 1u);
    return (unsigned short)(u >> 16);
}
__device__ __forceinline__ float bf2f(unsigned short s) {
    return __uint_as_float(((unsigned)s) << 16);
}

// Storage channel permutation for y/zh2: c' = (c&15)*4 + (c>>4).
// orig(c') = (c'&3)*16 + (c'>>2). Lets MFMA lanes store contiguous ushort4.

// ---------------------------------------------------------------------------
__global__ void k_detect(const int* __restrict__ ei, int* __restrict__ flag) {
    if (blockIdx.x == 0 && threadIdx.x == 0) {
        int is64 = 1;
        for (int k = 0; k < 16; ++k) is64 &= (ei[2 * k + 1] == 0) ? 1 : 0;
        *flag = is64;
    }
}

// Convert edge_index to packed int32 rows (one read of ei; all later passes
// read 5MB/pass instead of 10MB and lose the dtype branch).
__global__ void k_cvt(const int* __restrict__ ei, const int* __restrict__ flag,
                      int E, int* __restrict__ d32, int* __restrict__ s32) {
    int e = blockIdx.x * blockDim.x + threadIdx.x;
    if (e >= E) return;
    if (*flag) {
        s32[e] = (int)((const long long*)ei)[e];
        d32[e] = (int)((const long long*)ei)[E + e];
    } else {
        s32[e] = ei[e];
        d32[e] = ei[E + e];
    }
}

// ---------------------------------------------------------------------------
// CSR build: range-partitioned histogram (2 in-kernel passes) -> scan ->
// range-partitioned fill (4 in-kernel passes). Per-pass cnt/csr regions are
// L2-resident -> scattered 4B RMWs merge into full lines before writeback.
__global__ void k_hist2(const int* __restrict__ d32, int E, int ge,
                        int* __restrict__ cnt, int span) {
    int p = blockIdx.x / ge;
    int e = (blockIdx.x - p * ge) * blockDim.x + threadIdx.x;
    if (e >= E) return;
    int d = d32[e];
    int lo = p * span;
    if (d < lo || d >= lo + span) return;
    atomicAdd(&cnt[d], 1);
}

__device__ __forceinline__ int block_incl_scan(int v, int tid, int* total) {
    __shared__ int wsum[4];
    __shared__ int tot;
#pragma unroll
    for (int o = 1; o < 64; o <<= 1) {
        int u = __shfl_up(v, o, 64);
        if ((tid & 63) >= o) v += u;
    }
    if ((tid & 63) == 63) wsum[tid >> 6] = v;
    __syncthreads();
    int w = tid >> 6, add = 0;
    if (w > 0) add += wsum[0];
    if (w > 1) add += wsum[1];
    if (w > 2) add += wsum[2];
    v += add;
    if (tid == 255) tot = v;
    __syncthreads();
    *total = tot;
    __syncthreads();
    return v;
}

__global__ __launch_bounds__(256) void k_scanA(const int* __restrict__ cnt, int n,
                                               int* __restrict__ bsums) {
    int tid = threadIdx.x;
    int idx = blockIdx.x * 1024 + tid * 4;
    int s = 0;
#pragma unroll
    for (int k = 0; k < 4; ++k) { int i = idx + k; if (i < n) s += cnt[i]; }
#pragma unroll
    for (int o = 32; o > 0; o >>= 1) s += __shfl_xor(s, o, 64);
    __shared__ int ws[4];
    if ((tid & 63) == 0) ws[tid >> 6] = s;
    __syncthreads();
    if (tid == 0) bsums[blockIdx.x] = ws[0] + ws[1] + ws[2] + ws[3];
}

__global__ __launch_bounds__(256) void k_scanB(int* __restrict__ bsums, int nb,
                                               int* __restrict__ rowptr, int N) {
    int tid = threadIdx.x;
    __shared__ int sh_carry;
    if (tid == 0) sh_carry = 0;
    __syncthreads();
    int niter = (nb + 255) / 256;
    for (int it = 0; it < niter; ++it) {
        int i = it * 256 + tid;
        int v = (i < nb) ? bsums[i] : 0;
        int tot;
        int inc = block_incl_scan(v, tid, &tot);
        int carry = sh_carry;
        if (i < nb) bsums[i] = carry + inc - v;
        __syncthreads();
        if (tid == 0) sh_carry = carry + tot;
        __syncthreads();
    }
    if (tid == 0) rowptr[N] = sh_carry;
}

__global__ __launch_bounds__(256) void k_scanC(int* __restrict__ cnt_rowptr, int n,
                                               const int* __restrict__ bsums,
                                               int* __restrict__ cursor) {
    int tid = threadIdx.x;
    int idx = blockIdx.x * 1024 + tid * 4;
    int v[4]; int s = 0;
#pragma unroll
    for (int k = 0; k < 4; ++k) { int i = idx + k; v[k] = (i < n) ? cnt_rowptr[i] : 0; s += v[k]; }
    int tot;
    int inc = block_incl_scan(s, tid, &tot);
    int off = bsums[blockIdx.x] + inc - s;
#pragma unroll
    for (int k = 0; k < 4; ++k) {
        int i = idx + k;
        if (i < n) { cnt_rowptr[i] = off; cursor[i] = off; off += v[k]; }
    }
}

__global__ void k_fill4(const int* __restrict__ d32, const int* __restrict__ s32,
                        int E, int ge, int* __restrict__ cursor,
                        int* __restrict__ csr, int span) {
    int p = blockIdx.x / ge;
    int e = (blockIdx.x - p * ge) * blockDim.x + threadIdx.x;
    if (e >= E) return;
    int d = d32[e];
    int lo = p * span;
    if (d < lo || d >= lo + span) return;
    int pos = atomicAdd(&cursor[d], 1);
    csr[pos] = s32[e];
}

// ---------------------------------------------------------------------------
// Layer-1 gather fused with u-moments (u = (agg1, x), 14 scalars).
__global__ __launch_bounds__(256) void k_gather1m(
    const float* __restrict__ x, const int* __restrict__ rowptr,
    const int* __restrict__ csr, float* __restrict__ agg1,
    float* __restrict__ pmom, int n) {
    int tid = threadIdx.x;
    int i = blockIdx.x * 256 + tid;
    float m[14];
#pragma unroll
    for (int k = 0; k < 14; ++k) m[k] = 0.f;
    if (i < n) {
        int r0 = rowptr[i], r1 = rowptr[i + 1];
        float s0 = 0.f, s1 = 0.f;
        int j = r0;
        for (; j + 3 < r1; j += 4) {
            float2 v0 = ((const float2*)x)[csr[j]];
            float2 v1 = ((const float2*)x)[csr[j + 1]];
            float2 v2 = ((const float2*)x)[csr[j + 2]];
            float2 v3 = ((const float2*)x)[csr[j + 3]];
            s0 += v0.x + v1.x + v2.x + v3.x;
            s1 += v0.y + v1.y + v2.y + v3.y;
        }
        for (; j < r1; ++j) {
            float2 v = ((const float2*)x)[csr[j]];
            s0 += v.x; s1 += v.y;
        }
        float inv = 1.f / fmaxf((float)(r1 - r0), 1.f);
        float ax = s0 * inv, ay = s1 * inv;
        agg1[2 * i] = ax;
        agg1[2 * i + 1] = ay;
        float2 xv = ((const float2*)x)[i];
        m[0] = ax;        m[1] = ay;        m[2] = xv.x;      m[3] = xv.y;
        m[4] = ax * ax;   m[5] = ax * ay;   m[6] = ax * xv.x; m[7] = ax * xv.y;
        m[8] = ay * ay;   m[9] = ay * xv.x; m[10] = ay * xv.y;
        m[11] = xv.x * xv.x; m[12] = xv.x * xv.y; m[13] = xv.y * xv.y;
    }
#pragma unroll
    for (int k = 0; k < 14; ++k) {
#pragma unroll
        for (int o = 32; o > 0; o >>= 1) m[k] += __shfl_xor(m[k], o, 64);
    }
    __shared__ float red[4][14];
    int w = tid >> 6;
    if ((tid & 63) == 0) {
#pragma unroll
        for (int k = 0; k < 14; ++k) red[w][k] = m[k];
    }
    __syncthreads();
    if (tid < 14)
        pmom[(size_t)tid * gridDim.x + blockIdx.x] =
            red[0][tid] + red[1][tid] + red[2][tid] + red[3][tid];
}

// ---------------------------------------------------------------------------
// Reduce pmom partials + BN1-fold (1 block x 256).
__global__ __launch_bounds__(256) void k_bnfold1(
    const float* __restrict__ pmom, int gn,
    const float* __restrict__ W1l, const float* __restrict__ b1,
    const float* __restrict__ W1r,
    const float* __restrict__ g1, const float* __restrict__ be1,
    float* __restrict__ fold, float invN) {
    int tid = threadIdx.x;
    __shared__ float smom[14];
    __shared__ float ws[4];
    for (int k = 0; k < 14; ++k) {
        float s = 0.f;
        for (int idx = tid; idx < gn; idx += 256) s += pmom[(size_t)k * gn + idx];
#pragma unroll
        for (int o = 32; o > 0; o >>= 1) s += __shfl_xor(s, o, 64);
        if ((tid & 63) == 0) ws[tid >> 6] = s;
        __syncthreads();
        if (tid == 0) smom[k] = ws[0] + ws[1] + ws[2] + ws[3];
        __syncthreads();
    }
    if (tid < 64) {
        int c = tid;
        float w0 = W1l[c], w1 = W1l[64 + c], w2 = W1r[c], w3 = W1r[64 + c], w4 = b1[c];
        float lin = (smom[0] * w0 + smom[1] * w1 + smom[2] * w2 + smom[3] * w3) * invN;
        float mean = lin + w4;
        float q = smom[4] * w0 * w0 + smom[8] * w1 * w1 + smom[11] * w2 * w2 + smom[13] * w3 * w3
                + 2.f * (smom[5] * w0 * w1 + smom[6] * w0 * w2 + smom[7] * w0 * w3
                       + smom[9] * w1 * w2 + smom[10] * w1 * w3 + smom[12] * w2 * w3);
        float Eh2 = q * invN + 2.f * w4 * lin + w4 * w4;
        float var = Eh2 - mean * mean;
        float al = g1[c] * rsqrtf(var + EPS);
        float be = be1[c] - mean * al;
        fold[c]       = al * w0;
        fold[64 + c]  = al * w1;
        fold[128 + c] = al * w2;
        fold[192 + c] = al * w3;
        fold[256 + c] = al * w4 + be;
    }
}

// ---------------------------------------------------------------------------
// Fused: reduce pstats partials -> BN2 coefs (perm space; g2/be2 via orig()).
__global__ __launch_bounds__(256) void k_sredfin(
    const float* __restrict__ pstats, int nb,
    const float* __restrict__ g, const float* __restrict__ be,
    float* __restrict__ coef, float invN) {
    int c = blockIdx.x, tid = threadIdx.x;   // c = perm-space channel (0..63)
    float s = 0.f, q = 0.f;
    for (int i = tid; i < nb; i += 256) {
        s += pstats[(size_t)c * nb + i];
        q += pstats[(size_t)(64 + c) * nb + i];
    }
#pragma unroll
    for (int o = 32; o > 0; o >>= 1) {
        s += __shfl_xor(s, o, 64);
        q += __shfl_xor(q, o, 64);
    }
    __shared__ float ws[4], wq[4];
    if ((tid & 63) == 0) { ws[tid >> 6] = s; wq[tid >> 6] = q; }
    __syncthreads();
    if (tid == 0) {
        float S = ws[0] + ws[1] + ws[2] + ws[3];
        float Q = wq[0] + wq[1] + wq[2] + wq[3];
        float m = S * invN;
        float var = Q * invN - m * m;
        int o = (c & 3) * 16 + (c >> 2);      // original channel
        float a = g[o] * rsqrtf(var + EPS);
        coef[c] = a;
        coef[64 + c] = be[o] - m * a;
    }
}

// ---------------------------------------------------------------------------
// Pre-transform: x1 = relu(bn1-folded(agg1, x)) on the fly; y = x1@W2l;
// z = x1@W2r + b2; t1 = x1.W3l; v1 = x1.W3r. Direct PERMUTED ushort4 stores.
__global__ __launch_bounds__(256) void k_dense_pre(
    const float* __restrict__ agg1, const float* __restrict__ xin,
    const float* __restrict__ fold,
    const float* __restrict__ W2l, const float* __restrict__ b2,
    const float* __restrict__ W2r,
    const float* __restrict__ W3l, const float* __restrict__ W3r,
    unsigned short* __restrict__ y, unsigned short* __restrict__ z,
    float* __restrict__ t1, float* __restrict__ v1, int n) {
    __shared__ unsigned short lds_w[16 * 64 * 8];   // 16 KB (W frags only)
    int tid = threadIdx.x, w = tid >> 6, l = tid & 63, ln = l & 15, kg = l >> 4;

    for (int idx = tid; idx < 4096; idx += 256) {
        int k = idx >> 6, c = idx & 63;
        int lane = ((k >> 3) & 3) * 16 + (c & 15);
        int fbase = ((k >> 5) * 4 + (c >> 4)) * 64 + lane;
        lds_w[fbase * 8 + (k & 7)] = f2bf(W2l[idx]);
        lds_w[(8 * 64 + fbase) * 8 + (k & 7)] = f2bf(W2r[idx]);
    }
    __syncthreads();

    float bb[4];
#pragma unroll
    for (int cs = 0; cs < 4; ++cs) bb[cs] = b2[cs * 16 + ln];

    float F0[16], F1[16], F2[16], F3[16], F4[16];
#pragma unroll
    for (int j = 0; j < 8; ++j) {
        int c = kg * 8 + j;
        F0[j] = fold[c];       F1[j] = fold[64 + c];  F2[j] = fold[128 + c];
        F3[j] = fold[192 + c]; F4[j] = fold[256 + c];
        c += 32;
        F0[8 + j] = fold[c];       F1[8 + j] = fold[64 + c];  F2[8 + j] = fold[128 + c];
        F3[8 + j] = fold[192 + c]; F4[8 + j] = fold[256 + c];
    }
    bf16x8 b3a, b3b;
#pragma unroll
    for (int j = 0; j < 8; ++j) {
        float va = (ln == 0) ? W3l[kg * 8 + j] : ((ln == 1) ? W3r[kg * 8 + j] : 0.f);
        float vb = (ln == 0) ? W3l[32 + kg * 8 + j] : ((ln == 1) ? W3r[32 + kg * 8 + j] : 0.f);
        b3a[j] = (short)f2bf(va);
        b3b[j] = (short)f2bf(vb);
    }

    const bf16x8* wfrag = (const bf16x8*)lds_w;
    int nt = (n + 15) >> 4;
    int stride = gridDim.x * 4;

#define LOADH(T, A)                                                          \
    {                                                                        \
        int row_ = ((T) << 4) + ln;                                          \
        int rr_ = (row_ < n) ? row_ : (n - 1);                               \
        A##a = ((const float2*)agg1)[rr_];                                   \
        A##x = ((const float2*)xin)[rr_];                                    \
    }

#define PROCESSH(T, A)                                                       \
    {                                                                        \
        bf16x8 u0_, u1_;                                                     \
        _Pragma("unroll")                                                    \
        for (int j = 0; j < 8; ++j) {                                        \
            float h0_ = fmaf(A##a.x, F0[j], fmaf(A##a.y, F1[j],              \
                        fmaf(A##x.x, F2[j], fmaf(A##x.y, F3[j], F4[j]))));   \
            float h1_ = fmaf(A##a.x, F0[8 + j], fmaf(A##a.y, F1[8 + j],      \
                        fmaf(A##x.x, F2[8 + j], fmaf(A##x.y, F3[8 + j], F4[8 + j])))); \
            u0_[j] = (short)f2bf(fmaxf(0.f, h0_));                           \
            u1_[j] = (short)f2bf(fmaxf(0.f, h1_));                           \
        }                                                                    \
        f32x4 ya_[4], za_[4], a3_;                                           \
        _Pragma("unroll")                                                    \
        for (int cs = 0; cs < 4; ++cs) {                                     \
            ya_[cs] = (f32x4){0.f, 0.f, 0.f, 0.f};                           \
            za_[cs] = (f32x4){0.f, 0.f, 0.f, 0.f};                           \
        }                                                                    \
        a3_ = (f32x4){0.f, 0.f, 0.f, 0.f};                                   \
        _Pragma("unroll")                                                    \
        for (int cs = 0; cs < 4; ++cs) {                                     \
            ya_[cs] = __builtin_amdgcn_mfma_f32_16x16x32_bf16(u0_, wfrag[(0 * 4 + cs) * 64 + l], ya_[cs], 0, 0, 0);  \
            ya_[cs] = __builtin_amdgcn_mfma_f32_16x16x32_bf16(u1_, wfrag[(1 * 4 + cs) * 64 + l], ya_[cs], 0, 0, 0);  \
            za_[cs] = __builtin_amdgcn_mfma_f32_16x16x32_bf16(u0_, wfrag[(8 + cs) * 64 + l], za_[cs], 0, 0, 0);      \
            za_[cs] = __builtin_amdgcn_mfma_f32_16x16x32_bf16(u1_, wfrag[(12 + cs) * 64 + l], za_[cs], 0, 0, 0);     \
        }                                                                    \
        a3_ = __builtin_amdgcn_mfma_f32_16x16x32_bf16(u0_, b3a, a3_, 0, 0, 0); \
        a3_ = __builtin_amdgcn_mfma_f32_16x16x32_bf16(u1_, b3b, a3_, 0, 0, 0); \
        int base_ = (T) << 4;                                                \
        _Pragma("unroll")                                                    \
        for (int r = 0; r < 4; ++r) {                                        \
            int row_ = base_ + kg * 4 + r;                                   \
            if (row_ < n) {                                                  \
                ushort4 yv_, zv_;                                            \
                yv_.x = f2bf(ya_[0][r]); yv_.y = f2bf(ya_[1][r]);            \
                yv_.z = f2bf(ya_[2][r]); yv_.w = f2bf(ya_[3][r]);            \
                zv_.x = f2bf(za_[0][r] + bb[0]); zv_.y = f2bf(za_[1][r] + bb[1]); \
                zv_.z = f2bf(za_[2][r] + bb[2]); zv_.w = f2bf(za_[3][r] + bb[3]); \
                *(ushort4*)(y + (size_t)row_ * 64 + ln * 4) = yv_;           \
                *(ushort4*)(z + (size_t)row_ * 64 + ln * 4) = zv_;           \
            }                                                                \
        }                                                                    \
        if (ln < 2) {                                                        \
            float* d3_ = (ln == 0) ? t1 : v1;                                \
            _Pragma("unroll")                                                \
            for (int r = 0; r < 4; ++r) {                                    \
                int row_ = base_ + kg * 4 + r;                               \
                if (row_ < n) d3_[row_] = a3_[r];                            \
            }                                                                \
        }                                                                    \
    }

    float2 Pa, Px, Qa, Qx;
    int t = blockIdx.x * 4 + w;
    if (t < nt) {
        LOADH(t, P);
        while (t < nt) {
            int t1_ = t + stride;
            if (t1_ < nt) LOADH(t1_, Q);
            PROCESSH(t, P);
            int t2_ = t1_ + stride;
            if (t2_ < nt) LOADH(t2_, P);
            if (t1_ < nt) PROCESSH(t1_, Q);
            t = t2_;
        }
    }
#undef LOADH
#undef PROCESSH
}

// ---------------------------------------------------------------------------
// Gather + combine: h2_i = mean_j y[src_j] + z_i, in place on z (perm space).
// 8-lane groups, grid-stride. ATOMIC-FREE stats partials.
__global__ __launch_bounds__(256) void k_gather2b(
    const unsigned short* __restrict__ y, const int* __restrict__ rowptr,
    const int* __restrict__ csr, unsigned short* zh2,
    float* __restrict__ pstats, int n) {
    int tid = threadIdx.x;
    int lg = tid & 7;
    int gid0 = blockIdx.x * 32 + (tid >> 3);
    int gstep = gridDim.x * 32;
    float ls[8] = {0.f, 0.f, 0.f, 0.f, 0.f, 0.f, 0.f, 0.f};
    float lq[8] = {0.f, 0.f, 0.f, 0.f, 0.f, 0.f, 0.f, 0.f};

    for (int i = gid0; i < n; i += gstep) {
        bf16x8 z8 = *(const bf16x8*)(zh2 + (size_t)i * 64 + lg * 8);  // early
        int r0 = rowptr[i], r1 = rowptr[i + 1];
        float s[8] = {0.f, 0.f, 0.f, 0.f, 0.f, 0.f, 0.f, 0.f};
        int j = r0;
        for (; j + 1 < r1; j += 2) {
            int a = csr[j], b = csr[j + 1];
            bf16x8 va = *(const bf16x8*)(y + (size_t)a * 64 + lg * 8);
            bf16x8 vb = *(const bf16x8*)(y + (size_t)b * 64 + lg * 8);
#pragma unroll
            for (int k = 0; k < 8; ++k)
                s[k] += bf2f((unsigned short)va[k]) + bf2f((unsigned short)vb[k]);
        }
        if (j < r1) {
            bf16x8 va = *(const bf16x8*)(y + (size_t)csr[j] * 64 + lg * 8);
#pragma unroll
            for (int k = 0; k < 8; ++k) s[k] += bf2f((unsigned short)va[k]);
        }
        float inv = 1.f / fmaxf((float)(r1 - r0), 1.f);
        bf16x8 hb;
#pragma unroll
        for (int k = 0; k < 8; ++k) {
            float h = fmaf(s[k], inv, bf2f((unsigned short)z8[k]));
            unsigned short b = f2bf(h);
            hb[k] = (short)b;
            float hf = bf2f(b);
            ls[k] += hf; lq[k] += hf * hf;
        }
        *(bf16x8*)(zh2 + (size_t)i * 64 + lg * 8) = hb;
    }

#pragma unroll
    for (int k = 0; k < 8; ++k) {
        ls[k] += __shfl_xor(ls[k], 8, 64);
        ls[k] += __shfl_xor(ls[k], 16, 64);
        ls[k] += __shfl_xor(ls[k], 32, 64);
        lq[k] += __shfl_xor(lq[k], 8, 64);
        lq[k] += __shfl_xor(lq[k], 16, 64);
        lq[k] += __shfl_xor(lq[k], 32, 64);
    }
    __shared__ float red[2][4][64];
    int w = tid >> 6;
    if ((tid & 63) < 8) {
#pragma unroll
        for (int k = 0; k < 8; ++k) {
            red[0][w][lg * 8 + k] = ls[k];
            red[1][w][lg * 8 + k] = lq[k];
        }
    }
    __syncthreads();
    if (tid < 128) {
        int c = tid & 63;
        int half = tid >> 6;
        float v = red[half][0][c] + red[half][1][c] + red[half][2][c] + red[half][3][c];
        pstats[(size_t)tid * gridDim.x + blockIdx.x] = v;
    }
}

// ---------------------------------------------------------------------------
// Finalize via MFMA on PERM-space zh2. One tile per wave.
__global__ __launch_bounds__(256) void k_finalize(
    const unsigned short* __restrict__ h2b,
    const float* __restrict__ t1, const float* __restrict__ v1,
    const float* __restrict__ coef2,
    const float* __restrict__ W3l, const float* __restrict__ W3r,
    float* __restrict__ tb, float* __restrict__ vb, int n) {
    int tid = threadIdx.x, w = tid >> 6, l = tid & 63, ln = l & 15, kg = l >> 4;

    float c2a[16], c2b[16];
#pragma unroll
    for (int j = 0; j < 8; ++j) {
        c2a[j]     = coef2[kg * 8 + j];       c2b[j]     = coef2[64 + kg * 8 + j];
        c2a[8 + j] = coef2[32 + kg * 8 + j];  c2b[8 + j] = coef2[96 + kg * 8 + j];
    }
    bf16x8 b3a, b3b;
#pragma unroll
    for (int j = 0; j < 8; ++j) {
        int k0 = kg * 8 + j;
        int k1 = 32 + kg * 8 + j;
        int o0 = (k0 & 3) * 16 + (k0 >> 2);
        int o1 = (k1 & 3) * 16 + (k1 >> 2);
        float va = (ln == 0) ? W3l[o0] : ((ln == 1) ? W3r[o0] : 0.f);
        float vb = (ln == 0) ? W3l[o1] : ((ln == 1) ? W3r[o1] : 0.f);
        b3a[j] = (short)f2bf(va);
        b3b[j] = (short)f2bf(vb);
    }

    int t = blockIdx.x * 4 + w;
    int nt = (n + 15) >> 4;
    if (t >= nt) return;
    int i0 = t << 4;
    int row = i0 + ln;
    int rr = (row < n) ? row : (n - 1);
    const unsigned short* hr = h2b + (size_t)rr * 64 + kg * 8;
    bf16x8 r0 = *(const bf16x8*)hr;
    bf16x8 r1 = *(const bf16x8*)(hr + 32);
    bf16x8 u0, u1;
#pragma unroll
    for (int j = 0; j < 8; ++j) {
        float f0 = bf2f((unsigned short)r0[j]);
        float f1 = bf2f((unsigned short)r1[j]);
        u0[j] = (short)f2bf(fmaxf(0.f, fmaf(f0, c2a[j], c2b[j])));
        u1[j] = (short)f2bf(fmaxf(0.f, fmaf(f1, c2a[8 + j], c2b[8 + j])));
    }
    f32x4 acc = (f32x4){0.f, 0.f, 0.f, 0.f};
    acc = __builtin_amdgcn_mfma_f32_16x16x32_bf16(u0, b3a, acc, 0, 0, 0);
    acc = __builtin_amdgcn_mfma_f32_16x16x32_bf16(u1, b3b, acc, 0, 0, 0);
    if (ln < 2) {
        float* d = (ln == 0) ? tb : vb;
        const float* s1 = (ln == 0) ? t1 : v1;
#pragma unroll
        for (int r = 0; r < 4; ++r) {
            int orow = i0 + kg * 4 + r;
            if (orow < n) d[orow] = acc[r] + s1[orow];
        }
    }
}

// ---------------------------------------------------------------------------
__global__ void k_gather3(const float* __restrict__ tb, const float* __restrict__ vb,
                          const int* __restrict__ rowptr, const int* __restrict__ csr,
                          const float* __restrict__ b3, float* __restrict__ out, int n) {
    int i = blockIdx.x * blockDim.x + threadIdx.x;
    if (i >= n) return;
    int r0 = rowptr[i], r1 = rowptr[i + 1];
    float s = 0.f;
    int j = r0;
    for (; j + 3 < r1; j += 4)
        s += tb[csr[j]] + tb[csr[j + 1]] + tb[csr[j + 2]] + tb[csr[j + 3]];
    for (; j < r1; ++j) s += tb[csr[j]];
    float inv = 1.f / fmaxf((float)(r1 - r0), 1.f);
    out[i] = fmaf(s, inv, b3[0] + vb[i]);
}

// ---------------------------------------------------------------------------
// Workspace (4B units, N=500k, E=1.25M; cap 256 MiB = 67,108,864 units):
//   y 32N + zh2 32N + R 2N + t1 N + v1 N + rowptr N+1 + csr E + d32 E + s32 E
//   + bsums 2048 + pstats 128*2048 + pmom 14*2048 + small
//   = 68N + 3E + ~295k = ~38.1M units = 152 MB (safe)
extern "C" void kernel_launch(void* const* d_in, const int* in_sizes, int n_in,
                              void* d_out, int out_size, void* d_ws, size_t ws_size,
                              hipStream_t stream) {
    const float* x   = (const float*)d_in[0];
    const int*   ei  = (const int*)d_in[1];
    const float* W1l = (const float*)d_in[2];
    const float* b1  = (const float*)d_in[3];
    const float* W1r = (const float*)d_in[4];
    const float* g1  = (const float*)d_in[5];
    const float* be1 = (const float*)d_in[6];
    const float* W2l = (const float*)d_in[7];
    const float* b2  = (const float*)d_in[8];
    const float* W2r = (const float*)d_in[9];
    const float* g2  = (const float*)d_in[10];
    const float* be2 = (const float*)d_in[11];
    const float* W3l = (const float*)d_in[12];
    const float* b3  = (const float*)d_in[13];
    const float* W3r = (const float*)d_in[14];

    int N = in_sizes[0] / 2;
    int E = in_sizes[1] / 2;

    float* ws   = (float*)d_ws;
    size_t nn   = (size_t)N;
    unsigned short* y   = (unsigned short*)ws;             // 32N units
    unsigned short* zh2 = (unsigned short*)(ws + 32 * nn); // 32N units (z -> h2)
    float* R     = ws + 64 * nn;            // 2N time-shared: cursor -> agg1 -> tb/vb
    int*   cursor = (int*)R;
    float* agg1   = R;
    float* tb     = R;
    float* vb     = R + nn;
    float* t1     = ws + 66 * nn;           // N
    float* v1     = ws + 67 * nn;           // N
    int*   rowptr = (int*)(ws + 68 * nn);   // N+1 (doubles as histogram cnt)
    int*   csr    = rowptr + (N + 1);       // E
    int*   d32    = csr + E;                // E
    int*   s32    = d32 + E;                // E
    int*   bsums  = s32 + E;                // 2048
    float* pstats = (float*)(bsums + 2048); // 128 * 2048 partial stats
    float* pmom   = pstats + 128 * 2048;    // 14 * 2048 partial moments
    float* coef2  = pmom + 14 * 2048;       // 128: a2, b2 (perm space)
    float* fold   = coef2 + 128;            // 320: F0..F4
    int*   flag   = (int*)(fold + 320);     // 64

    hipMemsetAsync(rowptr, 0, (size_t)(N + 1) * sizeof(int), stream);

    k_detect<<<1, 1, 0, stream>>>(ei, flag);

    int ge = (E + 255) / 256;
    int gn = (N + 255) / 256;
    int nb = (N + 1023) / 1024;

    k_cvt<<<ge, 256, 0, stream>>>(ei, flag, E, d32, s32);

    // Range-partitioned histogram: 2 in-kernel passes (cnt region ~1MB/pass).
    {
        int span = (N + 1) / 2;
        k_hist2<<<2 * ge, 256, 0, stream>>>(d32, E, ge, rowptr, span);
    }
    k_scanA<<<nb, 256, 0, stream>>>(rowptr, N, bsums);
    k_scanB<<<1, 256, 0, stream>>>(bsums, nb, rowptr, N);
    k_scanC<<<nb, 256, 0, stream>>>(rowptr, N, bsums, cursor);
    // Range-partitioned fill: 4 in-kernel passes (csr region ~1.25MB/pass).
    {
        int span = (N + 3) / 4;
        k_fill4<<<4 * ge, 256, 0, stream>>>(d32, s32, E, ge, cursor, csr, span);
    }
    // cursor dead; R becomes agg1

    k_gather1m<<<gn, 256, 0, stream>>>(x, rowptr, csr, agg1, pmom, N);
    k_bnfold1<<<1, 256, 0, stream>>>(pmom, gn, W1l, b1, W1r, g1, be1, fold,
                                     1.0f / (float)N);

    k_dense_pre<<<2048, 256, 0, stream>>>(agg1, x, fold, W2l, b2, W2r, W3l, W3r,
                                          y, zh2, t1, v1, N);
    // agg1 dead after dense_pre

    k_gather2b<<<2048, 256, 0, stream>>>(y, rowptr, csr, zh2, pstats, N);
    k_sredfin<<<64, 256, 0, stream>>>(pstats, 2048, g2, be2, coef2, 1.0f / (float)N);

    // R becomes tb/vb
    int nt = (N + 15) / 16;
    k_finalize<<<(nt + 3) / 4, 256, 0, stream>>>(zh2, t1, v1, coef2,
                                                 W3l, W3r, tb, vb, N);
    k_gather3<<<gn, 256, 0, stream>>>(tb, vb, rowptr, csr, b3, (float*)d_out, N);
}

// Round 19
// 339.325 us; speedup vs baseline: 2.5414x; 1.0247x over previous
//
#include <hip/hip_runtime.h>

#define EPS 1e-5f

typedef __attribute__((ext_vector_type(8))) short bf16x8;
typedef __attribute__((ext_vector_type(4))) float f32x4;

__device__ __forceinline__ unsigned short f2bf(float f) {
    unsigned u = __float_as_uint(f);
    u += 0x7fffu + ((u >> 16) & 1u);
    return (unsigned short)(u >> 16);
}
__device__ __forceinline__ float bf2f(unsigned short s) {
    return __uint_as_float(((unsigned)s) << 16);
}

// Storage channel permutation for y/zh2: c' = (c&15)*4 + (c>>4).
// orig(c') = (c'&3)*16 + (c'>>2). Lets MFMA lanes store contiguous ushort4.

// ---------------------------------------------------------------------------
__global__ void k_detect(const int* __restrict__ ei, int* __restrict__ flag) {
    if (blockIdx.x == 0 && threadIdx.x == 0) {
        int is64 = 1;
        for (int k = 0; k < 16; ++k) is64 &= (ei[2 * k + 1] == 0) ? 1 : 0;
        *flag = is64;
    }
}

// Convert edge_index to packed int32 rows.
__global__ void k_cvt(const int* __restrict__ ei, const int* __restrict__ flag,
                      int E, int* __restrict__ d32, int* __restrict__ s32) {
    int e = blockIdx.x * blockDim.x + threadIdx.x;
    if (e >= E) return;
    if (*flag) {
        s32[e] = (int)((const long long*)ei)[e];
        d32[e] = (int)((const long long*)ei)[E + e];
    } else {
        s32[e] = ei[e];
        d32[e] = ei[E + e];
    }
}

// ---------------------------------------------------------------------------
// CSR build with XCD-ALIGNED range partitioning: range p = blockIdx & 7 so
// all blocks updating dst range p land on XCD p (blockIdx round-robins across
// the 8 XCDs). Range-p's cnt/cursor/csr lines then live in exactly ONE
// private L2 -> full-line writebacks (fixes the 8x cross-XCD write
// amplification measured in rounds 14-18: WRITE 70-87MB for ~7MB logical).
__global__ void k_hist8(const int* __restrict__ d32, int E,
                        int* __restrict__ cnt, int span) {
    int p = blockIdx.x & 7;
    int e = (blockIdx.x >> 3) * blockDim.x + threadIdx.x;
    if (e >= E) return;
    int d = d32[e];
    int lo = p * span;
    if (d < lo || d >= lo + span) return;
    atomicAdd(&cnt[d], 1);
}

__device__ __forceinline__ int block_incl_scan(int v, int tid, int* total) {
    __shared__ int wsum[4];
    __shared__ int tot;
#pragma unroll
    for (int o = 1; o < 64; o <<= 1) {
        int u = __shfl_up(v, o, 64);
        if ((tid & 63) >= o) v += u;
    }
    if ((tid & 63) == 63) wsum[tid >> 6] = v;
    __syncthreads();
    int w = tid >> 6, add = 0;
    if (w > 0) add += wsum[0];
    if (w > 1) add += wsum[1];
    if (w > 2) add += wsum[2];
    v += add;
    if (tid == 255) tot = v;
    __syncthreads();
    *total = tot;
    __syncthreads();
    return v;
}

__global__ __launch_bounds__(256) void k_scanA(const int* __restrict__ cnt, int n,
                                               int* __restrict__ bsums) {
    int tid = threadIdx.x;
    int idx = blockIdx.x * 1024 + tid * 4;
    int s = 0;
#pragma unroll
    for (int k = 0; k < 4; ++k) { int i = idx + k; if (i < n) s += cnt[i]; }
#pragma unroll
    for (int o = 32; o > 0; o >>= 1) s += __shfl_xor(s, o, 64);
    __shared__ int ws[4];
    if ((tid & 63) == 0) ws[tid >> 6] = s;
    __syncthreads();
    if (tid == 0) bsums[blockIdx.x] = ws[0] + ws[1] + ws[2] + ws[3];
}

__global__ __launch_bounds__(256) void k_scanB(int* __restrict__ bsums, int nb,
                                               int* __restrict__ rowptr, int N) {
    int tid = threadIdx.x;
    __shared__ int sh_carry;
    if (tid == 0) sh_carry = 0;
    __syncthreads();
    int niter = (nb + 255) / 256;
    for (int it = 0; it < niter; ++it) {
        int i = it * 256 + tid;
        int v = (i < nb) ? bsums[i] : 0;
        int tot;
        int inc = block_incl_scan(v, tid, &tot);
        int carry = sh_carry;
        if (i < nb) bsums[i] = carry + inc - v;
        __syncthreads();
        if (tid == 0) sh_carry = carry + tot;
        __syncthreads();
    }
    if (tid == 0) rowptr[N] = sh_carry;
}

__global__ __launch_bounds__(256) void k_scanC(int* __restrict__ cnt_rowptr, int n,
                                               const int* __restrict__ bsums,
                                               int* __restrict__ cursor) {
    int tid = threadIdx.x;
    int idx = blockIdx.x * 1024 + tid * 4;
    int v[4]; int s = 0;
#pragma unroll
    for (int k = 0; k < 4; ++k) { int i = idx + k; v[k] = (i < n) ? cnt_rowptr[i] : 0; s += v[k]; }
    int tot;
    int inc = block_incl_scan(s, tid, &tot);
    int off = bsums[blockIdx.x] + inc - s;
#pragma unroll
    for (int k = 0; k < 4; ++k) {
        int i = idx + k;
        if (i < n) { cnt_rowptr[i] = off; cursor[i] = off; off += v[k]; }
    }
}

__global__ void k_fill8(const int* __restrict__ d32, const int* __restrict__ s32,
                        int E, int* __restrict__ cursor,
                        int* __restrict__ csr, int span) {
    int p = blockIdx.x & 7;
    int e = (blockIdx.x >> 3) * blockDim.x + threadIdx.x;
    if (e >= E) return;
    int d = d32[e];
    int lo = p * span;
    if (d < lo || d >= lo + span) return;
    int pos = atomicAdd(&cursor[d], 1);
    csr[pos] = s32[e];
}

// ---------------------------------------------------------------------------
// Layer-1 gather fused with u-moments (u = (agg1, x), 14 scalars).
__global__ __launch_bounds__(256) void k_gather1m(
    const float* __restrict__ x, const int* __restrict__ rowptr,
    const int* __restrict__ csr, float* __restrict__ agg1,
    float* __restrict__ pmom, int n) {
    int tid = threadIdx.x;
    int i = blockIdx.x * 256 + tid;
    float m[14];
#pragma unroll
    for (int k = 0; k < 14; ++k) m[k] = 0.f;
    if (i < n) {
        int r0 = rowptr[i], r1 = rowptr[i + 1];
        float s0 = 0.f, s1 = 0.f;
        int j = r0;
        for (; j + 3 < r1; j += 4) {
            float2 v0 = ((const float2*)x)[csr[j]];
            float2 v1 = ((const float2*)x)[csr[j + 1]];
            float2 v2 = ((const float2*)x)[csr[j + 2]];
            float2 v3 = ((const float2*)x)[csr[j + 3]];
            s0 += v0.x + v1.x + v2.x + v3.x;
            s1 += v0.y + v1.y + v2.y + v3.y;
        }
        for (; j < r1; ++j) {
            float2 v = ((const float2*)x)[csr[j]];
            s0 += v.x; s1 += v.y;
        }
        float inv = 1.f / fmaxf((float)(r1 - r0), 1.f);
        float ax = s0 * inv, ay = s1 * inv;
        agg1[2 * i] = ax;
        agg1[2 * i + 1] = ay;
        float2 xv = ((const float2*)x)[i];
        m[0] = ax;        m[1] = ay;        m[2] = xv.x;      m[3] = xv.y;
        m[4] = ax * ax;   m[5] = ax * ay;   m[6] = ax * xv.x; m[7] = ax * xv.y;
        m[8] = ay * ay;   m[9] = ay * xv.x; m[10] = ay * xv.y;
        m[11] = xv.x * xv.x; m[12] = xv.x * xv.y; m[13] = xv.y * xv.y;
    }
#pragma unroll
    for (int k = 0; k < 14; ++k) {
#pragma unroll
        for (int o = 32; o > 0; o >>= 1) m[k] += __shfl_xor(m[k], o, 64);
    }
    __shared__ float red[4][14];
    int w = tid >> 6;
    if ((tid & 63) == 0) {
#pragma unroll
        for (int k = 0; k < 14; ++k) red[w][k] = m[k];
    }
    __syncthreads();
    if (tid < 14)
        pmom[(size_t)tid * gridDim.x + blockIdx.x] =
            red[0][tid] + red[1][tid] + red[2][tid] + red[3][tid];
}

// ---------------------------------------------------------------------------
// Reduce pmom partials + BN1-fold (1 block x 256).
__global__ __launch_bounds__(256) void k_bnfold1(
    const float* __restrict__ pmom, int gn,
    const float* __restrict__ W1l, const float* __restrict__ b1,
    const float* __restrict__ W1r,
    const float* __restrict__ g1, const float* __restrict__ be1,
    float* __restrict__ fold, float invN) {
    int tid = threadIdx.x;
    __shared__ float smom[14];
    __shared__ float ws[4];
    for (int k = 0; k < 14; ++k) {
        float s = 0.f;
        for (int idx = tid; idx < gn; idx += 256) s += pmom[(size_t)k * gn + idx];
#pragma unroll
        for (int o = 32; o > 0; o >>= 1) s += __shfl_xor(s, o, 64);
        if ((tid & 63) == 0) ws[tid >> 6] = s;
        __syncthreads();
        if (tid == 0) smom[k] = ws[0] + ws[1] + ws[2] + ws[3];
        __syncthreads();
    }
    if (tid < 64) {
        int c = tid;
        float w0 = W1l[c], w1 = W1l[64 + c], w2 = W1r[c], w3 = W1r[64 + c], w4 = b1[c];
        float lin = (smom[0] * w0 + smom[1] * w1 + smom[2] * w2 + smom[3] * w3) * invN;
        float mean = lin + w4;
        float q = smom[4] * w0 * w0 + smom[8] * w1 * w1 + smom[11] * w2 * w2 + smom[13] * w3 * w3
                + 2.f * (smom[5] * w0 * w1 + smom[6] * w0 * w2 + smom[7] * w0 * w3
                       + smom[9] * w1 * w2 + smom[10] * w1 * w3 + smom[12] * w2 * w3);
        float Eh2 = q * invN + 2.f * w4 * lin + w4 * w4;
        float var = Eh2 - mean * mean;
        float al = g1[c] * rsqrtf(var + EPS);
        float be = be1[c] - mean * al;
        fold[c]       = al * w0;
        fold[64 + c]  = al * w1;
        fold[128 + c] = al * w2;
        fold[192 + c] = al * w3;
        fold[256 + c] = al * w4 + be;
    }
}

// ---------------------------------------------------------------------------
// Fused: reduce pstats partials -> BN2 coefs (perm space; g2/be2 via orig()).
__global__ __launch_bounds__(256) void k_sredfin(
    const float* __restrict__ pstats, int nb,
    const float* __restrict__ g, const float* __restrict__ be,
    float* __restrict__ coef, float invN) {
    int c = blockIdx.x, tid = threadIdx.x;   // c = perm-space channel (0..63)
    float s = 0.f, q = 0.f;
    for (int i = tid; i < nb; i += 256) {
        s += pstats[(size_t)c * nb + i];
        q += pstats[(size_t)(64 + c) * nb + i];
    }
#pragma unroll
    for (int o = 32; o > 0; o >>= 1) {
        s += __shfl_xor(s, o, 64);
        q += __shfl_xor(q, o, 64);
    }
    __shared__ float ws[4], wq[4];
    if ((tid & 63) == 0) { ws[tid >> 6] = s; wq[tid >> 6] = q; }
    __syncthreads();
    if (tid == 0) {
        float S = ws[0] + ws[1] + ws[2] + ws[3];
        float Q = wq[0] + wq[1] + wq[2] + wq[3];
        float m = S * invN;
        float var = Q * invN - m * m;
        int o = (c & 3) * 16 + (c >> 2);      // original channel
        float a = g[o] * rsqrtf(var + EPS);
        coef[c] = a;
        coef[64 + c] = be[o] - m * a;
    }
}

// ---------------------------------------------------------------------------
// Pre-transform: x1 = relu(bn1-folded(agg1, x)) on the fly; y = x1@W2l;
// z = x1@W2r + b2; t1 = x1.W3l; v1 = x1.W3r. Direct PERMUTED ushort4 stores.
__global__ __launch_bounds__(256) void k_dense_pre(
    const float* __restrict__ agg1, const float* __restrict__ xin,
    const float* __restrict__ fold,
    const float* __restrict__ W2l, const float* __restrict__ b2,
    const float* __restrict__ W2r,
    const float* __restrict__ W3l, const float* __restrict__ W3r,
    unsigned short* __restrict__ y, unsigned short* __restrict__ z,
    float* __restrict__ t1, float* __restrict__ v1, int n) {
    __shared__ unsigned short lds_w[16 * 64 * 8];   // 16 KB (W frags only)
    int tid = threadIdx.x, w = tid >> 6, l = tid & 63, ln = l & 15, kg = l >> 4;

    for (int idx = tid; idx < 4096; idx += 256) {
        int k = idx >> 6, c = idx & 63;
        int lane = ((k >> 3) & 3) * 16 + (c & 15);
        int fbase = ((k >> 5) * 4 + (c >> 4)) * 64 + lane;
        lds_w[fbase * 8 + (k & 7)] = f2bf(W2l[idx]);
        lds_w[(8 * 64 + fbase) * 8 + (k & 7)] = f2bf(W2r[idx]);
    }
    __syncthreads();

    float bb[4];
#pragma unroll
    for (int cs = 0; cs < 4; ++cs) bb[cs] = b2[cs * 16 + ln];

    float F0[16], F1[16], F2[16], F3[16], F4[16];
#pragma unroll
    for (int j = 0; j < 8; ++j) {
        int c = kg * 8 + j;
        F0[j] = fold[c];       F1[j] = fold[64 + c];  F2[j] = fold[128 + c];
        F3[j] = fold[192 + c]; F4[j] = fold[256 + c];
        c += 32;
        F0[8 + j] = fold[c];       F1[8 + j] = fold[64 + c];  F2[8 + j] = fold[128 + c];
        F3[8 + j] = fold[192 + c]; F4[8 + j] = fold[256 + c];
    }
    bf16x8 b3a, b3b;
#pragma unroll
    for (int j = 0; j < 8; ++j) {
        float va = (ln == 0) ? W3l[kg * 8 + j] : ((ln == 1) ? W3r[kg * 8 + j] : 0.f);
        float vb = (ln == 0) ? W3l[32 + kg * 8 + j] : ((ln == 1) ? W3r[32 + kg * 8 + j] : 0.f);
        b3a[j] = (short)f2bf(va);
        b3b[j] = (short)f2bf(vb);
    }

    const bf16x8* wfrag = (const bf16x8*)lds_w;
    int nt = (n + 15) >> 4;
    int stride = gridDim.x * 4;

#define LOADH(T, A)                                                          \
    {                                                                        \
        int row_ = ((T) << 4) + ln;                                          \
        int rr_ = (row_ < n) ? row_ : (n - 1);                               \
        A##a = ((const float2*)agg1)[rr_];                                   \
        A##x = ((const float2*)xin)[rr_];                                    \
    }

#define PROCESSH(T, A)                                                       \
    {                                                                        \
        bf16x8 u0_, u1_;                                                     \
        _Pragma("unroll")                                                    \
        for (int j = 0; j < 8; ++j) {                                        \
            float h0_ = fmaf(A##a.x, F0[j], fmaf(A##a.y, F1[j],              \
                        fmaf(A##x.x, F2[j], fmaf(A##x.y, F3[j], F4[j]))));   \
            float h1_ = fmaf(A##a.x, F0[8 + j], fmaf(A##a.y, F1[8 + j],      \
                        fmaf(A##x.x, F2[8 + j], fmaf(A##x.y, F3[8 + j], F4[8 + j])))); \
            u0_[j] = (short)f2bf(fmaxf(0.f, h0_));                           \
            u1_[j] = (short)f2bf(fmaxf(0.f, h1_));                           \
        }                                                                    \
        f32x4 ya_[4], za_[4], a3_;                                           \
        _Pragma("unroll")                                                    \
        for (int cs = 0; cs < 4; ++cs) {                                     \
            ya_[cs] = (f32x4){0.f, 0.f, 0.f, 0.f};                           \
            za_[cs] = (f32x4){0.f, 0.f, 0.f, 0.f};                           \
        }                                                                    \
        a3_ = (f32x4){0.f, 0.f, 0.f, 0.f};                                   \
        _Pragma("unroll")                                                    \
        for (int cs = 0; cs < 4; ++cs) {                                     \
            ya_[cs] = __builtin_amdgcn_mfma_f32_16x16x32_bf16(u0_, wfrag[(0 * 4 + cs) * 64 + l], ya_[cs], 0, 0, 0);  \
            ya_[cs] = __builtin_amdgcn_mfma_f32_16x16x32_bf16(u1_, wfrag[(1 * 4 + cs) * 64 + l], ya_[cs], 0, 0, 0);  \
            za_[cs] = __builtin_amdgcn_mfma_f32_16x16x32_bf16(u0_, wfrag[(8 + cs) * 64 + l], za_[cs], 0, 0, 0);      \
            za_[cs] = __builtin_amdgcn_mfma_f32_16x16x32_bf16(u1_, wfrag[(12 + cs) * 64 + l], za_[cs], 0, 0, 0);     \
        }                                                                    \
        a3_ = __builtin_amdgcn_mfma_f32_16x16x32_bf16(u0_, b3a, a3_, 0, 0, 0); \
        a3_ = __builtin_amdgcn_mfma_f32_16x16x32_bf16(u1_, b3b, a3_, 0, 0, 0); \
        int base_ = (T) << 4;                                                \
        _Pragma("unroll")                                                    \
        for (int r = 0; r < 4; ++r) {                                        \
            int row_ = base_ + kg * 4 + r;                                   \
            if (row_ < n) {                                                  \
                ushort4 yv_, zv_;                                            \
                yv_.x = f2bf(ya_[0][r]); yv_.y = f2bf(ya_[1][r]);            \
                yv_.z = f2bf(ya_[2][r]); yv_.w = f2bf(ya_[3][r]);            \
                zv_.x = f2bf(za_[0][r] + bb[0]); zv_.y = f2bf(za_[1][r] + bb[1]); \
                zv_.z = f2bf(za_[2][r] + bb[2]); zv_.w = f2bf(za_[3][r] + bb[3]); \
                *(ushort4*)(y + (size_t)row_ * 64 + ln * 4) = yv_;           \
                *(ushort4*)(z + (size_t)row_ * 64 + ln * 4) = zv_;           \
            }                                                                \
        }                                                                    \
        if (ln < 2) {                                                        \
            float* d3_ = (ln == 0) ? t1 : v1;                                \
            _Pragma("unroll")                                                \
            for (int r = 0; r < 4; ++r) {                                    \
                int row_ = base_ + kg * 4 + r;                               \
                if (row_ < n) d3_[row_] = a3_[r];                            \
            }                                                                \
        }                                                                    \
    }

    float2 Pa, Px, Qa, Qx;
    int t = blockIdx.x * 4 + w;
    if (t < nt) {
        LOADH(t, P);
        while (t < nt) {
            int t1_ = t + stride;
            if (t1_ < nt) LOADH(t1_, Q);
            PROCESSH(t, P);
            int t2_ = t1_ + stride;
            if (t2_ < nt) LOADH(t2_, P);
            if (t1_ < nt) PROCESSH(t1_, Q);
            t = t2_;
        }
    }
#undef LOADH
#undef PROCESSH
}

// ---------------------------------------------------------------------------
// Gather + combine: h2_i = mean_j y[src_j] + z_i, in place on z (perm space).
// 8-lane groups, grid-stride. ATOMIC-FREE stats partials.
__global__ __launch_bounds__(256) void k_gather2b(
    const unsigned short* __restrict__ y, const int* __restrict__ rowptr,
    const int* __restrict__ csr, unsigned short* zh2,
    float* __restrict__ pstats, int n) {
    int tid = threadIdx.x;
    int lg = tid & 7;
    int gid0 = blockIdx.x * 32 + (tid >> 3);
    int gstep = gridDim.x * 32;
    float ls[8] = {0.f, 0.f, 0.f, 0.f, 0.f, 0.f, 0.f, 0.f};
    float lq[8] = {0.f, 0.f, 0.f, 0.f, 0.f, 0.f, 0.f, 0.f};

    for (int i = gid0; i < n; i += gstep) {
        bf16x8 z8 = *(const bf16x8*)(zh2 + (size_t)i * 64 + lg * 8);  // early
        int r0 = rowptr[i], r1 = rowptr[i + 1];
        float s[8] = {0.f, 0.f, 0.f, 0.f, 0.f, 0.f, 0.f, 0.f};
        int j = r0;
        for (; j + 1 < r1; j += 2) {
            int a = csr[j], b = csr[j + 1];
            bf16x8 va = *(const bf16x8*)(y + (size_t)a * 64 + lg * 8);
            bf16x8 vb = *(const bf16x8*)(y + (size_t)b * 64 + lg * 8);
#pragma unroll
            for (int k = 0; k < 8; ++k)
                s[k] += bf2f((unsigned short)va[k]) + bf2f((unsigned short)vb[k]);
        }
        if (j < r1) {
            bf16x8 va = *(const bf16x8*)(y + (size_t)csr[j] * 64 + lg * 8);
#pragma unroll
            for (int k = 0; k < 8; ++k) s[k] += bf2f((unsigned short)va[k]);
        }
        float inv = 1.f / fmaxf((float)(r1 - r0), 1.f);
        bf16x8 hb;
#pragma unroll
        for (int k = 0; k < 8; ++k) {
            float h = fmaf(s[k], inv, bf2f((unsigned short)z8[k]));
            unsigned short b = f2bf(h);
            hb[k] = (short)b;
            float hf = bf2f(b);
            ls[k] += hf; lq[k] += hf * hf;
        }
        *(bf16x8*)(zh2 + (size_t)i * 64 + lg * 8) = hb;
    }

#pragma unroll
    for (int k = 0; k < 8; ++k) {
        ls[k] += __shfl_xor(ls[k], 8, 64);
        ls[k] += __shfl_xor(ls[k], 16, 64);
        ls[k] += __shfl_xor(ls[k], 32, 64);
        lq[k] += __shfl_xor(lq[k], 8, 64);
        lq[k] += __shfl_xor(lq[k], 16, 64);
        lq[k] += __shfl_xor(lq[k], 32, 64);
    }
    __shared__ float red[2][4][64];
    int w = tid >> 6;
    if ((tid & 63) < 8) {
#pragma unroll
        for (int k = 0; k < 8; ++k) {
            red[0][w][lg * 8 + k] = ls[k];
            red[1][w][lg * 8 + k] = lq[k];
        }
    }
    __syncthreads();
    if (tid < 128) {
        int c = tid & 63;
        int half = tid >> 6;
        float v = red[half][0][c] + red[half][1][c] + red[half][2][c] + red[half][3][c];
        pstats[(size_t)tid * gridDim.x + blockIdx.x] = v;
    }
}

// ---------------------------------------------------------------------------
// Finalize via MFMA on PERM-space zh2. One tile per wave.
__global__ __launch_bounds__(256) void k_finalize(
    const unsigned short* __restrict__ h2b,
    const float* __restrict__ t1, const float* __restrict__ v1,
    const float* __restrict__ coef2,
    const float* __restrict__ W3l, const float* __restrict__ W3r,
    float* __restrict__ tb, float* __restrict__ vb, int n) {
    int tid = threadIdx.x, w = tid >> 6, l = tid & 63, ln = l & 15, kg = l >> 4;

    float c2a[16], c2b[16];
#pragma unroll
    for (int j = 0; j < 8; ++j) {
        c2a[j]     = coef2[kg * 8 + j];       c2b[j]     = coef2[64 + kg * 8 + j];
        c2a[8 + j] = coef2[32 + kg * 8 + j];  c2b[8 + j] = coef2[96 + kg * 8 + j];
    }
    bf16x8 b3a, b3b;
#pragma unroll
    for (int j = 0; j < 8; ++j) {
        int k0 = kg * 8 + j;
        int k1 = 32 + kg * 8 + j;
        int o0 = (k0 & 3) * 16 + (k0 >> 2);
        int o1 = (k1 & 3) * 16 + (k1 >> 2);
        float va = (ln == 0) ? W3l[o0] : ((ln == 1) ? W3r[o0] : 0.f);
        float vb = (ln == 0) ? W3l[o1] : ((ln == 1) ? W3r[o1] : 0.f);
        b3a[j] = (short)f2bf(va);
        b3b[j] = (short)f2bf(vb);
    }

    int t = blockIdx.x * 4 + w;
    int nt = (n + 15) >> 4;
    if (t >= nt) return;
    int i0 = t << 4;
    int row = i0 + ln;
    int rr = (row < n) ? row : (n - 1);
    const unsigned short* hr = h2b + (size_t)rr * 64 + kg * 8;
    bf16x8 r0 = *(const bf16x8*)hr;
    bf16x8 r1 = *(const bf16x8*)(hr + 32);
    bf16x8 u0, u1;
#pragma unroll
    for (int j = 0; j < 8; ++j) {
        float f0 = bf2f((unsigned short)r0[j]);
        float f1 = bf2f((unsigned short)r1[j]);
        u0[j] = (short)f2bf(fmaxf(0.f, fmaf(f0, c2a[j], c2b[j])));
        u1[j] = (short)f2bf(fmaxf(0.f, fmaf(f1, c2a[8 + j], c2b[8 + j])));
    }
    f32x4 acc = (f32x4){0.f, 0.f, 0.f, 0.f};
    acc = __builtin_amdgcn_mfma_f32_16x16x32_bf16(u0, b3a, acc, 0, 0, 0);
    acc = __builtin_amdgcn_mfma_f32_16x16x32_bf16(u1, b3b, acc, 0, 0, 0);
    if (ln < 2) {
        float* d = (ln == 0) ? tb : vb;
        const float* s1 = (ln == 0) ? t1 : v1;
#pragma unroll
        for (int r = 0; r < 4; ++r) {
            int orow = i0 + kg * 4 + r;
            if (orow < n) d[orow] = acc[r] + s1[orow];
        }
    }
}

// ---------------------------------------------------------------------------
__global__ void k_gather3(const float* __restrict__ tb, const float* __restrict__ vb,
                          const int* __restrict__ rowptr, const int* __restrict__ csr,
                          const float* __restrict__ b3, float* __restrict__ out, int n) {
    int i = blockIdx.x * blockDim.x + threadIdx.x;
    if (i >= n) return;
    int r0 = rowptr[i], r1 = rowptr[i + 1];
    float s = 0.f;
    int j = r0;
    for (; j + 3 < r1; j += 4)
        s += tb[csr[j]] + tb[csr[j + 1]] + tb[csr[j + 2]] + tb[csr[j + 3]];
    for (; j < r1; ++j) s += tb[csr[j]];
    float inv = 1.f / fmaxf((float)(r1 - r0), 1.f);
    out[i] = fmaf(s, inv, b3[0] + vb[i]);
}

// ---------------------------------------------------------------------------
// Workspace (4B units, N=500k, E=1.25M; cap 256 MiB = 67,108,864 units):
//   y 32N + zh2 32N + R 2N + t1 N + v1 N + rowptr N+1 + csr E + d32 E + s32 E
//   + bsums 2048 + pstats 128*2048 + pmom 14*2048 + small
//   = 68N + 3E + ~295k = ~38.1M units = 152 MB (safe)
extern "C" void kernel_launch(void* const* d_in, const int* in_sizes, int n_in,
                              void* d_out, int out_size, void* d_ws, size_t ws_size,
                              hipStream_t stream) {
    const float* x   = (const float*)d_in[0];
    const int*   ei  = (const int*)d_in[1];
    const float* W1l = (const float*)d_in[2];
    const float* b1  = (const float*)d_in[3];
    const float* W1r = (const float*)d_in[4];
    const float* g1  = (const float*)d_in[5];
    const float* be1 = (const float*)d_in[6];
    const float* W2l = (const float*)d_in[7];
    const float* b2  = (const float*)d_in[8];
    const float* W2r = (const float*)d_in[9];
    const float* g2  = (const float*)d_in[10];
    const float* be2 = (const float*)d_in[11];
    const float* W3l = (const float*)d_in[12];
    const float* b3  = (const float*)d_in[13];
    const float* W3r = (const float*)d_in[14];

    int N = in_sizes[0] / 2;
    int E = in_sizes[1] / 2;

    float* ws   = (float*)d_ws;
    size_t nn   = (size_t)N;
    unsigned short* y   = (unsigned short*)ws;             // 32N units
    unsigned short* zh2 = (unsigned short*)(ws + 32 * nn); // 32N units (z -> h2)
    float* R     = ws + 64 * nn;            // 2N time-shared: cursor -> agg1 -> tb/vb
    int*   cursor = (int*)R;
    float* agg1   = R;
    float* tb     = R;
    float* vb     = R + nn;
    float* t1     = ws + 66 * nn;           // N
    float* v1     = ws + 67 * nn;           // N
    int*   rowptr = (int*)(ws + 68 * nn);   // N+1 (doubles as histogram cnt)
    int*   csr    = rowptr + (N + 1);       // E
    int*   d32    = csr + E;                // E
    int*   s32    = d32 + E;                // E
    int*   bsums  = s32 + E;                // 2048
    float* pstats = (float*)(bsums + 2048); // 128 * 2048 partial stats
    float* pmom   = pstats + 128 * 2048;    // 14 * 2048 partial moments
    float* coef2  = pmom + 14 * 2048;       // 128: a2, b2 (perm space)
    float* fold   = coef2 + 128;            // 320: F0..F4
    int*   flag   = (int*)(fold + 320);     // 64

    hipMemsetAsync(rowptr, 0, (size_t)(N + 1) * sizeof(int), stream);

    k_detect<<<1, 1, 0, stream>>>(ei, flag);

    int ge = (E + 255) / 256;
    int gn = (N + 255) / 256;
    int nb = (N + 1023) / 1024;

    k_cvt<<<ge, 256, 0, stream>>>(ei, flag, E, d32, s32);

    // XCD-aligned histogram/fill: range = blockIdx & 7 (one dst range per XCD).
    {
        int span = (N + 7) / 8;
        k_hist8<<<8 * ge, 256, 0, stream>>>(d32, E, rowptr, span);
        k_scanA<<<nb, 256, 0, stream>>>(rowptr, N, bsums);
        k_scanB<<<1, 256, 0, stream>>>(bsums, nb, rowptr, N);
        k_scanC<<<nb, 256, 0, stream>>>(rowptr, N, bsums, cursor);
        k_fill8<<<8 * ge, 256, 0, stream>>>(d32, s32, E, cursor, csr, span);
    }
    // cursor dead; R becomes agg1

    k_gather1m<<<gn, 256, 0, stream>>>(x, rowptr, csr, agg1, pmom, N);
    k_bnfold1<<<1, 256, 0, stream>>>(pmom, gn, W1l, b1, W1r, g1, be1, fold,
                                     1.0f / (float)N);

    k_dense_pre<<<2048, 256, 0, stream>>>(agg1, x, fold, W2l, b2, W2r, W3l, W3r,
                                          y, zh2, t1, v1, N);
    // agg1 dead after dense_pre

    k_gather2b<<<2048, 256, 0, stream>>>(y, rowptr, csr, zh2, pstats, N);
    k_sredfin<<<64, 256, 0, stream>>>(pstats, 2048, g2, be2, coef2, 1.0f / (float)N);

    // R becomes tb/vb
    int nt = (N + 15) / 16;
    k_finalize<<<(nt + 3) / 4, 256, 0, stream>>>(zh2, t1, v1, coef2,
                                                 W3l, W3r, tb, vb, N);
    k_gather3<<<gn, 256, 0, stream>>>(tb, vb, rowptr, csr, b3, (float*)d_out, N);
}

// Round 20
// 334.079 us; speedup vs baseline: 2.5813x; 1.0157x over previous
//
#include <hip/hip_runtime.h>

#define EPS 1e-5f

typedef __attribute__((ext_vector_type(8))) short bf16x8;
typedef __attribute__((ext_vector_type(4))) float f32x4;

__device__ __forceinline__ unsigned short f2bf(float f) {
    unsigned u = __float_as_uint(f);
    u += 0x7fffu + ((u >> 16) & 1u);
    return (unsigned short)(u >> 16);
}
__device__ __forceinline__ float bf2f(unsigned short s) {
    return __uint_as_float(((unsigned)s) << 16);
}

// Storage channel permutation for y/zh2: c' = (c&15)*4 + (c>>4).
// orig(c') = (c'&3)*16 + (c'>>2). Lets MFMA lanes store contiguous ushort4.

// ---------------------------------------------------------------------------
__global__ void k_detect(const int* __restrict__ ei, int* __restrict__ flag) {
    if (blockIdx.x == 0 && threadIdx.x == 0) {
        int is64 = 1;
        for (int k = 0; k < 16; ++k) is64 &= (ei[2 * k + 1] == 0) ? 1 : 0;
        *flag = is64;
    }
}

// Convert edge_index to packed int32 rows; also zeroes rowptr (fused memset).
__global__ void k_cvt(const int* __restrict__ ei, const int* __restrict__ flag,
                      int E, int N, int* __restrict__ d32, int* __restrict__ s32,
                      int* __restrict__ rowptr) {
    int e = blockIdx.x * blockDim.x + threadIdx.x;
    if (e <= N) rowptr[e] = 0;
    if (e >= E) return;
    if (*flag) {
        s32[e] = (int)((const long long*)ei)[e];
        d32[e] = (int)((const long long*)ei)[E + e];
    } else {
        s32[e] = ei[e];
        d32[e] = ei[E + e];
    }
}

// ---------------------------------------------------------------------------
// CSR build with XCD-ALIGNED range partitioning: range p = blockIdx & 7 so
// all blocks updating dst range p land on XCD p. Range-p's cnt/cursor/csr
// lines then live in exactly ONE private L2 -> full-line writebacks.
__global__ void k_hist8(const int* __restrict__ d32, int E,
                        int* __restrict__ cnt, int span) {
    int p = blockIdx.x & 7;
    int e = (blockIdx.x >> 3) * blockDim.x + threadIdx.x;
    if (e >= E) return;
    int d = d32[e];
    int lo = p * span;
    if (d < lo || d >= lo + span) return;
    atomicAdd(&cnt[d], 1);
}

__device__ __forceinline__ int block_incl_scan(int v, int tid, int* total) {
    __shared__ int wsum[4];
    __shared__ int tot;
#pragma unroll
    for (int o = 1; o < 64; o <<= 1) {
        int u = __shfl_up(v, o, 64);
        if ((tid & 63) >= o) v += u;
    }
    if ((tid & 63) == 63) wsum[tid >> 6] = v;
    __syncthreads();
    int w = tid >> 6, add = 0;
    if (w > 0) add += wsum[0];
    if (w > 1) add += wsum[1];
    if (w > 2) add += wsum[2];
    v += add;
    if (tid == 255) tot = v;
    __syncthreads();
    *total = tot;
    __syncthreads();
    return v;
}

__global__ __launch_bounds__(256) void k_scanA(const int* __restrict__ cnt, int n,
                                               int* __restrict__ bsums) {
    int tid = threadIdx.x;
    int idx = blockIdx.x * 1024 + tid * 4;
    int s = 0;
#pragma unroll
    for (int k = 0; k < 4; ++k) { int i = idx + k; if (i < n) s += cnt[i]; }
#pragma unroll
    for (int o = 32; o > 0; o >>= 1) s += __shfl_xor(s, o, 64);
    __shared__ int ws[4];
    if ((tid & 63) == 0) ws[tid >> 6] = s;
    __syncthreads();
    if (tid == 0) bsums[blockIdx.x] = ws[0] + ws[1] + ws[2] + ws[3];
}

__global__ __launch_bounds__(256) void k_scanB(int* __restrict__ bsums, int nb,
                                               int* __restrict__ rowptr, int N) {
    int tid = threadIdx.x;
    __shared__ int sh_carry;
    if (tid == 0) sh_carry = 0;
    __syncthreads();
    int niter = (nb + 255) / 256;
    for (int it = 0; it < niter; ++it) {
        int i = it * 256 + tid;
        int v = (i < nb) ? bsums[i] : 0;
        int tot;
        int inc = block_incl_scan(v, tid, &tot);
        int carry = sh_carry;
        if (i < nb) bsums[i] = carry + inc - v;
        __syncthreads();
        if (tid == 0) sh_carry = carry + tot;
        __syncthreads();
    }
    if (tid == 0) rowptr[N] = sh_carry;
}

__global__ __launch_bounds__(256) void k_scanC(int* __restrict__ cnt_rowptr, int n,
                                               const int* __restrict__ bsums,
                                               int* __restrict__ cursor) {
    int tid = threadIdx.x;
    int idx = blockIdx.x * 1024 + tid * 4;
    int v[4]; int s = 0;
#pragma unroll
    for (int k = 0; k < 4; ++k) { int i = idx + k; v[k] = (i < n) ? cnt_rowptr[i] : 0; s += v[k]; }
    int tot;
    int inc = block_incl_scan(s, tid, &tot);
    int off = bsums[blockIdx.x] + inc - s;
#pragma unroll
    for (int k = 0; k < 4; ++k) {
        int i = idx + k;
        if (i < n) { cnt_rowptr[i] = off; cursor[i] = off; off += v[k]; }
    }
}

__global__ void k_fill8(const int* __restrict__ d32, const int* __restrict__ s32,
                        int E, int* __restrict__ cursor,
                        int* __restrict__ csr, int span) {
    int p = blockIdx.x & 7;
    int e = (blockIdx.x >> 3) * blockDim.x + threadIdx.x;
    if (e >= E) return;
    int d = d32[e];
    int lo = p * span;
    if (d < lo || d >= lo + span) return;
    int pos = atomicAdd(&cursor[d], 1);
    csr[pos] = s32[e];
}

// ---------------------------------------------------------------------------
// Layer-1 gather fused with u-moments (u = (agg1, x), 14 scalars).
__global__ __launch_bounds__(256) void k_gather1m(
    const float* __restrict__ x, const int* __restrict__ rowptr,
    const int* __restrict__ csr, float* __restrict__ agg1,
    float* __restrict__ pmom, int n) {
    int tid = threadIdx.x;
    int i = blockIdx.x * 256 + tid;
    float m[14];
#pragma unroll
    for (int k = 0; k < 14; ++k) m[k] = 0.f;
    if (i < n) {
        int r0 = rowptr[i], r1 = rowptr[i + 1];
        float s0 = 0.f, s1 = 0.f;
        int j = r0;
        for (; j + 3 < r1; j += 4) {
            float2 v0 = ((const float2*)x)[csr[j]];
            float2 v1 = ((const float2*)x)[csr[j + 1]];
            float2 v2 = ((const float2*)x)[csr[j + 2]];
            float2 v3 = ((const float2*)x)[csr[j + 3]];
            s0 += v0.x + v1.x + v2.x + v3.x;
            s1 += v0.y + v1.y + v2.y + v3.y;
        }
        for (; j < r1; ++j) {
            float2 v = ((const float2*)x)[csr[j]];
            s0 += v.x; s1 += v.y;
        }
        float inv = 1.f / fmaxf((float)(r1 - r0), 1.f);
        float ax = s0 * inv, ay = s1 * inv;
        agg1[2 * i] = ax;
        agg1[2 * i + 1] = ay;
        float2 xv = ((const float2*)x)[i];
        m[0] = ax;        m[1] = ay;        m[2] = xv.x;      m[3] = xv.y;
        m[4] = ax * ax;   m[5] = ax * ay;   m[6] = ax * xv.x; m[7] = ax * xv.y;
        m[8] = ay * ay;   m[9] = ay * xv.x; m[10] = ay * xv.y;
        m[11] = xv.x * xv.x; m[12] = xv.x * xv.y; m[13] = xv.y * xv.y;
    }
#pragma unroll
    for (int k = 0; k < 14; ++k) {
#pragma unroll
        for (int o = 32; o > 0; o >>= 1) m[k] += __shfl_xor(m[k], o, 64);
    }
    __shared__ float red[4][14];
    int w = tid >> 6;
    if ((tid & 63) == 0) {
#pragma unroll
        for (int k = 0; k < 14; ++k) red[w][k] = m[k];
    }
    __syncthreads();
    if (tid < 14)
        pmom[(size_t)tid * gridDim.x + blockIdx.x] =
            red[0][tid] + red[1][tid] + red[2][tid] + red[3][tid];
}

// ---------------------------------------------------------------------------
// Reduce pmom partials + BN1-fold (1 block x 256).
__global__ __launch_bounds__(256) void k_bnfold1(
    const float* __restrict__ pmom, int gn,
    const float* __restrict__ W1l, const float* __restrict__ b1,
    const float* __restrict__ W1r,
    const float* __restrict__ g1, const float* __restrict__ be1,
    float* __restrict__ fold, float invN) {
    int tid = threadIdx.x;
    __shared__ float smom[14];
    __shared__ float ws[4];
    for (int k = 0; k < 14; ++k) {
        float s = 0.f;
        for (int idx = tid; idx < gn; idx += 256) s += pmom[(size_t)k * gn + idx];
#pragma unroll
        for (int o = 32; o > 0; o >>= 1) s += __shfl_xor(s, o, 64);
        if ((tid & 63) == 0) ws[tid >> 6] = s;
        __syncthreads();
        if (tid == 0) smom[k] = ws[0] + ws[1] + ws[2] + ws[3];
        __syncthreads();
    }
    if (tid < 64) {
        int c = tid;
        float w0 = W1l[c], w1 = W1l[64 + c], w2 = W1r[c], w3 = W1r[64 + c], w4 = b1[c];
        float lin = (smom[0] * w0 + smom[1] * w1 + smom[2] * w2 + smom[3] * w3) * invN;
        float mean = lin + w4;
        float q = smom[4] * w0 * w0 + smom[8] * w1 * w1 + smom[11] * w2 * w2 + smom[13] * w3 * w3
                + 2.f * (smom[5] * w0 * w1 + smom[6] * w0 * w2 + smom[7] * w0 * w3
                       + smom[9] * w1 * w2 + smom[10] * w1 * w3 + smom[12] * w2 * w3);
        float Eh2 = q * invN + 2.f * w4 * lin + w4 * w4;
        float var = Eh2 - mean * mean;
        float al = g1[c] * rsqrtf(var + EPS);
        float be = be1[c] - mean * al;
        fold[c]       = al * w0;
        fold[64 + c]  = al * w1;
        fold[128 + c] = al * w2;
        fold[192 + c] = al * w3;
        fold[256 + c] = al * w4 + be;
    }
}

// ---------------------------------------------------------------------------
// Fused: reduce pstats partials -> BN2 coefs (perm space; g2/be2 via orig()).
__global__ __launch_bounds__(256) void k_sredfin(
    const float* __restrict__ pstats, int nb,
    const float* __restrict__ g, const float* __restrict__ be,
    float* __restrict__ coef, float invN) {
    int c = blockIdx.x, tid = threadIdx.x;   // c = perm-space channel (0..63)
    float s = 0.f, q = 0.f;
    for (int i = tid; i < nb; i += 256) {
        s += pstats[(size_t)c * nb + i];
        q += pstats[(size_t)(64 + c) * nb + i];
    }
#pragma unroll
    for (int o = 32; o > 0; o >>= 1) {
        s += __shfl_xor(s, o, 64);
        q += __shfl_xor(q, o, 64);
    }
    __shared__ float ws[4], wq[4];
    if ((tid & 63) == 0) { ws[tid >> 6] = s; wq[tid >> 6] = q; }
    __syncthreads();
    if (tid == 0) {
        float S = ws[0] + ws[1] + ws[2] + ws[3];
        float Q = wq[0] + wq[1] + wq[2] + wq[3];
        float m = S * invN;
        float var = Q * invN - m * m;
        int o = (c & 3) * 16 + (c >> 2);      // original channel
        float a = g[o] * rsqrtf(var + EPS);
        coef[c] = a;
        coef[64 + c] = be[o] - m * a;
    }
}

// ---------------------------------------------------------------------------
// Pre-transform: x1 = relu(bn1-folded(agg1, x)) on the fly; y = x1@W2l;
// z = x1@W2r + b2; t1 = x1.W3l; v1 = x1.W3r. Direct PERMUTED ushort4 stores.
__global__ __launch_bounds__(256) void k_dense_pre(
    const float* __restrict__ agg1, const float* __restrict__ xin,
    const float* __restrict__ fold,
    const float* __restrict__ W2l, const float* __restrict__ b2,
    const float* __restrict__ W2r,
    const float* __restrict__ W3l, const float* __restrict__ W3r,
    unsigned short* __restrict__ y, unsigned short* __restrict__ z,
    float* __restrict__ t1, float* __restrict__ v1, int n) {
    __shared__ unsigned short lds_w[16 * 64 * 8];   // 16 KB (W frags only)
    int tid = threadIdx.x, w = tid >> 6, l = tid & 63, ln = l & 15, kg = l >> 4;

    for (int idx = tid; idx < 4096; idx += 256) {
        int k = idx >> 6, c = idx & 63;
        int lane = ((k >> 3) & 3) * 16 + (c & 15);
        int fbase = ((k >> 5) * 4 + (c >> 4)) * 64 + lane;
        lds_w[fbase * 8 + (k & 7)] = f2bf(W2l[idx]);
        lds_w[(8 * 64 + fbase) * 8 + (k & 7)] = f2bf(W2r[idx]);
    }
    __syncthreads();

    float bb[4];
#pragma unroll
    for (int cs = 0; cs < 4; ++cs) bb[cs] = b2[cs * 16 + ln];

    float F0[16], F1[16], F2[16], F3[16], F4[16];
#pragma unroll
    for (int j = 0; j < 8; ++j) {
        int c = kg * 8 + j;
        F0[j] = fold[c];       F1[j] = fold[64 + c];  F2[j] = fold[128 + c];
        F3[j] = fold[192 + c]; F4[j] = fold[256 + c];
        c += 32;
        F0[8 + j] = fold[c];       F1[8 + j] = fold[64 + c];  F2[8 + j] = fold[128 + c];
        F3[8 + j] = fold[192 + c]; F4[8 + j] = fold[256 + c];
    }
    bf16x8 b3a, b3b;
#pragma unroll
    for (int j = 0; j < 8; ++j) {
        float va = (ln == 0) ? W3l[kg * 8 + j] : ((ln == 1) ? W3r[kg * 8 + j] : 0.f);
        float vb = (ln == 0) ? W3l[32 + kg * 8 + j] : ((ln == 1) ? W3r[32 + kg * 8 + j] : 0.f);
        b3a[j] = (short)f2bf(va);
        b3b[j] = (short)f2bf(vb);
    }

    const bf16x8* wfrag = (const bf16x8*)lds_w;
    int nt = (n + 15) >> 4;
    int stride = gridDim.x * 4;

#define LOADH(T, A)                                                          \
    {                                                                        \
        int row_ = ((T) << 4) + ln;                                          \
        int rr_ = (row_ < n) ? row_ : (n - 1);                               \
        A##a = ((const float2*)agg1)[rr_];                                   \
        A##x = ((const float2*)xin)[rr_];                                    \
    }

#define PROCESSH(T, A)                                                       \
    {                                                                        \
        bf16x8 u0_, u1_;                                                     \
        _Pragma("unroll")                                                    \
        for (int j = 0; j < 8; ++j) {                                        \
            float h0_ = fmaf(A##a.x, F0[j], fmaf(A##a.y, F1[j],              \
                        fmaf(A##x.x, F2[j], fmaf(A##x.y, F3[j], F4[j]))));   \
            float h1_ = fmaf(A##a.x, F0[8 + j], fmaf(A##a.y, F1[8 + j],      \
                        fmaf(A##x.x, F2[8 + j], fmaf(A##x.y, F3[8 + j], F4[8 + j])))); \
            u0_[j] = (short)f2bf(fmaxf(0.f, h0_));                           \
            u1_[j] = (short)f2bf(fmaxf(0.f, h1_));                           \
        }                                                                    \
        f32x4 ya_[4], za_[4], a3_;                                           \
        _Pragma("unroll")                                                    \
        for (int cs = 0; cs < 4; ++cs) {                                     \
            ya_[cs] = (f32x4){0.f, 0.f, 0.f, 0.f};                           \
            za_[cs] = (f32x4){0.f, 0.f, 0.f, 0.f};                           \
        }                                                                    \
        a3_ = (f32x4){0.f, 0.f, 0.f, 0.f};                                   \
        _Pragma("unroll")                                                    \
        for (int cs = 0; cs < 4; ++cs) {                                     \
            ya_[cs] = __builtin_amdgcn_mfma_f32_16x16x32_bf16(u0_, wfrag[(0 * 4 + cs) * 64 + l], ya_[cs], 0, 0, 0);  \
            ya_[cs] = __builtin_amdgcn_mfma_f32_16x16x32_bf16(u1_, wfrag[(1 * 4 + cs) * 64 + l], ya_[cs], 0, 0, 0);  \
            za_[cs] = __builtin_amdgcn_mfma_f32_16x16x32_bf16(u0_, wfrag[(8 + cs) * 64 + l], za_[cs], 0, 0, 0);      \
            za_[cs] = __builtin_amdgcn_mfma_f32_16x16x32_bf16(u1_, wfrag[(12 + cs) * 64 + l], za_[cs], 0, 0, 0);     \
        }                                                                    \
        a3_ = __builtin_amdgcn_mfma_f32_16x16x32_bf16(u0_, b3a, a3_, 0, 0, 0); \
        a3_ = __builtin_amdgcn_mfma_f32_16x16x32_bf16(u1_, b3b, a3_, 0, 0, 0); \
        int base_ = (T) << 4;                                                \
        _Pragma("unroll")                                                    \
        for (int r = 0; r < 4; ++r) {                                        \
            int row_ = base_ + kg * 4 + r;                                   \
            if (row_ < n) {                                                  \
                ushort4 yv_, zv_;                                            \
                yv_.x = f2bf(ya_[0][r]); yv_.y = f2bf(ya_[1][r]);            \
                yv_.z = f2bf(ya_[2][r]); yv_.w = f2bf(ya_[3][r]);            \
                zv_.x = f2bf(za_[0][r] + bb[0]); zv_.y = f2bf(za_[1][r] + bb[1]); \
                zv_.z = f2bf(za_[2][r] + bb[2]); zv_.w = f2bf(za_[3][r] + bb[3]); \
                *(ushort4*)(y + (size_t)row_ * 64 + ln * 4) = yv_;           \
                *(ushort4*)(z + (size_t)row_ * 64 + ln * 4) = zv_;           \
            }                                                                \
        }                                                                    \
        if (ln < 2) {                                                        \
            float* d3_ = (ln == 0) ? t1 : v1;                                \
            _Pragma("unroll")                                                \
            for (int r = 0; r < 4; ++r) {                                    \
                int row_ = base_ + kg * 4 + r;                               \
                if (row_ < n) d3_[row_] = a3_[r];                            \
            }                                                                \
        }                                                                    \
    }

    float2 Pa, Px, Qa, Qx;
    int t = blockIdx.x * 4 + w;
    if (t < nt) {
        LOADH(t, P);
        while (t < nt) {
            int t1_ = t + stride;
            if (t1_ < nt) LOADH(t1_, Q);
            PROCESSH(t, P);
            int t2_ = t1_ + stride;
            if (t2_ < nt) LOADH(t2_, P);
            if (t1_ < nt) PROCESSH(t1_, Q);
            t = t2_;
        }
    }
#undef LOADH
#undef PROCESSH
}

// ---------------------------------------------------------------------------
// Gather + combine: h2_i = mean_j y[src_j] + z_i, in place on z (perm space).
// 8-lane groups, grid-stride, SOFTWARE-PIPELINED: next node's zh2 row and
// rowptr pair are issued before the current node's csr/y chain, hiding their
// latency. Neighbor loop is a 4/2/1 ladder (no regression at low degree).
// ATOMIC-FREE stats partials.
__global__ __launch_bounds__(256) void k_gather2b(
    const unsigned short* __restrict__ y, const int* __restrict__ rowptr,
    const int* __restrict__ csr, unsigned short* zh2,
    float* __restrict__ pstats, int n) {
    int tid = threadIdx.x;
    int lg = tid & 7;
    int gid0 = blockIdx.x * 32 + (tid >> 3);
    int gstep = gridDim.x * 32;
    float ls[8] = {0.f, 0.f, 0.f, 0.f, 0.f, 0.f, 0.f, 0.f};
    float lq[8] = {0.f, 0.f, 0.f, 0.f, 0.f, 0.f, 0.f, 0.f};

    int i = gid0;
    if (i < n) {
        bf16x8 z8 = *(const bf16x8*)(zh2 + (size_t)i * 64 + lg * 8);
        int r0 = rowptr[i], r1 = rowptr[i + 1];
        while (true) {
            // ---- prefetch next node (in flight during this node's gather)
            int inext = i + gstep;
            bool hasnext = inext < n;
            bf16x8 z8n;
            int nr0 = 0, nr1 = 0;
            if (hasnext) {
                z8n = *(const bf16x8*)(zh2 + (size_t)inext * 64 + lg * 8);
                nr0 = rowptr[inext];
                nr1 = rowptr[inext + 1];
            }
            // ---- gather this node's neighbors (4/2/1 ladder)
            float s[8] = {0.f, 0.f, 0.f, 0.f, 0.f, 0.f, 0.f, 0.f};
            int j = r0;
            for (; j + 3 < r1; j += 4) {
                int a = csr[j], b = csr[j + 1], c = csr[j + 2], d = csr[j + 3];
                bf16x8 va = *(const bf16x8*)(y + (size_t)a * 64 + lg * 8);
                bf16x8 vb = *(const bf16x8*)(y + (size_t)b * 64 + lg * 8);
                bf16x8 vc = *(const bf16x8*)(y + (size_t)c * 64 + lg * 8);
                bf16x8 vd = *(const bf16x8*)(y + (size_t)d * 64 + lg * 8);
#pragma unroll
                for (int k = 0; k < 8; ++k)
                    s[k] += (bf2f((unsigned short)va[k]) + bf2f((unsigned short)vb[k]))
                          + (bf2f((unsigned short)vc[k]) + bf2f((unsigned short)vd[k]));
            }
            if (j + 1 < r1) {
                int a = csr[j], b = csr[j + 1];
                bf16x8 va = *(const bf16x8*)(y + (size_t)a * 64 + lg * 8);
                bf16x8 vb = *(const bf16x8*)(y + (size_t)b * 64 + lg * 8);
#pragma unroll
                for (int k = 0; k < 8; ++k)
                    s[k] += bf2f((unsigned short)va[k]) + bf2f((unsigned short)vb[k]);
                j += 2;
            }
            if (j < r1) {
                bf16x8 va = *(const bf16x8*)(y + (size_t)csr[j] * 64 + lg * 8);
#pragma unroll
                for (int k = 0; k < 8; ++k) s[k] += bf2f((unsigned short)va[k]);
            }
            float inv = 1.f / fmaxf((float)(r1 - r0), 1.f);
            bf16x8 hb;
#pragma unroll
            for (int k = 0; k < 8; ++k) {
                float h = fmaf(s[k], inv, bf2f((unsigned short)z8[k]));
                unsigned short b = f2bf(h);
                hb[k] = (short)b;
                float hf = bf2f(b);
                ls[k] += hf; lq[k] += hf * hf;
            }
            *(bf16x8*)(zh2 + (size_t)i * 64 + lg * 8) = hb;
            if (!hasnext) break;
            i = inext; z8 = z8n; r0 = nr0; r1 = nr1;
        }
    }

#pragma unroll
    for (int k = 0; k < 8; ++k) {
        ls[k] += __shfl_xor(ls[k], 8, 64);
        ls[k] += __shfl_xor(ls[k], 16, 64);
        ls[k] += __shfl_xor(ls[k], 32, 64);
        lq[k] += __shfl_xor(lq[k], 8, 64);
        lq[k] += __shfl_xor(lq[k], 16, 64);
        lq[k] += __shfl_xor(lq[k], 32, 64);
    }
    __shared__ float red[2][4][64];
    int w = tid >> 6;
    if ((tid & 63) < 8) {
#pragma unroll
        for (int k = 0; k < 8; ++k) {
            red[0][w][lg * 8 + k] = ls[k];
            red[1][w][lg * 8 + k] = lq[k];
        }
    }
    __syncthreads();
    if (tid < 128) {
        int c = tid & 63;
        int half = tid >> 6;
        float v = red[half][0][c] + red[half][1][c] + red[half][2][c] + red[half][3][c];
        pstats[(size_t)tid * gridDim.x + blockIdx.x] = v;
    }
}

// ---------------------------------------------------------------------------
// Finalize via MFMA on PERM-space zh2. One tile per wave.
__global__ __launch_bounds__(256) void k_finalize(
    const unsigned short* __restrict__ h2b,
    const float* __restrict__ t1, const float* __restrict__ v1,
    const float* __restrict__ coef2,
    const float* __restrict__ W3l, const float* __restrict__ W3r,
    float* __restrict__ tb, float* __restrict__ vb, int n) {
    int tid = threadIdx.x, w = tid >> 6, l = tid & 63, ln = l & 15, kg = l >> 4;

    float c2a[16], c2b[16];
#pragma unroll
    for (int j = 0; j < 8; ++j) {
        c2a[j]     = coef2[kg * 8 + j];       c2b[j]     = coef2[64 + kg * 8 + j];
        c2a[8 + j] = coef2[32 + kg * 8 + j];  c2b[8 + j] = coef2[96 + kg * 8 + j];
    }
    bf16x8 b3a, b3b;
#pragma unroll
    for (int j = 0; j < 8; ++j) {
        int k0 = kg * 8 + j;
        int k1 = 32 + kg * 8 + j;
        int o0 = (k0 & 3) * 16 + (k0 >> 2);
        int o1 = (k1 & 3) * 16 + (k1 >> 2);
        float va = (ln == 0) ? W3l[o0] : ((ln == 1) ? W3r[o0] : 0.f);
        float vb = (ln == 0) ? W3l[o1] : ((ln == 1) ? W3r[o1] : 0.f);
        b3a[j] = (short)f2bf(va);
        b3b[j] = (short)f2bf(vb);
    }

    int t = blockIdx.x * 4 + w;
    int nt = (n + 15) >> 4;
    if (t >= nt) return;
    int i0 = t << 4;
    int row = i0 + ln;
    int rr = (row < n) ? row : (n - 1);
    const unsigned short* hr = h2b + (size_t)rr * 64 + kg * 8;
    bf16x8 r0 = *(const bf16x8*)hr;
    bf16x8 r1 = *(const bf16x8*)(hr + 32);
    bf16x8 u0, u1;
#pragma unroll
    for (int j = 0; j < 8; ++j) {
        float f0 = bf2f((unsigned short)r0[j]);
        float f1 = bf2f((unsigned short)r1[j]);
        u0[j] = (short)f2bf(fmaxf(0.f, fmaf(f0, c2a[j], c2b[j])));
        u1[j] = (short)f2bf(fmaxf(0.f, fmaf(f1, c2a[8 + j], c2b[8 + j])));
    }
    f32x4 acc = (f32x4){0.f, 0.f, 0.f, 0.f};
    acc = __builtin_amdgcn_mfma_f32_16x16x32_bf16(u0, b3a, acc, 0, 0, 0);
    acc = __builtin_amdgcn_mfma_f32_16x16x32_bf16(u1, b3b, acc, 0, 0, 0);
    if (ln < 2) {
        float* d = (ln == 0) ? tb : vb;
        const float* s1 = (ln == 0) ? t1 : v1;
#pragma unroll
        for (int r = 0; r < 4; ++r) {
            int orow = i0 + kg * 4 + r;
            if (orow < n) d[orow] = acc[r] + s1[orow];
        }
    }
}

// ---------------------------------------------------------------------------
__global__ void k_gather3(const float* __restrict__ tb, const float* __restrict__ vb,
                          const int* __restrict__ rowptr, const int* __restrict__ csr,
                          const float* __restrict__ b3, float* __restrict__ out, int n) {
    int i = blockIdx.x * blockDim.x + threadIdx.x;
    if (i >= n) return;
    int r0 = rowptr[i], r1 = rowptr[i + 1];
    float s = 0.f;
    int j = r0;
    for (; j + 3 < r1; j += 4)
        s += tb[csr[j]] + tb[csr[j + 1]] + tb[csr[j + 2]] + tb[csr[j + 3]];
    for (; j < r1; ++j) s += tb[csr[j]];
    float inv = 1.f / fmaxf((float)(r1 - r0), 1.f);
    out[i] = fmaf(s, inv, b3[0] + vb[i]);
}

// ---------------------------------------------------------------------------
// Workspace (4B units, N=500k, E=1.25M; cap 256 MiB = 67,108,864 units):
//   y 32N + zh2 32N + R 2N + t1 N + v1 N + rowptr N+1 + csr E + d32 E + s32 E
//   + bsums 2048 + pstats 128*2048 + pmom 14*2048 + small
//   = 68N + 3E + ~295k = ~38.1M units = 152 MB (safe)
extern "C" void kernel_launch(void* const* d_in, const int* in_sizes, int n_in,
                              void* d_out, int out_size, void* d_ws, size_t ws_size,
                              hipStream_t stream) {
    const float* x   = (const float*)d_in[0];
    const int*   ei  = (const int*)d_in[1];
    const float* W1l = (const float*)d_in[2];
    const float* b1  = (const float*)d_in[3];
    const float* W1r = (const float*)d_in[4];
    const float* g1  = (const float*)d_in[5];
    const float* be1 = (const float*)d_in[6];
    const float* W2l = (const float*)d_in[7];
    const float* b2  = (const float*)d_in[8];
    const float* W2r = (const float*)d_in[9];
    const float* g2  = (const float*)d_in[10];
    const float* be2 = (const float*)d_in[11];
    const float* W3l = (const float*)d_in[12];
    const float* b3  = (const float*)d_in[13];
    const float* W3r = (const float*)d_in[14];

    int N = in_sizes[0] / 2;
    int E = in_sizes[1] / 2;

    float* ws   = (float*)d_ws;
    size_t nn   = (size_t)N;
    unsigned short* y   = (unsigned short*)ws;             // 32N units
    unsigned short* zh2 = (unsigned short*)(ws + 32 * nn); // 32N units (z -> h2)
    float* R     = ws + 64 * nn;            // 2N time-shared: cursor -> agg1 -> tb/vb
    int*   cursor = (int*)R;
    float* agg1   = R;
    float* tb     = R;
    float* vb     = R + nn;
    float* t1     = ws + 66 * nn;           // N
    float* v1     = ws + 67 * nn;           // N
    int*   rowptr = (int*)(ws + 68 * nn);   // N+1 (doubles as histogram cnt)
    int*   csr    = rowptr + (N + 1);       // E
    int*   d32    = csr + E;                // E
    int*   s32    = d32 + E;                // E
    int*   bsums  = s32 + E;                // 2048
    float* pstats = (float*)(bsums + 2048); // 128 * 2048 partial stats
    float* pmom   = pstats + 128 * 2048;    // 14 * 2048 partial moments
    float* coef2  = pmom + 14 * 2048;       // 128: a2, b2 (perm space)
    float* fold   = coef2 + 128;            // 320: F0..F4
    int*   flag   = (int*)(fold + 320);     // 64

    k_detect<<<1, 1, 0, stream>>>(ei, flag);

    int ge = (E + 255) / 256;
    int gn = (N + 255) / 256;
    int nb = (N + 1023) / 1024;

    // cvt also zeroes rowptr (grid covers max(E, N+1) threads)
    int gc = (((E > N + 1) ? E : (N + 1)) + 255) / 256;
    k_cvt<<<gc, 256, 0, stream>>>(ei, flag, E, N, d32, s32, rowptr);

    // XCD-aligned histogram/fill: range = blockIdx & 7 (one dst range per XCD).
    {
        int span = (N + 7) / 8;
        k_hist8<<<8 * ge, 256, 0, stream>>>(d32, E, rowptr, span);
        k_scanA<<<nb, 256, 0, stream>>>(rowptr, N, bsums);
        k_scanB<<<1, 256, 0, stream>>>(bsums, nb, rowptr, N);
        k_scanC<<<nb, 256, 0, stream>>>(rowptr, N, bsums, cursor);
        k_fill8<<<8 * ge, 256, 0, stream>>>(d32, s32, E, cursor, csr, span);
    }
    // cursor dead; R becomes agg1

    k_gather1m<<<gn, 256, 0, stream>>>(x, rowptr, csr, agg1, pmom, N);
    k_bnfold1<<<1, 256, 0, stream>>>(pmom, gn, W1l, b1, W1r, g1, be1, fold,
                                     1.0f / (float)N);

    k_dense_pre<<<2048, 256, 0, stream>>>(agg1, x, fold, W2l, b2, W2r, W3l, W3r,
                                          y, zh2, t1, v1, N);
    // agg1 dead after dense_pre

    k_gather2b<<<2048, 256, 0, stream>>>(y, rowptr, csr, zh2, pstats, N);
    k_sredfin<<<64, 256, 0, stream>>>(pstats, 2048, g2, be2, coef2, 1.0f / (float)N);

    // R becomes tb/vb
    int nt = (N + 15) / 16;
    k_finalize<<<(nt + 3) / 4, 256, 0, stream>>>(zh2, t1, v1, coef2,
                                                 W3l, W3r, tb, vb, N);
    k_gather3<<<gn, 256, 0, stream>>>(tb, vb, rowptr, csr, b3, (float*)d_out, N);
}